// Round 2
// baseline (1354.835 us; speedup 1.0000x reference)
//
#include <hip/hip_runtime.h>
#include <math.h>

// Physics_Attention: B=1, N=65536, DIM=256, H=8, D=64, G=64
#define NPTS  65536
#define DIMX  256
#define NH    8
#define HDIM  512   // H*D
// ws layout (floats):
//   xmid  [NPTS][512]            = 33.55M
//   sw    [NPTS][512] (h*64+g)   = 33.55M
//   stp   [H][64ch][64g][64c]    = 2.10M
//   normp [H][64ch][64g]         = 32768
//   Mt    [256][512]             = 131072
// total ~278 MB

__device__ __forceinline__ float gelu_f(float x) {
    return 0.5f * x * (1.0f + erff(x * 0.7071067811865476f));
}

// ---------------------------------------------------------------------------
// C[m][o] = sum_k A[m][k]*B[o][k] + bias[o]; 128x128 tile, 8x8/thread, KC=8
// ---------------------------------------------------------------------------
template<int K>
__global__ __launch_bounds__(256)
void gemm_f32(const float* __restrict__ A, const float* __restrict__ B,
              const float* __restrict__ bias, float* __restrict__ C, int O) {
    __shared__ float As[8][132];
    __shared__ float Bs[8][132];
    const int m0 = blockIdx.x * 128;
    const int o0 = blockIdx.y * 128;
    const int t  = threadIdx.x;
    const int tx = t & 15, ty = t >> 4;
    const int r  = t >> 1, c4 = (t & 1) * 4;
    float acc[8][8];
    #pragma unroll
    for (int i = 0; i < 8; ++i)
        #pragma unroll
        for (int j = 0; j < 8; ++j) acc[i][j] = 0.f;

    const float* Ap = A + (size_t)(m0 + r) * K + c4;
    const float* Bp = B + (size_t)(o0 + r) * K + c4;

    for (int kc = 0; kc < K; kc += 8) {
        float4 av = *(const float4*)(Ap + kc);
        float4 bv = *(const float4*)(Bp + kc);
        __syncthreads();
        As[c4+0][r] = av.x; As[c4+1][r] = av.y; As[c4+2][r] = av.z; As[c4+3][r] = av.w;
        Bs[c4+0][r] = bv.x; Bs[c4+1][r] = bv.y; Bs[c4+2][r] = bv.z; Bs[c4+3][r] = bv.w;
        __syncthreads();
        #pragma unroll
        for (int kk = 0; kk < 8; ++kk) {
            float a_[8], b_[8];
            #pragma unroll
            for (int i = 0; i < 8; ++i) a_[i] = As[kk][ty*8 + i];
            #pragma unroll
            for (int j = 0; j < 8; ++j) b_[j] = Bs[kk][tx*8 + j];
            #pragma unroll
            for (int i = 0; i < 8; ++i)
                #pragma unroll
                for (int j = 0; j < 8; ++j)
                    acc[i][j] = fmaf(a_[i], b_[j], acc[i][j]);
        }
    }
    float bb[8];
    #pragma unroll
    for (int j = 0; j < 8; ++j) bb[j] = bias[o0 + tx*8 + j];
    #pragma unroll
    for (int i = 0; i < 8; ++i) {
        float* cp = C + (size_t)(m0 + ty*8 + i) * O + o0 + tx*8;
        float4 v0 = make_float4(acc[i][0]+bb[0], acc[i][1]+bb[1], acc[i][2]+bb[2], acc[i][3]+bb[3]);
        float4 v1 = make_float4(acc[i][4]+bb[4], acc[i][5]+bb[5], acc[i][6]+bb[6], acc[i][7]+bb[7]);
        *(float4*)cp       = v0;
        *(float4*)(cp + 4) = v1;
    }
}

// ---------------------------------------------------------------------------
// Fused: [lg | t1] = xmid_h @ [Ws; Wt1]^T  (128 pts x 128 out, K=64),
// then temp-MLP + gumbel softmax in registers via 16-lane shuffle groups,
// writing sw directly. Row layout: for point row, lanes tx=0..7 hold the 64
// logits (8 each), lanes tx=8..15 hold the 64 t1 values.
// ---------------------------------------------------------------------------
__global__ __launch_bounds__(256)
void lgt1_fused_kernel(const float* __restrict__ xmid,
                       const float* __restrict__ Ws,  const float* __restrict__ bs,
                       const float* __restrict__ Wt1, const float* __restrict__ bt1,
                       const float* __restrict__ Wt2, const float* __restrict__ bt2,
                       const float* __restrict__ biasp,
                       const float* __restrict__ u,
                       float* __restrict__ sw) {
    __shared__ float As[8][132];
    __shared__ float Bs[8][132];
    const int h  = blockIdx.y;
    const int m0 = blockIdx.x * 128;
    const int t  = threadIdx.x;
    const int tx = t & 15, ty = t >> 4;
    const int r  = t >> 1, c4 = (t & 1) * 4;

    float acc[8][8];
    #pragma unroll
    for (int i = 0; i < 8; ++i)
        #pragma unroll
        for (int j = 0; j < 8; ++j) acc[i][j] = 0.f;

    const float* Ap = xmid + (size_t)(m0 + r) * HDIM + h*64 + c4;
    const float* Bp = (r < 64 ? Ws + (size_t)r * 64 : Wt1 + (size_t)(r - 64) * 64) + c4;

    for (int kc = 0; kc < 64; kc += 8) {
        float4 av = *(const float4*)(Ap + kc);
        float4 bv = *(const float4*)(Bp + kc);
        __syncthreads();
        As[c4+0][r] = av.x; As[c4+1][r] = av.y; As[c4+2][r] = av.z; As[c4+3][r] = av.w;
        Bs[c4+0][r] = bv.x; Bs[c4+1][r] = bv.y; Bs[c4+2][r] = bv.z; Bs[c4+3][r] = bv.w;
        __syncthreads();
        #pragma unroll
        for (int kk = 0; kk < 8; ++kk) {
            float a_[8], b_[8];
            #pragma unroll
            for (int i = 0; i < 8; ++i) a_[i] = As[kk][ty*8 + i];
            #pragma unroll
            for (int j = 0; j < 8; ++j) b_[j] = Bs[kk][tx*8 + j];
            #pragma unroll
            for (int i = 0; i < 8; ++i)
                #pragma unroll
                for (int j = 0; j < 8; ++j)
                    acc[i][j] = fmaf(a_[i], b_[j], acc[i][j]);
        }
    }

    // per-lane constants: g8 = (tx&7)*8 .. +7
    const int g8 = (tx & 7) * 8;
    float bsr[8], bt1r[8], wt2r[8];
    #pragma unroll
    for (int j = 0; j < 8; ++j) {
        bsr[j]  = bs [g8 + j];
        bt1r[j] = bt1[g8 + j];
        wt2r[j] = Wt2[g8 + j];
    }
    const float bt2v   = bt2[0];
    const float biasph = biasp[h];
    const bool  is_lg  = (tx < 8);

    #pragma unroll 1
    for (int i = 0; i < 8; ++i) {
        const int n = m0 + ty*8 + i;
        // ---- temperature path: t1 lanes (tx>=8) compute sum_g gelu(t1)*Wt2
        float mysum = 0.f;
        if (!is_lg) {
            #pragma unroll
            for (int j = 0; j < 8; ++j)
                mysum += gelu_f(acc[i][j] + bt1r[j]) * wt2r[j];
        }
        // reduce across the 16-lane group (lg lanes contribute 0)
        mysum += __shfl_xor(mysum, 1);
        mysum += __shfl_xor(mysum, 2);
        mysum += __shfl_xor(mysum, 4);
        mysum += __shfl_xor(mysum, 8);
        float temp = gelu_f(mysum + bt2v) + biasph;
        temp = fmaxf(temp, 0.01f);
        const float invt = 1.0f / temp;

        // ---- gumbel softmax: lg lanes (tx<8) own 8 g-values each
        if (is_lg) {
            const float* up = u + ((size_t)h * NPTS + n) * 64 + g8;
            float4 u0 = *(const float4*)up;
            float4 u1 = *(const float4*)(up + 4);
            float uu[8] = {u0.x,u0.y,u0.z,u0.w,u1.x,u1.y,u1.z,u1.w};
            float s[8];
            float mx = -1e30f;
            #pragma unroll
            for (int j = 0; j < 8; ++j) {
                float gn = -logf(-logf(uu[j] + 1e-8f) + 1e-8f);
                s[j] = (acc[i][j] + bsr[j] + gn) * invt;
                mx = fmaxf(mx, s[j]);
            }
            mx = fmaxf(mx, __shfl_xor(mx, 1));
            mx = fmaxf(mx, __shfl_xor(mx, 2));
            mx = fmaxf(mx, __shfl_xor(mx, 4));
            float ps = 0.f;
            #pragma unroll
            for (int j = 0; j < 8; ++j) { s[j] = expf(s[j] - mx); ps += s[j]; }
            ps += __shfl_xor(ps, 1);
            ps += __shfl_xor(ps, 2);
            ps += __shfl_xor(ps, 4);
            const float inv = 1.0f / ps;
            float* sp = sw + ((size_t)n * NH + h) * 64 + g8;
            *(float4*)sp       = make_float4(s[0]*inv, s[1]*inv, s[2]*inv, s[3]*inv);
            *(float4*)(sp + 4) = make_float4(s[4]*inv, s[5]*inv, s[6]*inv, s[7]*inv);
        }
    }
}

// ---------------------------------------------------------------------------
// Per (h, chunk of 1024 pts): partial slice_tokens[g][c] and norm[g]
// ---------------------------------------------------------------------------
__global__ __launch_bounds__(256)
void gather_kernel(const float* __restrict__ xmid, const float* __restrict__ sw,
                   float* __restrict__ stp, float* __restrict__ normp) {
    __shared__ float xt [64][68];
    __shared__ float stl[64][68];
    __shared__ float nacc[4][64];
    const int h  = blockIdx.y;
    const int n0 = blockIdx.x * 1024;
    const int t  = threadIdx.x;
    const int q  = t >> 6, c = t & 63;
    float acc[16];
    #pragma unroll
    for (int i = 0; i < 16; ++i) acc[i] = 0.f;
    float nsum = 0.f;

    for (int tile = 0; tile < 16; ++tile) {
        const int pt = n0 + tile * 64;
        __syncthreads();
        #pragma unroll
        for (int i = 0; i < 4; ++i) {
            int idx = t + i * 256;
            int p = idx >> 4, cc = (idx & 15) * 4;
            *(float4*)&xt [p][cc] = *(const float4*)&xmid[(size_t)(pt + p) * HDIM + h*64 + cc];
            *(float4*)&stl[p][cc] = *(const float4*)&sw [((size_t)(pt + p) * NH + h) * 64 + cc];
        }
        __syncthreads();
        for (int p = 0; p < 64; ++p) {
            float xvv = xt[p][c];
            #pragma unroll
            for (int i4 = 0; i4 < 4; ++i4) {
                float4 sv = *(const float4*)&stl[p][q*16 + i4*4];
                acc[i4*4+0] = fmaf(sv.x, xvv, acc[i4*4+0]);
                acc[i4*4+1] = fmaf(sv.y, xvv, acc[i4*4+1]);
                acc[i4*4+2] = fmaf(sv.z, xvv, acc[i4*4+2]);
                acc[i4*4+3] = fmaf(sv.w, xvv, acc[i4*4+3]);
            }
        }
        #pragma unroll
        for (int pp = 0; pp < 16; ++pp) nsum += stl[q*16 + pp][c];
    }
    const size_t pbase = ((size_t)h * 64 + blockIdx.x) * 4096;
    #pragma unroll
    for (int i = 0; i < 16; ++i)
        stp[pbase + (size_t)(q*16 + i)*64 + c] = acc[i];
    nacc[q][c] = nsum;
    __syncthreads();
    if (t < 64)
        normp[((size_t)h * 64 + blockIdx.x) * 64 + t] =
            nacc[0][t] + nacc[1][t] + nacc[2][t] + nacc[3][t];
}

// ---------------------------------------------------------------------------
// Per head: reduce partials, normalize, qkv, 64x64 attention, fold into Wout
// ---------------------------------------------------------------------------
__global__ __launch_bounds__(256)
void attn_kernel(const float* __restrict__ stp, const float* __restrict__ normp,
                 const float* __restrict__ Wq, const float* __restrict__ Wk,
                 const float* __restrict__ Wv, const float* __restrict__ Wout,
                 float* __restrict__ Mt) {
    __shared__ float st[64][68];
    __shared__ float ql[64][68];
    __shared__ float kl[64][68];
    __shared__ float vl[64][68];
    __shared__ float sc[64][68];
    __shared__ float nrm[64];
    const int h = blockIdx.x;
    const int t = threadIdx.x;

    for (int e = t; e < 4096; e += 256) {
        float s = 0.f;
        for (int ch = 0; ch < 64; ++ch) s += stp[(((size_t)h*64) + ch)*4096 + e];
        st[e>>6][e&63] = s;
    }
    if (t < 64) {
        float s = 0.f;
        for (int ch = 0; ch < 64; ++ch) s += normp[(((size_t)h*64) + ch)*64 + t];
        nrm[t] = s + 1e-5f;
    }
    __syncthreads();
    for (int e = t; e < 4096; e += 256) st[e>>6][e&63] /= nrm[e>>6];
    __syncthreads();
    for (int e = t; e < 4096; e += 256) {
        int g = e >> 6, dd = e & 63;
        float aq = 0.f, ak = 0.f, av = 0.f;
        for (int cc = 0; cc < 64; ++cc) {
            float sv = st[g][cc];
            aq = fmaf(sv, Wq[dd*64 + cc], aq);
            ak = fmaf(sv, Wk[dd*64 + cc], ak);
            av = fmaf(sv, Wv[dd*64 + cc], av);
        }
        ql[g][dd] = aq; kl[g][dd] = ak; vl[g][dd] = av;
    }
    __syncthreads();
    for (int e = t; e < 4096; e += 256) {
        int g = e >> 6, gp = e & 63;
        float s = 0.f;
        for (int dd = 0; dd < 64; ++dd) s = fmaf(ql[g][dd], kl[gp][dd], s);
        sc[g][gp] = s * 0.125f;
    }
    __syncthreads();
    if (t < 64) {
        float m = -1e30f;
        for (int j = 0; j < 64; ++j) m = fmaxf(m, sc[t][j]);
        float ssum = 0.f;
        for (int j = 0; j < 64; ++j) { float p = expf(sc[t][j] - m); sc[t][j] = p; ssum += p; }
        float inv = 1.f / ssum;
        for (int j = 0; j < 64; ++j) sc[t][j] *= inv;
    }
    __syncthreads();
    for (int e = t; e < 4096; e += 256) {
        int g = e >> 6, dd = e & 63;
        float s = 0.f;
        for (int gp = 0; gp < 64; ++gp) s = fmaf(sc[g][gp], vl[gp][dd], s);
        st[g][dd] = s;
    }
    __syncthreads();
    for (int e = t; e < 16384; e += 256) {
        int i = e >> 6, g = e & 63;
        float s = 0.f;
        for (int dd = 0; dd < 64; ++dd)
            s = fmaf(st[g][dd], Wout[(size_t)i * HDIM + h*64 + dd], s);
        Mt[(size_t)i * HDIM + h*64 + g] = s;
    }
}

// ---------------------------------------------------------------------------
extern "C" void kernel_launch(void* const* d_in, const int* in_sizes, int n_in,
                              void* d_out, int out_size, void* d_ws, size_t ws_size,
                              hipStream_t stream) {
    const float* x    = (const float*)d_in[0];
    const float* Wx   = (const float*)d_in[1];
    const float* bx   = (const float*)d_in[2];
    const float* Wt1  = (const float*)d_in[3];
    const float* bt1  = (const float*)d_in[4];
    const float* Wt2  = (const float*)d_in[5];
    const float* bt2  = (const float*)d_in[6];
    const float* biasp= (const float*)d_in[7];
    const float* Ws   = (const float*)d_in[8];
    const float* bs   = (const float*)d_in[9];
    const float* Wq   = (const float*)d_in[10];
    const float* Wk   = (const float*)d_in[11];
    const float* Wv   = (const float*)d_in[12];
    const float* Wout = (const float*)d_in[13];
    const float* bout = (const float*)d_in[14];
    const float* u    = (const float*)d_in[15];
    float* out = (float*)d_out;

    float* ws    = (float*)d_ws;
    float* xmid  = ws;                                   // 65536*512
    float* sw    = xmid  + (size_t)NPTS * HDIM;          // 65536*512
    float* stp   = sw    + (size_t)NPTS * HDIM;          // 8*64*4096
    float* normp = stp   + (size_t)NH * 64 * 4096;       // 8*64*64
    float* Mt    = normp + (size_t)NH * 64 * 64;         // 256*512

    // 1) x_mid = x @ Wx^T + bx
    gemm_f32<256><<<dim3(512, 4), 256, 0, stream>>>(x, Wx, bx, xmid, 512);
    // 2) fused logits/temp GEMM + gumbel softmax -> sw
    lgt1_fused_kernel<<<dim3(512, 8), 256, 0, stream>>>(xmid, Ws, bs, Wt1, bt1,
                                                        Wt2, bt2, biasp, u, sw);
    // 3) slice token partials
    gather_kernel<<<dim3(64, 8), 256, 0, stream>>>(xmid, sw, stp, normp);
    // 4) tiny attention + fold Wout
    attn_kernel<<<8, 256, 0, stream>>>(stp, normp, Wq, Wk, Wv, Wout, Mt);
    // 5) out = sw_flat @ Mt^T + bout
    gemm_f32<512><<<dim3(512, 2), 256, 0, stream>>>(sw, Mt, bout, out, 256);
}

// Round 3
// 891.932 us; speedup vs baseline: 1.5190x; 1.5190x over previous
//
#include <hip/hip_runtime.h>
#include <math.h>

// Physics_Attention: B=1, N=65536, DIM=256, H=8, D=64, G=64
#define NPTS  65536
#define DIMX  256
#define NH    8
#define HDIM  512   // H*D
// ws layout (floats):
//   xmid  [NPTS][512]            = 33.55M
//   sw    [NPTS][512] (h*64+g)   = 33.55M
//   stp   [H][64ch][64g][64c]    = 2.10M
//   normp [H][64ch][64g]         = 32768
//   Mt    [256][512]             = 131072
// total ~278 MB

__device__ __forceinline__ float gelu_f(float x) {
    return 0.5f * x * (1.0f + erff(x * 0.7071067811865476f));
}

// ---------------------------------------------------------------------------
// C[m][o] = sum_k A[m][k]*B[o][k] + bias[o]; 128x128 tile, 8x8/thread, KC=8
// ---------------------------------------------------------------------------
template<int K>
__global__ __launch_bounds__(256)
void gemm_f32(const float* __restrict__ A, const float* __restrict__ B,
              const float* __restrict__ bias, float* __restrict__ C, int O) {
    __shared__ float As[8][132];
    __shared__ float Bs[8][132];
    const int m0 = blockIdx.x * 128;
    const int o0 = blockIdx.y * 128;
    const int t  = threadIdx.x;
    const int tx = t & 15, ty = t >> 4;
    const int r  = t >> 1, c4 = (t & 1) * 4;
    float acc[8][8];
    #pragma unroll
    for (int i = 0; i < 8; ++i)
        #pragma unroll
        for (int j = 0; j < 8; ++j) acc[i][j] = 0.f;

    const float* Ap = A + (size_t)(m0 + r) * K + c4;
    const float* Bp = B + (size_t)(o0 + r) * K + c4;

    for (int kc = 0; kc < K; kc += 8) {
        float4 av = *(const float4*)(Ap + kc);
        float4 bv = *(const float4*)(Bp + kc);
        __syncthreads();
        As[c4+0][r] = av.x; As[c4+1][r] = av.y; As[c4+2][r] = av.z; As[c4+3][r] = av.w;
        Bs[c4+0][r] = bv.x; Bs[c4+1][r] = bv.y; Bs[c4+2][r] = bv.z; Bs[c4+3][r] = bv.w;
        __syncthreads();
        #pragma unroll
        for (int kk = 0; kk < 8; ++kk) {
            float a_[8], b_[8];
            #pragma unroll
            for (int i = 0; i < 8; ++i) a_[i] = As[kk][ty*8 + i];
            #pragma unroll
            for (int j = 0; j < 8; ++j) b_[j] = Bs[kk][tx*8 + j];
            #pragma unroll
            for (int i = 0; i < 8; ++i)
                #pragma unroll
                for (int j = 0; j < 8; ++j)
                    acc[i][j] = fmaf(a_[i], b_[j], acc[i][j]);
        }
    }
    float bb[8];
    #pragma unroll
    for (int j = 0; j < 8; ++j) bb[j] = bias[o0 + tx*8 + j];
    #pragma unroll
    for (int i = 0; i < 8; ++i) {
        float* cp = C + (size_t)(m0 + ty*8 + i) * O + o0 + tx*8;
        float4 v0 = make_float4(acc[i][0]+bb[0], acc[i][1]+bb[1], acc[i][2]+bb[2], acc[i][3]+bb[3]);
        float4 v1 = make_float4(acc[i][4]+bb[4], acc[i][5]+bb[5], acc[i][6]+bb[6], acc[i][7]+bb[7]);
        *(float4*)cp       = v0;
        *(float4*)(cp + 4) = v1;
    }
}

// ---------------------------------------------------------------------------
// Fused: [lg | t1] = xmid_h @ [Ws; Wt1]^T  (128 pts x 128 out, K=64),
// then temp-MLP + gumbel softmax in registers via 16-lane shuffle groups,
// writing sw directly. Row layout: for point row, lanes tx=0..7 hold the 64
// logits (8 each), lanes tx=8..15 hold the 64 t1 values.
// NOTE: epilogue is FULLY unrolled — runtime-indexing acc[][] would demote
// it to scratch (round-2 lesson: VGPR=56, 2.3 GB scratch writes).
// ---------------------------------------------------------------------------
__global__ __launch_bounds__(256)
void lgt1_fused_kernel(const float* __restrict__ xmid,
                       const float* __restrict__ Ws,  const float* __restrict__ bs,
                       const float* __restrict__ Wt1, const float* __restrict__ bt1,
                       const float* __restrict__ Wt2, const float* __restrict__ bt2,
                       const float* __restrict__ biasp,
                       const float* __restrict__ u,
                       float* __restrict__ sw) {
    __shared__ float As[8][132];
    __shared__ float Bs[8][132];
    const int h  = blockIdx.y;
    const int m0 = blockIdx.x * 128;
    const int t  = threadIdx.x;
    const int tx = t & 15, ty = t >> 4;
    const int r  = t >> 1, c4 = (t & 1) * 4;

    float acc[8][8];
    #pragma unroll
    for (int i = 0; i < 8; ++i)
        #pragma unroll
        for (int j = 0; j < 8; ++j) acc[i][j] = 0.f;

    const float* Ap = xmid + (size_t)(m0 + r) * HDIM + h*64 + c4;
    const float* Bp = (r < 64 ? Ws + (size_t)r * 64 : Wt1 + (size_t)(r - 64) * 64) + c4;

    for (int kc = 0; kc < 64; kc += 8) {
        float4 av = *(const float4*)(Ap + kc);
        float4 bv = *(const float4*)(Bp + kc);
        __syncthreads();
        As[c4+0][r] = av.x; As[c4+1][r] = av.y; As[c4+2][r] = av.z; As[c4+3][r] = av.w;
        Bs[c4+0][r] = bv.x; Bs[c4+1][r] = bv.y; Bs[c4+2][r] = bv.z; Bs[c4+3][r] = bv.w;
        __syncthreads();
        #pragma unroll
        for (int kk = 0; kk < 8; ++kk) {
            float a_[8], b_[8];
            #pragma unroll
            for (int i = 0; i < 8; ++i) a_[i] = As[kk][ty*8 + i];
            #pragma unroll
            for (int j = 0; j < 8; ++j) b_[j] = Bs[kk][tx*8 + j];
            #pragma unroll
            for (int i = 0; i < 8; ++i)
                #pragma unroll
                for (int j = 0; j < 8; ++j)
                    acc[i][j] = fmaf(a_[i], b_[j], acc[i][j]);
        }
    }

    // per-lane constants: g8 = (tx&7)*8 .. +7
    const int g8 = (tx & 7) * 8;
    float bsr[8], bt1r[8], wt2r[8];
    #pragma unroll
    for (int j = 0; j < 8; ++j) {
        bsr[j]  = bs [g8 + j];
        bt1r[j] = bt1[g8 + j];
        wt2r[j] = Wt2[g8 + j];
    }
    const float bt2v   = bt2[0];
    const float biasph = biasp[h];
    const bool  is_lg  = (tx < 8);

    #pragma unroll
    for (int i = 0; i < 8; ++i) {
        const int n = m0 + ty*8 + i;
        // ---- temperature path: t1 lanes (tx>=8) compute sum_g gelu(t1)*Wt2
        float mysum = 0.f;
        if (!is_lg) {
            #pragma unroll
            for (int j = 0; j < 8; ++j)
                mysum += gelu_f(acc[i][j] + bt1r[j]) * wt2r[j];
        }
        // reduce across the 16-lane group (lg lanes contribute 0)
        mysum += __shfl_xor(mysum, 1);
        mysum += __shfl_xor(mysum, 2);
        mysum += __shfl_xor(mysum, 4);
        mysum += __shfl_xor(mysum, 8);
        float temp = gelu_f(mysum + bt2v) + biasph;
        temp = fmaxf(temp, 0.01f);
        const float invt = 1.0f / temp;

        // ---- gumbel softmax: lg lanes (tx<8) own 8 g-values each
        if (is_lg) {
            const float* up = u + ((size_t)h * NPTS + n) * 64 + g8;
            float4 u0 = *(const float4*)up;
            float4 u1 = *(const float4*)(up + 4);
            float uu[8] = {u0.x,u0.y,u0.z,u0.w,u1.x,u1.y,u1.z,u1.w};
            float s[8];
            float mx = -1e30f;
            #pragma unroll
            for (int j = 0; j < 8; ++j) {
                float gn = -logf(-logf(uu[j] + 1e-8f) + 1e-8f);
                s[j] = (acc[i][j] + bsr[j] + gn) * invt;
                mx = fmaxf(mx, s[j]);
            }
            mx = fmaxf(mx, __shfl_xor(mx, 1));
            mx = fmaxf(mx, __shfl_xor(mx, 2));
            mx = fmaxf(mx, __shfl_xor(mx, 4));
            float ps = 0.f;
            #pragma unroll
            for (int j = 0; j < 8; ++j) { s[j] = expf(s[j] - mx); ps += s[j]; }
            ps += __shfl_xor(ps, 1);
            ps += __shfl_xor(ps, 2);
            ps += __shfl_xor(ps, 4);
            const float inv = 1.0f / ps;
            float* sp = sw + ((size_t)n * NH + h) * 64 + g8;
            *(float4*)sp       = make_float4(s[0]*inv, s[1]*inv, s[2]*inv, s[3]*inv);
            *(float4*)(sp + 4) = make_float4(s[4]*inv, s[5]*inv, s[6]*inv, s[7]*inv);
        }
    }
}

// ---------------------------------------------------------------------------
// Per (h, chunk of 1024 pts): partial slice_tokens[g][c] and norm[g]
// ---------------------------------------------------------------------------
__global__ __launch_bounds__(256)
void gather_kernel(const float* __restrict__ xmid, const float* __restrict__ sw,
                   float* __restrict__ stp, float* __restrict__ normp) {
    __shared__ float xt [64][68];
    __shared__ float stl[64][68];
    __shared__ float nacc[4][64];
    const int h  = blockIdx.y;
    const int n0 = blockIdx.x * 1024;
    const int t  = threadIdx.x;
    const int q  = t >> 6, c = t & 63;
    float acc[16];
    #pragma unroll
    for (int i = 0; i < 16; ++i) acc[i] = 0.f;
    float nsum = 0.f;

    for (int tile = 0; tile < 16; ++tile) {
        const int pt = n0 + tile * 64;
        __syncthreads();
        #pragma unroll
        for (int i = 0; i < 4; ++i) {
            int idx = t + i * 256;
            int p = idx >> 4, cc = (idx & 15) * 4;
            *(float4*)&xt [p][cc] = *(const float4*)&xmid[(size_t)(pt + p) * HDIM + h*64 + cc];
            *(float4*)&stl[p][cc] = *(const float4*)&sw [((size_t)(pt + p) * NH + h) * 64 + cc];
        }
        __syncthreads();
        for (int p = 0; p < 64; ++p) {
            float xvv = xt[p][c];
            #pragma unroll
            for (int i4 = 0; i4 < 4; ++i4) {
                float4 sv = *(const float4*)&stl[p][q*16 + i4*4];
                acc[i4*4+0] = fmaf(sv.x, xvv, acc[i4*4+0]);
                acc[i4*4+1] = fmaf(sv.y, xvv, acc[i4*4+1]);
                acc[i4*4+2] = fmaf(sv.z, xvv, acc[i4*4+2]);
                acc[i4*4+3] = fmaf(sv.w, xvv, acc[i4*4+3]);
            }
        }
        #pragma unroll
        for (int pp = 0; pp < 16; ++pp) nsum += stl[q*16 + pp][c];
    }
    const size_t pbase = ((size_t)h * 64 + blockIdx.x) * 4096;
    #pragma unroll
    for (int i = 0; i < 16; ++i)
        stp[pbase + (size_t)(q*16 + i)*64 + c] = acc[i];
    nacc[q][c] = nsum;
    __syncthreads();
    if (t < 64)
        normp[((size_t)h * 64 + blockIdx.x) * 64 + t] =
            nacc[0][t] + nacc[1][t] + nacc[2][t] + nacc[3][t];
}

// ---------------------------------------------------------------------------
// Per head: reduce partials, normalize, qkv, 64x64 attention, fold into Wout
// ---------------------------------------------------------------------------
__global__ __launch_bounds__(256)
void attn_kernel(const float* __restrict__ stp, const float* __restrict__ normp,
                 const float* __restrict__ Wq, const float* __restrict__ Wk,
                 const float* __restrict__ Wv, const float* __restrict__ Wout,
                 float* __restrict__ Mt) {
    __shared__ float st[64][68];
    __shared__ float ql[64][68];
    __shared__ float kl[64][68];
    __shared__ float vl[64][68];
    __shared__ float sc[64][68];
    __shared__ float nrm[64];
    const int h = blockIdx.x;
    const int t = threadIdx.x;

    for (int e = t; e < 4096; e += 256) {
        float s = 0.f;
        for (int ch = 0; ch < 64; ++ch) s += stp[(((size_t)h*64) + ch)*4096 + e];
        st[e>>6][e&63] = s;
    }
    if (t < 64) {
        float s = 0.f;
        for (int ch = 0; ch < 64; ++ch) s += normp[(((size_t)h*64) + ch)*64 + t];
        nrm[t] = s + 1e-5f;
    }
    __syncthreads();
    for (int e = t; e < 4096; e += 256) st[e>>6][e&63] /= nrm[e>>6];
    __syncthreads();
    for (int e = t; e < 4096; e += 256) {
        int g = e >> 6, dd = e & 63;
        float aq = 0.f, ak = 0.f, av = 0.f;
        for (int cc = 0; cc < 64; ++cc) {
            float sv = st[g][cc];
            aq = fmaf(sv, Wq[dd*64 + cc], aq);
            ak = fmaf(sv, Wk[dd*64 + cc], ak);
            av = fmaf(sv, Wv[dd*64 + cc], av);
        }
        ql[g][dd] = aq; kl[g][dd] = ak; vl[g][dd] = av;
    }
    __syncthreads();
    for (int e = t; e < 4096; e += 256) {
        int g = e >> 6, gp = e & 63;
        float s = 0.f;
        for (int dd = 0; dd < 64; ++dd) s = fmaf(ql[g][dd], kl[gp][dd], s);
        sc[g][gp] = s * 0.125f;
    }
    __syncthreads();
    if (t < 64) {
        float m = -1e30f;
        for (int j = 0; j < 64; ++j) m = fmaxf(m, sc[t][j]);
        float ssum = 0.f;
        for (int j = 0; j < 64; ++j) { float p = expf(sc[t][j] - m); sc[t][j] = p; ssum += p; }
        float inv = 1.f / ssum;
        for (int j = 0; j < 64; ++j) sc[t][j] *= inv;
    }
    __syncthreads();
    for (int e = t; e < 4096; e += 256) {
        int g = e >> 6, dd = e & 63;
        float s = 0.f;
        for (int gp = 0; gp < 64; ++gp) s = fmaf(sc[g][gp], vl[gp][dd], s);
        st[g][dd] = s;
    }
    __syncthreads();
    for (int e = t; e < 16384; e += 256) {
        int i = e >> 6, g = e & 63;
        float s = 0.f;
        for (int dd = 0; dd < 64; ++dd)
            s = fmaf(st[g][dd], Wout[(size_t)i * HDIM + h*64 + dd], s);
        Mt[(size_t)i * HDIM + h*64 + g] = s;
    }
}

// ---------------------------------------------------------------------------
extern "C" void kernel_launch(void* const* d_in, const int* in_sizes, int n_in,
                              void* d_out, int out_size, void* d_ws, size_t ws_size,
                              hipStream_t stream) {
    const float* x    = (const float*)d_in[0];
    const float* Wx   = (const float*)d_in[1];
    const float* bx   = (const float*)d_in[2];
    const float* Wt1  = (const float*)d_in[3];
    const float* bt1  = (const float*)d_in[4];
    const float* Wt2  = (const float*)d_in[5];
    const float* bt2  = (const float*)d_in[6];
    const float* biasp= (const float*)d_in[7];
    const float* Ws   = (const float*)d_in[8];
    const float* bs   = (const float*)d_in[9];
    const float* Wq   = (const float*)d_in[10];
    const float* Wk   = (const float*)d_in[11];
    const float* Wv   = (const float*)d_in[12];
    const float* Wout = (const float*)d_in[13];
    const float* bout = (const float*)d_in[14];
    const float* u    = (const float*)d_in[15];
    float* out = (float*)d_out;

    float* ws    = (float*)d_ws;
    float* xmid  = ws;                                   // 65536*512
    float* sw    = xmid  + (size_t)NPTS * HDIM;          // 65536*512
    float* stp   = sw    + (size_t)NPTS * HDIM;          // 8*64*4096
    float* normp = stp   + (size_t)NH * 64 * 4096;       // 8*64*64
    float* Mt    = normp + (size_t)NH * 64 * 64;         // 256*512

    // 1) x_mid = x @ Wx^T + bx
    gemm_f32<256><<<dim3(512, 4), 256, 0, stream>>>(x, Wx, bx, xmid, 512);
    // 2) fused logits/temp GEMM + gumbel softmax -> sw
    lgt1_fused_kernel<<<dim3(512, 8), 256, 0, stream>>>(xmid, Ws, bs, Wt1, bt1,
                                                        Wt2, bt2, biasp, u, sw);
    // 3) slice token partials
    gather_kernel<<<dim3(64, 8), 256, 0, stream>>>(xmid, sw, stp, normp);
    // 4) tiny attention + fold Wout
    attn_kernel<<<8, 256, 0, stream>>>(stp, normp, Wq, Wk, Wv, Wout, Mt);
    // 5) out = sw_flat @ Mt^T + bout
    gemm_f32<512><<<dim3(512, 2), 256, 0, stream>>>(sw, Mt, bout, out, 256);
}

// Round 4
// 435.977 us; speedup vs baseline: 3.1076x; 2.0458x over previous
//
#include <hip/hip_runtime.h>
#include <math.h>

// Physics_Attention: B=1, N=65536, DIM=256, H=8, D=64, G=64
#define NPTS  65536
#define DIMX  256
#define NH    8
#define HDIM  512   // H*D
// ws layout:
//   stp   f32 [H][64ch][64g][64c]   8.39 MB
//   normp f32 [H][64ch][64g]        131 KB
//   Mt    f32 [256][512]            524 KB
//   xmb   bf16[NPTS][512]           67 MB
//   swb   bf16[NPTS][512]           67 MB
// total ~143 MB

typedef __attribute__((ext_vector_type(4))) float f32x4;
typedef __attribute__((ext_vector_type(8))) short short8;
typedef __attribute__((ext_vector_type(8))) unsigned short ushort8;

__device__ __forceinline__ ushort f2bf(float f) {   // RNE f32->bf16
    unsigned x = __float_as_uint(f);
    return (ushort)((x + 0x7fffu + ((x >> 16) & 1u)) >> 16);
}
__device__ __forceinline__ float bf2f(ushort u) {
    return __uint_as_float((unsigned)u << 16);
}
__device__ __forceinline__ float gelu_f(float x) {
    return 0.5f * x * (1.0f + erff(x * 0.7071067811865476f));
}

// ---------------------------------------------------------------------------
// Stage 1: xmb_bf16[M][512] = x_f32[M][256] @ Wx^T + bx   (M=65536)
// 128x128 tile, 4 waves (2x2), 16x16x32 bf16 MFMA, XOR-swizzled LDS.
// ---------------------------------------------------------------------------
__global__ __launch_bounds__(256)
void gemm_xmid_kernel(const float* __restrict__ A, const float* __restrict__ B,
                      const float* __restrict__ bias, ushort* __restrict__ C) {
    __shared__ __align__(16) ushort Al[128][64];
    __shared__ __align__(16) ushort Bl[128][64];
    const int m0 = blockIdx.x * 128, n0 = blockIdx.y * 128;
    const int t = threadIdx.x, l = t & 63, w = t >> 6;
    const int wr = w >> 1, wc = w & 1;
    const int lr = l & 15, lq = l >> 4;

    f32x4 acc[4][4];
    #pragma unroll
    for (int mi = 0; mi < 4; ++mi)
        #pragma unroll
        for (int ni = 0; ni < 4; ++ni) acc[mi][ni] = (f32x4){0.f, 0.f, 0.f, 0.f};

    for (int ks = 0; ks < 4; ++ks) {          // K-step of 64 (K=256)
        __syncthreads();
        #pragma unroll
        for (int i = 0; i < 4; ++i) {
            int idx = i * 256 + t;            // 0..1023
            int row = idx >> 3, g = idx & 7;
            const float* ap = &A[(size_t)(m0 + row) * 256 + ks * 64 + g * 8];
            float4 a0 = *(const float4*)ap;
            float4 a1 = *(const float4*)(ap + 4);
            ushort8 av = { f2bf(a0.x), f2bf(a0.y), f2bf(a0.z), f2bf(a0.w),
                           f2bf(a1.x), f2bf(a1.y), f2bf(a1.z), f2bf(a1.w) };
            *(ushort8*)&Al[row][(g ^ (row & 7)) * 8] = av;
            const float* bp = &B[(size_t)(n0 + row) * 256 + ks * 64 + g * 8];
            float4 b0 = *(const float4*)bp;
            float4 b1 = *(const float4*)(bp + 4);
            ushort8 bv = { f2bf(b0.x), f2bf(b0.y), f2bf(b0.z), f2bf(b0.w),
                           f2bf(b1.x), f2bf(b1.y), f2bf(b1.z), f2bf(b1.w) };
            *(ushort8*)&Bl[row][(g ^ (row & 7)) * 8] = bv;
        }
        __syncthreads();
        #pragma unroll
        for (int kf = 0; kf < 2; ++kf) {
            short8 af[4], bfr[4];
            #pragma unroll
            for (int mi = 0; mi < 4; ++mi) {
                int row = wr * 64 + mi * 16 + lr, g = kf * 4 + lq;
                af[mi] = *(const short8*)&Al[row][(g ^ (row & 7)) * 8];
            }
            #pragma unroll
            for (int ni = 0; ni < 4; ++ni) {
                int row = wc * 64 + ni * 16 + lr, g = kf * 4 + lq;
                bfr[ni] = *(const short8*)&Bl[row][(g ^ (row & 7)) * 8];
            }
            #pragma unroll
            for (int mi = 0; mi < 4; ++mi)
                #pragma unroll
                for (int ni = 0; ni < 4; ++ni)
                    acc[mi][ni] = __builtin_amdgcn_mfma_f32_16x16x32_bf16(
                        af[mi], bfr[ni], acc[mi][ni], 0, 0, 0);
        }
    }
    #pragma unroll
    for (int ni = 0; ni < 4; ++ni) {
        int col = n0 + wc * 64 + ni * 16 + lr;
        float bb = bias[col];
        #pragma unroll
        for (int mi = 0; mi < 4; ++mi)
            #pragma unroll
            for (int j = 0; j < 4; ++j) {
                int row = m0 + wr * 64 + mi * 16 + lq * 4 + j;
                C[(size_t)row * 512 + col] = f2bf(acc[mi][ni][j] + bb);
            }
    }
}

// ---------------------------------------------------------------------------
// Stage 2: per (128-pt tile, head): [lg | t1] = xmb_h @ [Ws;Wt1]^T via MFMA
// (K=64), then temp-MLP + gumbel softmax in-wave, write swb bf16.
// Wave w owns rows w*32..+32 and ALL 128 cols so temp (t1 cols) and softmax
// (lg cols) reduce within the wave's 16-lane groups.
// ---------------------------------------------------------------------------
__global__ __launch_bounds__(256)
void lgt1_mfma_kernel(const ushort* __restrict__ xmb,
                      const float* __restrict__ Ws,  const float* __restrict__ bs,
                      const float* __restrict__ Wt1, const float* __restrict__ bt1,
                      const float* __restrict__ Wt2, const float* __restrict__ bt2,
                      const float* __restrict__ biasp,
                      const float* __restrict__ u,
                      ushort* __restrict__ swb) {
    __shared__ __align__(16) ushort Al[128][64];
    __shared__ __align__(16) ushort Bl[128][64];
    const int h = blockIdx.y, m0 = blockIdx.x * 128;
    const int t = threadIdx.x, l = t & 63, w = t >> 6;
    const int lr = l & 15, lq = l >> 4;

    #pragma unroll
    for (int i = 0; i < 4; ++i) {
        int idx = i * 256 + t;
        int row = idx >> 3, g = idx & 7;
        ushort8 av = *(const ushort8*)&xmb[(size_t)(m0 + row) * 512 + h * 64 + g * 8];
        *(ushort8*)&Al[row][(g ^ (row & 7)) * 8] = av;
        const float* src = (row < 64 ? &Ws[(size_t)row * 64]
                                     : &Wt1[(size_t)(row - 64) * 64]) + g * 8;
        float4 b0 = *(const float4*)src;
        float4 b1 = *(const float4*)(src + 4);
        ushort8 bv = { f2bf(b0.x), f2bf(b0.y), f2bf(b0.z), f2bf(b0.w),
                       f2bf(b1.x), f2bf(b1.y), f2bf(b1.z), f2bf(b1.w) };
        *(ushort8*)&Bl[row][(g ^ (row & 7)) * 8] = bv;
    }
    __syncthreads();

    f32x4 acc[2][8];
    #pragma unroll
    for (int mi = 0; mi < 2; ++mi)
        #pragma unroll
        for (int ni = 0; ni < 8; ++ni) acc[mi][ni] = (f32x4){0.f, 0.f, 0.f, 0.f};

    #pragma unroll
    for (int kf = 0; kf < 2; ++kf) {
        short8 af[2], bfr[8];
        #pragma unroll
        for (int mi = 0; mi < 2; ++mi) {
            int row = w * 32 + mi * 16 + lr, g = kf * 4 + lq;
            af[mi] = *(const short8*)&Al[row][(g ^ (row & 7)) * 8];
        }
        #pragma unroll
        for (int ni = 0; ni < 8; ++ni) {
            int row = ni * 16 + lr, g = kf * 4 + lq;
            bfr[ni] = *(const short8*)&Bl[row][(g ^ (row & 7)) * 8];
        }
        #pragma unroll
        for (int mi = 0; mi < 2; ++mi)
            #pragma unroll
            for (int ni = 0; ni < 8; ++ni)
                acc[mi][ni] = __builtin_amdgcn_mfma_f32_16x16x32_bf16(
                    af[mi], bfr[ni], acc[mi][ni], 0, 0, 0);
    }

    const float bt2v = bt2[0], biasph = biasp[h];
    float bsr[4], bt1r[4], wt2r[4];
    #pragma unroll
    for (int ni = 0; ni < 4; ++ni) {
        bsr[ni]  = bs [ni * 16 + lr];
        bt1r[ni] = bt1[ni * 16 + lr];
        wt2r[ni] = Wt2[ni * 16 + lr];
    }

    #pragma unroll
    for (int mi = 0; mi < 2; ++mi)
        #pragma unroll
        for (int jj = 0; jj < 4; ++jj) {
            const int n = m0 + w * 32 + mi * 16 + lq * 4 + jj;
            // temperature: t1 cols are ni 4..7 (cols 64..127)
            float tsum = 0.f;
            #pragma unroll
            for (int ni = 0; ni < 4; ++ni)
                tsum += gelu_f(acc[mi][ni + 4][jj] + bt1r[ni]) * wt2r[ni];
            tsum += __shfl_xor(tsum, 1);
            tsum += __shfl_xor(tsum, 2);
            tsum += __shfl_xor(tsum, 4);
            tsum += __shfl_xor(tsum, 8);
            float temp = gelu_f(tsum + bt2v) + biasph;
            temp = fmaxf(temp, 0.01f);
            const float invt = 1.0f / temp;

            // gumbel softmax over 64 lg cols (ni 0..3, 16 lanes)
            const float* up = &u[((size_t)h * NPTS + n) * 64 + lr];
            float s[4];
            float mx = -1e30f;
            #pragma unroll
            for (int ni = 0; ni < 4; ++ni) {
                float uu = up[ni * 16];
                float gn = -logf(-logf(uu + 1e-8f) + 1e-8f);
                s[ni] = (acc[mi][ni][jj] + bsr[ni] + gn) * invt;
                mx = fmaxf(mx, s[ni]);
            }
            mx = fmaxf(mx, __shfl_xor(mx, 1));
            mx = fmaxf(mx, __shfl_xor(mx, 2));
            mx = fmaxf(mx, __shfl_xor(mx, 4));
            mx = fmaxf(mx, __shfl_xor(mx, 8));
            float ps = 0.f;
            #pragma unroll
            for (int ni = 0; ni < 4; ++ni) { s[ni] = expf(s[ni] - mx); ps += s[ni]; }
            ps += __shfl_xor(ps, 1);
            ps += __shfl_xor(ps, 2);
            ps += __shfl_xor(ps, 4);
            ps += __shfl_xor(ps, 8);
            const float inv = 1.0f / ps;
            ushort* sp = &swb[(size_t)n * 512 + h * 64 + lr];
            #pragma unroll
            for (int ni = 0; ni < 4; ++ni)
                sp[ni * 16] = f2bf(s[ni] * inv);
        }
}

// ---------------------------------------------------------------------------
// Stage 3: per (h, chunk of 1024 pts): partial slice_tokens[g][c], norm[g]
// (bf16 inputs converted to f32 during LDS staging; math unchanged)
// ---------------------------------------------------------------------------
__global__ __launch_bounds__(256)
void gather_kernel(const ushort* __restrict__ xmb, const ushort* __restrict__ swb,
                   float* __restrict__ stp, float* __restrict__ normp) {
    __shared__ float xt [64][68];
    __shared__ float stl[64][68];
    __shared__ float nacc[4][64];
    const int h  = blockIdx.y;
    const int n0 = blockIdx.x * 1024;
    const int t  = threadIdx.x;
    const int q  = t >> 6, c = t & 63;
    float acc[16];
    #pragma unroll
    for (int i = 0; i < 16; ++i) acc[i] = 0.f;
    float nsum = 0.f;

    for (int tile = 0; tile < 16; ++tile) {
        const int pt = n0 + tile * 64;
        __syncthreads();
        #pragma unroll
        for (int i = 0; i < 2; ++i) {
            int idx = i * 256 + t;            // 0..511
            int p = idx >> 3, cc = (idx & 7) * 8;
            ushort8 xv = *(const ushort8*)&xmb[(size_t)(pt + p) * 512 + h * 64 + cc];
            ushort8 sv = *(const ushort8*)&swb[(size_t)(pt + p) * 512 + h * 64 + cc];
            #pragma unroll
            for (int j = 0; j < 8; ++j) {
                xt [p][cc + j] = bf2f(xv[j]);
                stl[p][cc + j] = bf2f(sv[j]);
            }
        }
        __syncthreads();
        for (int p = 0; p < 64; ++p) {
            float xvv = xt[p][c];
            #pragma unroll
            for (int i4 = 0; i4 < 4; ++i4) {
                float4 sv = *(const float4*)&stl[p][q*16 + i4*4];
                acc[i4*4+0] = fmaf(sv.x, xvv, acc[i4*4+0]);
                acc[i4*4+1] = fmaf(sv.y, xvv, acc[i4*4+1]);
                acc[i4*4+2] = fmaf(sv.z, xvv, acc[i4*4+2]);
                acc[i4*4+3] = fmaf(sv.w, xvv, acc[i4*4+3]);
            }
        }
        #pragma unroll
        for (int pp = 0; pp < 16; ++pp) nsum += stl[q*16 + pp][c];
    }
    const size_t pbase = ((size_t)h * 64 + blockIdx.x) * 4096;
    #pragma unroll
    for (int i = 0; i < 16; ++i)
        stp[pbase + (size_t)(q*16 + i)*64 + c] = acc[i];
    nacc[q][c] = nsum;
    __syncthreads();
    if (t < 64)
        normp[((size_t)h * 64 + blockIdx.x) * 64 + t] =
            nacc[0][t] + nacc[1][t] + nacc[2][t] + nacc[3][t];
}

// ---------------------------------------------------------------------------
// Stage 4: per head: reduce partials, normalize, qkv, 64x64 attention,
// fold out_slice into Wout: Mt[i][h*64+g]
// ---------------------------------------------------------------------------
__global__ __launch_bounds__(256)
void attn_kernel(const float* __restrict__ stp, const float* __restrict__ normp,
                 const float* __restrict__ Wq, const float* __restrict__ Wk,
                 const float* __restrict__ Wv, const float* __restrict__ Wout,
                 float* __restrict__ Mt) {
    __shared__ float st[64][68];
    __shared__ float ql[64][68];
    __shared__ float kl[64][68];
    __shared__ float vl[64][68];
    __shared__ float sc[64][68];
    __shared__ float nrm[64];
    const int h = blockIdx.x;
    const int t = threadIdx.x;

    for (int e = t; e < 4096; e += 256) {
        float s = 0.f;
        for (int ch = 0; ch < 64; ++ch) s += stp[(((size_t)h*64) + ch)*4096 + e];
        st[e>>6][e&63] = s;
    }
    if (t < 64) {
        float s = 0.f;
        for (int ch = 0; ch < 64; ++ch) s += normp[(((size_t)h*64) + ch)*64 + t];
        nrm[t] = s + 1e-5f;
    }
    __syncthreads();
    for (int e = t; e < 4096; e += 256) st[e>>6][e&63] /= nrm[e>>6];
    __syncthreads();
    for (int e = t; e < 4096; e += 256) {
        int g = e >> 6, dd = e & 63;
        float aq = 0.f, ak = 0.f, av = 0.f;
        for (int cc = 0; cc < 64; ++cc) {
            float sv = st[g][cc];
            aq = fmaf(sv, Wq[dd*64 + cc], aq);
            ak = fmaf(sv, Wk[dd*64 + cc], ak);
            av = fmaf(sv, Wv[dd*64 + cc], av);
        }
        ql[g][dd] = aq; kl[g][dd] = ak; vl[g][dd] = av;
    }
    __syncthreads();
    for (int e = t; e < 4096; e += 256) {
        int g = e >> 6, gp = e & 63;
        float s = 0.f;
        for (int dd = 0; dd < 64; ++dd) s = fmaf(ql[g][dd], kl[gp][dd], s);
        sc[g][gp] = s * 0.125f;
    }
    __syncthreads();
    if (t < 64) {
        float m = -1e30f;
        for (int j = 0; j < 64; ++j) m = fmaxf(m, sc[t][j]);
        float ssum = 0.f;
        for (int j = 0; j < 64; ++j) { float p = expf(sc[t][j] - m); sc[t][j] = p; ssum += p; }
        float inv = 1.f / ssum;
        for (int j = 0; j < 64; ++j) sc[t][j] *= inv;
    }
    __syncthreads();
    for (int e = t; e < 4096; e += 256) {
        int g = e >> 6, dd = e & 63;
        float s = 0.f;
        for (int gp = 0; gp < 64; ++gp) s = fmaf(sc[g][gp], vl[gp][dd], s);
        st[g][dd] = s;
    }
    __syncthreads();
    for (int e = t; e < 16384; e += 256) {
        int i = e >> 6, g = e & 63;
        float s = 0.f;
        for (int dd = 0; dd < 64; ++dd)
            s = fmaf(st[g][dd], Wout[(size_t)i * HDIM + h*64 + dd], s);
        Mt[(size_t)i * HDIM + h*64 + g] = s;
    }
}

// ---------------------------------------------------------------------------
// Stage 5: out_f32[M][256] = swb_bf16[M][512] @ Mt^T + bout
// ---------------------------------------------------------------------------
__global__ __launch_bounds__(256)
void gemm_out_kernel(const ushort* __restrict__ A, const float* __restrict__ B,
                     const float* __restrict__ bias, float* __restrict__ C) {
    __shared__ __align__(16) ushort Al[128][64];
    __shared__ __align__(16) ushort Bl[128][64];
    const int m0 = blockIdx.x * 128, n0 = blockIdx.y * 128;
    const int t = threadIdx.x, l = t & 63, w = t >> 6;
    const int wr = w >> 1, wc = w & 1;
    const int lr = l & 15, lq = l >> 4;

    f32x4 acc[4][4];
    #pragma unroll
    for (int mi = 0; mi < 4; ++mi)
        #pragma unroll
        for (int ni = 0; ni < 4; ++ni) acc[mi][ni] = (f32x4){0.f, 0.f, 0.f, 0.f};

    for (int ks = 0; ks < 8; ++ks) {          // K-step of 64 (K=512)
        __syncthreads();
        #pragma unroll
        for (int i = 0; i < 4; ++i) {
            int idx = i * 256 + t;
            int row = idx >> 3, g = idx & 7;
            ushort8 av = *(const ushort8*)&A[(size_t)(m0 + row) * 512 + ks * 64 + g * 8];
            *(ushort8*)&Al[row][(g ^ (row & 7)) * 8] = av;
            const float* bp = &B[(size_t)(n0 + row) * 512 + ks * 64 + g * 8];
            float4 b0 = *(const float4*)bp;
            float4 b1 = *(const float4*)(bp + 4);
            ushort8 bv = { f2bf(b0.x), f2bf(b0.y), f2bf(b0.z), f2bf(b0.w),
                           f2bf(b1.x), f2bf(b1.y), f2bf(b1.z), f2bf(b1.w) };
            *(ushort8*)&Bl[row][(g ^ (row & 7)) * 8] = bv;
        }
        __syncthreads();
        #pragma unroll
        for (int kf = 0; kf < 2; ++kf) {
            short8 af[4], bfr[4];
            #pragma unroll
            for (int mi = 0; mi < 4; ++mi) {
                int row = wr * 64 + mi * 16 + lr, g = kf * 4 + lq;
                af[mi] = *(const short8*)&Al[row][(g ^ (row & 7)) * 8];
            }
            #pragma unroll
            for (int ni = 0; ni < 4; ++ni) {
                int row = wc * 64 + ni * 16 + lr, g = kf * 4 + lq;
                bfr[ni] = *(const short8*)&Bl[row][(g ^ (row & 7)) * 8];
            }
            #pragma unroll
            for (int mi = 0; mi < 4; ++mi)
                #pragma unroll
                for (int ni = 0; ni < 4; ++ni)
                    acc[mi][ni] = __builtin_amdgcn_mfma_f32_16x16x32_bf16(
                        af[mi], bfr[ni], acc[mi][ni], 0, 0, 0);
        }
    }
    #pragma unroll
    for (int ni = 0; ni < 4; ++ni) {
        int col = n0 + wc * 64 + ni * 16 + lr;
        float bb = bias[col];
        #pragma unroll
        for (int mi = 0; mi < 4; ++mi)
            #pragma unroll
            for (int j = 0; j < 4; ++j) {
                int row = m0 + wr * 64 + mi * 16 + lq * 4 + j;
                C[(size_t)row * 256 + col] = acc[mi][ni][j] + bb;
            }
    }
}

// ---------------------------------------------------------------------------
extern "C" void kernel_launch(void* const* d_in, const int* in_sizes, int n_in,
                              void* d_out, int out_size, void* d_ws, size_t ws_size,
                              hipStream_t stream) {
    const float* x    = (const float*)d_in[0];
    const float* Wx   = (const float*)d_in[1];
    const float* bx   = (const float*)d_in[2];
    const float* Wt1  = (const float*)d_in[3];
    const float* bt1  = (const float*)d_in[4];
    const float* Wt2  = (const float*)d_in[5];
    const float* bt2  = (const float*)d_in[6];
    const float* biasp= (const float*)d_in[7];
    const float* Ws   = (const float*)d_in[8];
    const float* bs   = (const float*)d_in[9];
    const float* Wq   = (const float*)d_in[10];
    const float* Wk   = (const float*)d_in[11];
    const float* Wv   = (const float*)d_in[12];
    const float* Wout = (const float*)d_in[13];
    const float* bout = (const float*)d_in[14];
    const float* u    = (const float*)d_in[15];
    float* out = (float*)d_out;

    float*  stp   = (float*)d_ws;                          // 8*64*4096 f32
    float*  normp = stp + (size_t)NH * 64 * 4096;          // 8*64*64
    float*  Mt    = normp + (size_t)NH * 64 * 64;          // 256*512
    ushort* xmb   = (ushort*)(Mt + (size_t)DIMX * HDIM);   // 65536*512 bf16
    ushort* swb   = xmb + (size_t)NPTS * HDIM;             // 65536*512 bf16

    // 1) xmid (bf16) = x @ Wx^T + bx
    gemm_xmid_kernel<<<dim3(512, 4), 256, 0, stream>>>(x, Wx, bx, xmb);
    // 2) fused logits/temp MFMA GEMM + gumbel softmax -> sw (bf16)
    lgt1_mfma_kernel<<<dim3(512, 8), 256, 0, stream>>>(xmb, Ws, bs, Wt1, bt1,
                                                       Wt2, bt2, biasp, u, swb);
    // 3) slice token partials
    gather_kernel<<<dim3(64, 8), 256, 0, stream>>>(xmb, swb, stp, normp);
    // 4) tiny attention + fold Wout
    attn_kernel<<<8, 256, 0, stream>>>(stp, normp, Wq, Wk, Wv, Wout, Mt);
    // 5) out = sw @ Mt^T + bout
    gemm_out_kernel<<<dim3(512, 2), 256, 0, stream>>>(swb, Mt, bout, out);
}

// Round 5
// 376.131 us; speedup vs baseline: 3.6020x; 1.1591x over previous
//
#include <hip/hip_runtime.h>
#include <math.h>

// Physics_Attention: B=1, N=65536, DIM=256, H=8, D=64, G=64
#define NPTS  65536
#define DIMX  256
#define NH    8
#define HDIM  512   // H*D
// ws layout:
//   stp    f32 [H][64ch][64g][64c]  8.39 MB
//   normp  f32 [H][64ch][64g]       131 KB
//   Mt     f32 [256][512]           524 KB
//   st_red f32 [H][64g][64c]        131 KB
//   nrm    f32 [H][64]              2 KB
//   osl    f32 [H][64g][64d]        131 KB
//   xmb    bf16[NPTS][512]          67 MB
//   swb    bf16[NPTS][512]          67 MB

typedef __attribute__((ext_vector_type(4))) float f32x4;
typedef __attribute__((ext_vector_type(8))) short short8;
typedef __attribute__((ext_vector_type(8))) unsigned short ushort8;

__device__ __forceinline__ ushort f2bf(float f) {   // RNE f32->bf16
    unsigned x = __float_as_uint(f);
    return (ushort)((x + 0x7fffu + ((x >> 16) & 1u)) >> 16);
}
__device__ __forceinline__ float bf2f(ushort u) {
    return __uint_as_float((unsigned)u << 16);
}
__device__ __forceinline__ float gelu_f(float x) {
    return 0.5f * x * (1.0f + erff(x * 0.7071067811865476f));
}

// ---------------------------------------------------------------------------
// Stage 1: xmb_bf16[M][512] = x_f32[M][256] @ Wx^T + bx   (M=65536)
// ---------------------------------------------------------------------------
__global__ __launch_bounds__(256)
void gemm_xmid_kernel(const float* __restrict__ A, const float* __restrict__ B,
                      const float* __restrict__ bias, ushort* __restrict__ C) {
    __shared__ __align__(16) ushort Al[128][64];
    __shared__ __align__(16) ushort Bl[128][64];
    const int m0 = blockIdx.x * 128, n0 = blockIdx.y * 128;
    const int t = threadIdx.x, l = t & 63, w = t >> 6;
    const int wr = w >> 1, wc = w & 1;
    const int lr = l & 15, lq = l >> 4;

    f32x4 acc[4][4];
    #pragma unroll
    for (int mi = 0; mi < 4; ++mi)
        #pragma unroll
        for (int ni = 0; ni < 4; ++ni) acc[mi][ni] = (f32x4){0.f, 0.f, 0.f, 0.f};

    for (int ks = 0; ks < 4; ++ks) {          // K-step of 64 (K=256)
        __syncthreads();
        #pragma unroll
        for (int i = 0; i < 4; ++i) {
            int idx = i * 256 + t;            // 0..1023
            int row = idx >> 3, g = idx & 7;
            const float* ap = &A[(size_t)(m0 + row) * 256 + ks * 64 + g * 8];
            float4 a0 = *(const float4*)ap;
            float4 a1 = *(const float4*)(ap + 4);
            ushort8 av = { f2bf(a0.x), f2bf(a0.y), f2bf(a0.z), f2bf(a0.w),
                           f2bf(a1.x), f2bf(a1.y), f2bf(a1.z), f2bf(a1.w) };
            *(ushort8*)&Al[row][(g ^ (row & 7)) * 8] = av;
            const float* bp = &B[(size_t)(n0 + row) * 256 + ks * 64 + g * 8];
            float4 b0 = *(const float4*)bp;
            float4 b1 = *(const float4*)(bp + 4);
            ushort8 bv = { f2bf(b0.x), f2bf(b0.y), f2bf(b0.z), f2bf(b0.w),
                           f2bf(b1.x), f2bf(b1.y), f2bf(b1.z), f2bf(b1.w) };
            *(ushort8*)&Bl[row][(g ^ (row & 7)) * 8] = bv;
        }
        __syncthreads();
        #pragma unroll
        for (int kf = 0; kf < 2; ++kf) {
            short8 af[4], bfr[4];
            #pragma unroll
            for (int mi = 0; mi < 4; ++mi) {
                int row = wr * 64 + mi * 16 + lr, g = kf * 4 + lq;
                af[mi] = *(const short8*)&Al[row][(g ^ (row & 7)) * 8];
            }
            #pragma unroll
            for (int ni = 0; ni < 4; ++ni) {
                int row = wc * 64 + ni * 16 + lr, g = kf * 4 + lq;
                bfr[ni] = *(const short8*)&Bl[row][(g ^ (row & 7)) * 8];
            }
            #pragma unroll
            for (int mi = 0; mi < 4; ++mi)
                #pragma unroll
                for (int ni = 0; ni < 4; ++ni)
                    acc[mi][ni] = __builtin_amdgcn_mfma_f32_16x16x32_bf16(
                        af[mi], bfr[ni], acc[mi][ni], 0, 0, 0);
        }
    }
    #pragma unroll
    for (int ni = 0; ni < 4; ++ni) {
        int col = n0 + wc * 64 + ni * 16 + lr;
        float bb = bias[col];
        #pragma unroll
        for (int mi = 0; mi < 4; ++mi)
            #pragma unroll
            for (int j = 0; j < 4; ++j) {
                int row = m0 + wr * 64 + mi * 16 + lq * 4 + j;
                C[(size_t)row * 512 + col] = f2bf(acc[mi][ni][j] + bb);
            }
    }
}

// ---------------------------------------------------------------------------
// Stage 2: per (128-pt tile, head): [lg | t1] = xmb_h @ [Ws;Wt1]^T via MFMA,
// then temp-MLP + gumbel softmax in-wave (HW transcendentals), write swb.
// ---------------------------------------------------------------------------
__global__ __launch_bounds__(256)
void lgt1_mfma_kernel(const ushort* __restrict__ xmb,
                      const float* __restrict__ Ws,  const float* __restrict__ bs,
                      const float* __restrict__ Wt1, const float* __restrict__ bt1,
                      const float* __restrict__ Wt2, const float* __restrict__ bt2,
                      const float* __restrict__ biasp,
                      const float* __restrict__ u,
                      ushort* __restrict__ swb) {
    __shared__ __align__(16) ushort Al[128][64];
    __shared__ __align__(16) ushort Bl[128][64];
    const int h = blockIdx.y, m0 = blockIdx.x * 128;
    const int t = threadIdx.x, l = t & 63, w = t >> 6;
    const int lr = l & 15, lq = l >> 4;

    #pragma unroll
    for (int i = 0; i < 4; ++i) {
        int idx = i * 256 + t;
        int row = idx >> 3, g = idx & 7;
        ushort8 av = *(const ushort8*)&xmb[(size_t)(m0 + row) * 512 + h * 64 + g * 8];
        *(ushort8*)&Al[row][(g ^ (row & 7)) * 8] = av;
        const float* src = (row < 64 ? &Ws[(size_t)row * 64]
                                     : &Wt1[(size_t)(row - 64) * 64]) + g * 8;
        float4 b0 = *(const float4*)src;
        float4 b1 = *(const float4*)(src + 4);
        ushort8 bv = { f2bf(b0.x), f2bf(b0.y), f2bf(b0.z), f2bf(b0.w),
                       f2bf(b1.x), f2bf(b1.y), f2bf(b1.z), f2bf(b1.w) };
        *(ushort8*)&Bl[row][(g ^ (row & 7)) * 8] = bv;
    }
    __syncthreads();

    f32x4 acc[2][8];
    #pragma unroll
    for (int mi = 0; mi < 2; ++mi)
        #pragma unroll
        for (int ni = 0; ni < 8; ++ni) acc[mi][ni] = (f32x4){0.f, 0.f, 0.f, 0.f};

    #pragma unroll
    for (int kf = 0; kf < 2; ++kf) {
        short8 af[2], bfr[8];
        #pragma unroll
        for (int mi = 0; mi < 2; ++mi) {
            int row = w * 32 + mi * 16 + lr, g = kf * 4 + lq;
            af[mi] = *(const short8*)&Al[row][(g ^ (row & 7)) * 8];
        }
        #pragma unroll
        for (int ni = 0; ni < 8; ++ni) {
            int row = ni * 16 + lr, g = kf * 4 + lq;
            bfr[ni] = *(const short8*)&Bl[row][(g ^ (row & 7)) * 8];
        }
        #pragma unroll
        for (int mi = 0; mi < 2; ++mi)
            #pragma unroll
            for (int ni = 0; ni < 8; ++ni)
                acc[mi][ni] = __builtin_amdgcn_mfma_f32_16x16x32_bf16(
                    af[mi], bfr[ni], acc[mi][ni], 0, 0, 0);
    }

    const float bt2v = bt2[0], biasph = biasp[h];
    float bsr[4], bt1r[4], wt2r[4];
    #pragma unroll
    for (int ni = 0; ni < 4; ++ni) {
        bsr[ni]  = bs [ni * 16 + lr];
        bt1r[ni] = bt1[ni * 16 + lr];
        wt2r[ni] = Wt2[ni * 16 + lr];
    }

    #pragma unroll
    for (int mi = 0; mi < 2; ++mi)
        #pragma unroll
        for (int jj = 0; jj < 4; ++jj) {
            const int n = m0 + w * 32 + mi * 16 + lq * 4 + jj;
            // temperature: t1 cols are ni 4..7 (cols 64..127)
            float tsum = 0.f;
            #pragma unroll
            for (int ni = 0; ni < 4; ++ni)
                tsum += gelu_f(acc[mi][ni + 4][jj] + bt1r[ni]) * wt2r[ni];
            tsum += __shfl_xor(tsum, 1);
            tsum += __shfl_xor(tsum, 2);
            tsum += __shfl_xor(tsum, 4);
            tsum += __shfl_xor(tsum, 8);
            float temp = gelu_f(tsum + bt2v) + biasph;
            temp = fmaxf(temp, 0.01f);
            const float invt = 1.0f / temp;

            // gumbel softmax over 64 lg cols (ni 0..3, 16 lanes)
            const float* up = &u[((size_t)h * NPTS + n) * 64 + lr];
            float s[4];
            float mx = -1e30f;
            #pragma unroll
            for (int ni = 0; ni < 4; ++ni) {
                float uu = up[ni * 16];
                float gn = -__logf(-__logf(uu + 1e-8f) + 1e-8f);
                s[ni] = (acc[mi][ni][jj] + bsr[ni] + gn) * invt;
                mx = fmaxf(mx, s[ni]);
            }
            mx = fmaxf(mx, __shfl_xor(mx, 1));
            mx = fmaxf(mx, __shfl_xor(mx, 2));
            mx = fmaxf(mx, __shfl_xor(mx, 4));
            mx = fmaxf(mx, __shfl_xor(mx, 8));
            float ps = 0.f;
            #pragma unroll
            for (int ni = 0; ni < 4; ++ni) { s[ni] = __expf(s[ni] - mx); ps += s[ni]; }
            ps += __shfl_xor(ps, 1);
            ps += __shfl_xor(ps, 2);
            ps += __shfl_xor(ps, 4);
            ps += __shfl_xor(ps, 8);
            const float inv = 1.0f / ps;
            ushort* sp = &swb[(size_t)n * 512 + h * 64 + lr];
            #pragma unroll
            for (int ni = 0; ni < 4; ++ni)
                sp[ni * 16] = f2bf(s[ni] * inv);
        }
}

// ---------------------------------------------------------------------------
// Stage 3: per (h, chunk of 1024 pts): partial slice_tokens[g][c], norm[g]
// ---------------------------------------------------------------------------
__global__ __launch_bounds__(256)
void gather_kernel(const ushort* __restrict__ xmb, const ushort* __restrict__ swb,
                   float* __restrict__ stp, float* __restrict__ normp) {
    __shared__ float xt [64][68];
    __shared__ float stl[64][68];
    __shared__ float nacc[4][64];
    const int h  = blockIdx.y;
    const int n0 = blockIdx.x * 1024;
    const int t  = threadIdx.x;
    const int q  = t >> 6, c = t & 63;
    float acc[16];
    #pragma unroll
    for (int i = 0; i < 16; ++i) acc[i] = 0.f;
    float nsum = 0.f;

    for (int tile = 0; tile < 16; ++tile) {
        const int pt = n0 + tile * 64;
        __syncthreads();
        #pragma unroll
        for (int i = 0; i < 2; ++i) {
            int idx = i * 256 + t;            // 0..511
            int p = idx >> 3, cc = (idx & 7) * 8;
            ushort8 xv = *(const ushort8*)&xmb[(size_t)(pt + p) * 512 + h * 64 + cc];
            ushort8 sv = *(const ushort8*)&swb[(size_t)(pt + p) * 512 + h * 64 + cc];
            #pragma unroll
            for (int j = 0; j < 8; ++j) {
                xt [p][cc + j] = bf2f(xv[j]);
                stl[p][cc + j] = bf2f(sv[j]);
            }
        }
        __syncthreads();
        for (int p = 0; p < 64; ++p) {
            float xvv = xt[p][c];
            #pragma unroll
            for (int i4 = 0; i4 < 4; ++i4) {
                float4 sv = *(const float4*)&stl[p][q*16 + i4*4];
                acc[i4*4+0] = fmaf(sv.x, xvv, acc[i4*4+0]);
                acc[i4*4+1] = fmaf(sv.y, xvv, acc[i4*4+1]);
                acc[i4*4+2] = fmaf(sv.z, xvv, acc[i4*4+2]);
                acc[i4*4+3] = fmaf(sv.w, xvv, acc[i4*4+3]);
            }
        }
        #pragma unroll
        for (int pp = 0; pp < 16; ++pp) nsum += stl[q*16 + pp][c];
    }
    const size_t pbase = ((size_t)h * 64 + blockIdx.x) * 4096;
    #pragma unroll
    for (int i = 0; i < 16; ++i)
        stp[pbase + (size_t)(q*16 + i)*64 + c] = acc[i];
    nacc[q][c] = nsum;
    __syncthreads();
    if (t < 64)
        normp[((size_t)h * 64 + blockIdx.x) * 64 + t] =
            nacc[0][t] + nacc[1][t] + nacc[2][t] + nacc[3][t];
}

// ---------------------------------------------------------------------------
// Stage 4a: parallel reduction of chunk partials -> st_red, nrm
// grid (8 heads, 16); each thread reduces one (g,c) over 64 chunks.
// ---------------------------------------------------------------------------
__global__ __launch_bounds__(256)
void reduce_st_kernel(const float* __restrict__ stp, const float* __restrict__ normp,
                      float* __restrict__ st_red, float* __restrict__ nrm) {
    const int h = blockIdx.x;
    const int e = blockIdx.y * 256 + threadIdx.x;   // 0..4095
    float s = 0.f;
    #pragma unroll 8
    for (int ch = 0; ch < 64; ++ch)
        s += stp[((size_t)h * 64 + ch) * 4096 + e];
    st_red[(size_t)h * 4096 + e] = s;
    if (blockIdx.y == 0 && threadIdx.x < 64) {
        float ns = 0.f;
        #pragma unroll 8
        for (int ch = 0; ch < 64; ++ch)
            ns += normp[((size_t)h * 64 + ch) * 64 + threadIdx.x];
        nrm[h * 64 + threadIdx.x] = ns + 1e-5f;
    }
}

// ---------------------------------------------------------------------------
// Stage 4b: per head: normalize tokens, qkv, 64x64 attention -> osl
// ---------------------------------------------------------------------------
__global__ __launch_bounds__(256)
void attn_small_kernel(const float* __restrict__ st_red, const float* __restrict__ nrm,
                       const float* __restrict__ Wq, const float* __restrict__ Wk,
                       const float* __restrict__ Wv, float* __restrict__ osl) {
    __shared__ float st[64][68];
    __shared__ float ql[64][68];
    __shared__ float kl[64][68];
    __shared__ float vl[64][68];
    __shared__ float sc[64][68];
    __shared__ float nl[64];
    const int h = blockIdx.x;
    const int t = threadIdx.x;

    if (t < 64) nl[t] = nrm[h * 64 + t];
    __syncthreads();
    for (int e = t; e < 4096; e += 256)
        st[e>>6][e&63] = st_red[(size_t)h * 4096 + e] / nl[e>>6];
    __syncthreads();
    for (int e = t; e < 4096; e += 256) {
        int g = e >> 6, dd = e & 63;
        float aq = 0.f, ak = 0.f, av = 0.f;
        for (int cc = 0; cc < 64; ++cc) {
            float sv = st[g][cc];
            aq = fmaf(sv, Wq[dd*64 + cc], aq);
            ak = fmaf(sv, Wk[dd*64 + cc], ak);
            av = fmaf(sv, Wv[dd*64 + cc], av);
        }
        ql[g][dd] = aq; kl[g][dd] = ak; vl[g][dd] = av;
    }
    __syncthreads();
    for (int e = t; e < 4096; e += 256) {
        int g = e >> 6, gp = e & 63;
        float s = 0.f;
        for (int dd = 0; dd < 64; ++dd) s = fmaf(ql[g][dd], kl[gp][dd], s);
        sc[g][gp] = s * 0.125f;
    }
    __syncthreads();
    if (t < 64) {
        float m = -1e30f;
        for (int j = 0; j < 64; ++j) m = fmaxf(m, sc[t][j]);
        float ssum = 0.f;
        for (int j = 0; j < 64; ++j) { float p = expf(sc[t][j] - m); sc[t][j] = p; ssum += p; }
        float inv = 1.f / ssum;
        for (int j = 0; j < 64; ++j) sc[t][j] *= inv;
    }
    __syncthreads();
    for (int e = t; e < 4096; e += 256) {
        int g = e >> 6, dd = e & 63;
        float s = 0.f;
        for (int gp = 0; gp < 64; ++gp) s = fmaf(sc[g][gp], vl[gp][dd], s);
        osl[(size_t)h * 4096 + e] = s;
    }
}

// ---------------------------------------------------------------------------
// Stage 4c: fold out_slice into Wout: Mt[i][h*64+g] = sum_d osl[h][g][d]*Wout[i][h*64+d]
// grid (8 heads, 2 i-halves of 128)
// ---------------------------------------------------------------------------
__global__ __launch_bounds__(256)
void fold_kernel(const float* __restrict__ osl, const float* __restrict__ Wout,
                 float* __restrict__ Mt) {
    __shared__ float os[64][65];
    __shared__ float wl[128][65];
    const int h  = blockIdx.x;
    const int i0 = blockIdx.y * 128;
    const int t  = threadIdx.x;
    for (int e = t; e < 4096; e += 256) os[e>>6][e&63] = osl[(size_t)h * 4096 + e];
    for (int e = t; e < 8192; e += 256) {
        int i = e >> 6, d = e & 63;
        wl[i][d] = Wout[(size_t)(i0 + i) * HDIM + h * 64 + d];
    }
    __syncthreads();
    const int g = t & 63, iq = t >> 6;
    #pragma unroll 4
    for (int k = 0; k < 32; ++k) {
        int i = iq * 32 + k;
        float s = 0.f;
        #pragma unroll
        for (int d = 0; d < 64; ++d) s = fmaf(os[g][d], wl[i][d], s);
        Mt[(size_t)(i0 + i) * HDIM + h * 64 + g] = s;
    }
}

// ---------------------------------------------------------------------------
// Stage 5: out_f32[M][256] = swb_bf16[M][512] @ Mt^T + bout
// ---------------------------------------------------------------------------
__global__ __launch_bounds__(256)
void gemm_out_kernel(const ushort* __restrict__ A, const float* __restrict__ B,
                     const float* __restrict__ bias, float* __restrict__ C) {
    __shared__ __align__(16) ushort Al[128][64];
    __shared__ __align__(16) ushort Bl[128][64];
    const int m0 = blockIdx.x * 128, n0 = blockIdx.y * 128;
    const int t = threadIdx.x, l = t & 63, w = t >> 6;
    const int wr = w >> 1, wc = w & 1;
    const int lr = l & 15, lq = l >> 4;

    f32x4 acc[4][4];
    #pragma unroll
    for (int mi = 0; mi < 4; ++mi)
        #pragma unroll
        for (int ni = 0; ni < 4; ++ni) acc[mi][ni] = (f32x4){0.f, 0.f, 0.f, 0.f};

    for (int ks = 0; ks < 8; ++ks) {          // K-step of 64 (K=512)
        __syncthreads();
        #pragma unroll
        for (int i = 0; i < 4; ++i) {
            int idx = i * 256 + t;
            int row = idx >> 3, g = idx & 7;
            ushort8 av = *(const ushort8*)&A[(size_t)(m0 + row) * 512 + ks * 64 + g * 8];
            *(ushort8*)&Al[row][(g ^ (row & 7)) * 8] = av;
            const float* bp = &B[(size_t)(n0 + row) * 512 + ks * 64 + g * 8];
            float4 b0 = *(const float4*)bp;
            float4 b1 = *(const float4*)(bp + 4);
            ushort8 bv = { f2bf(b0.x), f2bf(b0.y), f2bf(b0.z), f2bf(b0.w),
                           f2bf(b1.x), f2bf(b1.y), f2bf(b1.z), f2bf(b1.w) };
            *(ushort8*)&Bl[row][(g ^ (row & 7)) * 8] = bv;
        }
        __syncthreads();
        #pragma unroll
        for (int kf = 0; kf < 2; ++kf) {
            short8 af[4], bfr[4];
            #pragma unroll
            for (int mi = 0; mi < 4; ++mi) {
                int row = wr * 64 + mi * 16 + lr, g = kf * 4 + lq;
                af[mi] = *(const short8*)&Al[row][(g ^ (row & 7)) * 8];
            }
            #pragma unroll
            for (int ni = 0; ni < 4; ++ni) {
                int row = wc * 64 + ni * 16 + lr, g = kf * 4 + lq;
                bfr[ni] = *(const short8*)&Bl[row][(g ^ (row & 7)) * 8];
            }
            #pragma unroll
            for (int mi = 0; mi < 4; ++mi)
                #pragma unroll
                for (int ni = 0; ni < 4; ++ni)
                    acc[mi][ni] = __builtin_amdgcn_mfma_f32_16x16x32_bf16(
                        af[mi], bfr[ni], acc[mi][ni], 0, 0, 0);
        }
    }
    #pragma unroll
    for (int ni = 0; ni < 4; ++ni) {
        int col = n0 + wc * 64 + ni * 16 + lr;
        float bb = bias[col];
        #pragma unroll
        for (int mi = 0; mi < 4; ++mi)
            #pragma unroll
            for (int j = 0; j < 4; ++j) {
                int row = m0 + wr * 64 + mi * 16 + lq * 4 + j;
                C[(size_t)row * 256 + col] = acc[mi][ni][j] + bb;
            }
    }
}

// ---------------------------------------------------------------------------
extern "C" void kernel_launch(void* const* d_in, const int* in_sizes, int n_in,
                              void* d_out, int out_size, void* d_ws, size_t ws_size,
                              hipStream_t stream) {
    const float* x    = (const float*)d_in[0];
    const float* Wx   = (const float*)d_in[1];
    const float* bx   = (const float*)d_in[2];
    const float* Wt1  = (const float*)d_in[3];
    const float* bt1  = (const float*)d_in[4];
    const float* Wt2  = (const float*)d_in[5];
    const float* bt2  = (const float*)d_in[6];
    const float* biasp= (const float*)d_in[7];
    const float* Ws   = (const float*)d_in[8];
    const float* bs   = (const float*)d_in[9];
    const float* Wq   = (const float*)d_in[10];
    const float* Wk   = (const float*)d_in[11];
    const float* Wv   = (const float*)d_in[12];
    const float* Wout = (const float*)d_in[13];
    const float* bout = (const float*)d_in[14];
    const float* u    = (const float*)d_in[15];
    float* out = (float*)d_out;

    float*  stp    = (float*)d_ws;                           // 8*64*4096 f32
    float*  normp  = stp    + (size_t)NH * 64 * 4096;        // 8*64*64
    float*  Mt     = normp  + (size_t)NH * 64 * 64;          // 256*512
    float*  st_red = Mt     + (size_t)DIMX * HDIM;           // 8*4096
    float*  nrm    = st_red + (size_t)NH * 4096;             // 8*64
    float*  osl    = nrm    + (size_t)NH * 64;               // 8*4096
    ushort* xmb    = (ushort*)(osl + (size_t)NH * 4096);     // 65536*512 bf16
    ushort* swb    = xmb + (size_t)NPTS * HDIM;              // 65536*512 bf16

    // 1) xmid (bf16) = x @ Wx^T + bx
    gemm_xmid_kernel<<<dim3(512, 4), 256, 0, stream>>>(x, Wx, bx, xmb);
    // 2) fused logits/temp MFMA GEMM + gumbel softmax -> sw (bf16)
    lgt1_mfma_kernel<<<dim3(512, 8), 256, 0, stream>>>(xmb, Ws, bs, Wt1, bt1,
                                                       Wt2, bt2, biasp, u, swb);
    // 3) slice token partials
    gather_kernel<<<dim3(64, 8), 256, 0, stream>>>(xmb, swb, stp, normp);
    // 4a) reduce partials (parallel)
    reduce_st_kernel<<<dim3(8, 16), 256, 0, stream>>>(stp, normp, st_red, nrm);
    // 4b) tiny attention
    attn_small_kernel<<<8, 256, 0, stream>>>(st_red, nrm, Wq, Wk, Wv, osl);
    // 4c) fold out_slice into Wout
    fold_kernel<<<dim3(8, 2), 256, 0, stream>>>(osl, Wout, Mt);
    // 5) out = sw @ Mt^T + bout
    gemm_out_kernel<<<dim3(512, 2), 256, 0, stream>>>(swb, Mt, bout, out);
}

// Round 6
// 350.662 us; speedup vs baseline: 3.8636x; 1.0726x over previous
//
#include <hip/hip_runtime.h>
#include <math.h>

// Physics_Attention: B=1, N=65536, DIM=256, H=8, D=64, G=64
#define NPTS  65536
#define DIMX  256
#define NH    8
#define HDIM  512   // H*D

typedef __attribute__((ext_vector_type(4))) float f32x4;
typedef __attribute__((ext_vector_type(8))) short short8;
typedef __attribute__((ext_vector_type(8))) unsigned short ushort8;

__device__ __forceinline__ ushort f2bf(float f) {   // RNE f32->bf16
    unsigned x = __float_as_uint(f);
    return (ushort)((x + 0x7fffu + ((x >> 16) & 1u)) >> 16);
}
__device__ __forceinline__ float bf2f(ushort u) {
    return __uint_as_float((unsigned)u << 16);
}
__device__ __forceinline__ float gelu_f(float x) {   // exact (small kernels only)
    return 0.5f * x * (1.0f + erff(x * 0.7071067811865476f));
}
// Fast erf (A&S 7.1.26, abs err 1.5e-7) — no branches, HW exp/rcp
__device__ __forceinline__ float erf_fast(float x) {
    float ax = fabsf(x);
    float t  = __builtin_amdgcn_rcpf(1.0f + 0.3275911f * ax);
    float p  = fmaf(fmaf(fmaf(fmaf(1.061405429f, t, -1.453152027f), t,
                   1.421413741f), t, -0.284496736f), t, 0.254829592f) * t;
    float y  = 1.0f - p * __expf(-ax * ax);
    return copysignf(y, x);
}
__device__ __forceinline__ float gelu_fast(float x) {
    return 0.5f * x * (1.0f + erf_fast(x * 0.7071067811865476f));
}

// ---------------------------------------------------------------------------
// Stage 1: xmb_bf16[M][512] = x_f32[M][256] @ Wx^T + bx   (M=65536)
// ---------------------------------------------------------------------------
__global__ __launch_bounds__(256)
void gemm_xmid_kernel(const float* __restrict__ A, const float* __restrict__ B,
                      const float* __restrict__ bias, ushort* __restrict__ C) {
    __shared__ __align__(16) ushort Al[128][64];
    __shared__ __align__(16) ushort Bl[128][64];
    const int m0 = blockIdx.x * 128, n0 = blockIdx.y * 128;
    const int t = threadIdx.x, l = t & 63, w = t >> 6;
    const int wr = w >> 1, wc = w & 1;
    const int lr = l & 15, lq = l >> 4;

    f32x4 acc[4][4];
    #pragma unroll
    for (int mi = 0; mi < 4; ++mi)
        #pragma unroll
        for (int ni = 0; ni < 4; ++ni) acc[mi][ni] = (f32x4){0.f, 0.f, 0.f, 0.f};

    for (int ks = 0; ks < 4; ++ks) {          // K-step of 64 (K=256)
        __syncthreads();
        #pragma unroll
        for (int i = 0; i < 4; ++i) {
            int idx = i * 256 + t;            // 0..1023
            int row = idx >> 3, g = idx & 7;
            const float* ap = &A[(size_t)(m0 + row) * 256 + ks * 64 + g * 8];
            float4 a0 = *(const float4*)ap;
            float4 a1 = *(const float4*)(ap + 4);
            ushort8 av = { f2bf(a0.x), f2bf(a0.y), f2bf(a0.z), f2bf(a0.w),
                           f2bf(a1.x), f2bf(a1.y), f2bf(a1.z), f2bf(a1.w) };
            *(ushort8*)&Al[row][(g ^ (row & 7)) * 8] = av;
            const float* bp = &B[(size_t)(n0 + row) * 256 + ks * 64 + g * 8];
            float4 b0 = *(const float4*)bp;
            float4 b1 = *(const float4*)(bp + 4);
            ushort8 bv = { f2bf(b0.x), f2bf(b0.y), f2bf(b0.z), f2bf(b0.w),
                           f2bf(b1.x), f2bf(b1.y), f2bf(b1.z), f2bf(b1.w) };
            *(ushort8*)&Bl[row][(g ^ (row & 7)) * 8] = bv;
        }
        __syncthreads();
        #pragma unroll
        for (int kf = 0; kf < 2; ++kf) {
            short8 af[4], bfr[4];
            #pragma unroll
            for (int mi = 0; mi < 4; ++mi) {
                int row = wr * 64 + mi * 16 + lr, g = kf * 4 + lq;
                af[mi] = *(const short8*)&Al[row][(g ^ (row & 7)) * 8];
            }
            #pragma unroll
            for (int ni = 0; ni < 4; ++ni) {
                int row = wc * 64 + ni * 16 + lr, g = kf * 4 + lq;
                bfr[ni] = *(const short8*)&Bl[row][(g ^ (row & 7)) * 8];
            }
            #pragma unroll
            for (int mi = 0; mi < 4; ++mi)
                #pragma unroll
                for (int ni = 0; ni < 4; ++ni)
                    acc[mi][ni] = __builtin_amdgcn_mfma_f32_16x16x32_bf16(
                        af[mi], bfr[ni], acc[mi][ni], 0, 0, 0);
        }
    }
    #pragma unroll
    for (int ni = 0; ni < 4; ++ni) {
        int col = n0 + wc * 64 + ni * 16 + lr;
        float bb = bias[col];
        #pragma unroll
        for (int mi = 0; mi < 4; ++mi)
            #pragma unroll
            for (int j = 0; j < 4; ++j) {
                int row = m0 + wr * 64 + mi * 16 + lq * 4 + j;
                C[(size_t)row * 512 + col] = f2bf(acc[mi][ni][j] + bb);
            }
    }
}

// ---------------------------------------------------------------------------
// Stage 2: per (128-pt tile, head): [lg | t1] = xmb_h @ [Ws;Wt1]^T via MFMA,
// then temp-MLP + gumbel softmax in-wave. Fast erf, constant-shift softmax
// (temp >= 0.33 and gn <= ~18 bound args; exp(s-25) cannot overflow).
// ---------------------------------------------------------------------------
__global__ __launch_bounds__(256)
void lgt1_mfma_kernel(const ushort* __restrict__ xmb,
                      const float* __restrict__ Ws,  const float* __restrict__ bs,
                      const float* __restrict__ Wt1, const float* __restrict__ bt1,
                      const float* __restrict__ Wt2, const float* __restrict__ bt2,
                      const float* __restrict__ biasp,
                      const float* __restrict__ u,
                      ushort* __restrict__ swb) {
    __shared__ __align__(16) ushort Al[128][64];
    __shared__ __align__(16) ushort Bl[128][64];
    const int h = blockIdx.y, m0 = blockIdx.x * 128;
    const int t = threadIdx.x, l = t & 63, w = t >> 6;
    const int lr = l & 15, lq = l >> 4;

    #pragma unroll
    for (int i = 0; i < 4; ++i) {
        int idx = i * 256 + t;
        int row = idx >> 3, g = idx & 7;
        ushort8 av = *(const ushort8*)&xmb[(size_t)(m0 + row) * 512 + h * 64 + g * 8];
        *(ushort8*)&Al[row][(g ^ (row & 7)) * 8] = av;
        const float* src = (row < 64 ? &Ws[(size_t)row * 64]
                                     : &Wt1[(size_t)(row - 64) * 64]) + g * 8;
        float4 b0 = *(const float4*)src;
        float4 b1 = *(const float4*)(src + 4);
        ushort8 bv = { f2bf(b0.x), f2bf(b0.y), f2bf(b0.z), f2bf(b0.w),
                       f2bf(b1.x), f2bf(b1.y), f2bf(b1.z), f2bf(b1.w) };
        *(ushort8*)&Bl[row][(g ^ (row & 7)) * 8] = bv;
    }
    __syncthreads();

    f32x4 acc[2][8];
    #pragma unroll
    for (int mi = 0; mi < 2; ++mi)
        #pragma unroll
        for (int ni = 0; ni < 8; ++ni) acc[mi][ni] = (f32x4){0.f, 0.f, 0.f, 0.f};

    #pragma unroll
    for (int kf = 0; kf < 2; ++kf) {
        short8 af[2], bfr[8];
        #pragma unroll
        for (int mi = 0; mi < 2; ++mi) {
            int row = w * 32 + mi * 16 + lr, g = kf * 4 + lq;
            af[mi] = *(const short8*)&Al[row][(g ^ (row & 7)) * 8];
        }
        #pragma unroll
        for (int ni = 0; ni < 8; ++ni) {
            int row = ni * 16 + lr, g = kf * 4 + lq;
            bfr[ni] = *(const short8*)&Bl[row][(g ^ (row & 7)) * 8];
        }
        #pragma unroll
        for (int mi = 0; mi < 2; ++mi)
            #pragma unroll
            for (int ni = 0; ni < 8; ++ni)
                acc[mi][ni] = __builtin_amdgcn_mfma_f32_16x16x32_bf16(
                    af[mi], bfr[ni], acc[mi][ni], 0, 0, 0);
    }

    const float bt2v = bt2[0], biasph = biasp[h];
    float bsr[4], bt1r[4], wt2r[4];
    #pragma unroll
    for (int ni = 0; ni < 4; ++ni) {
        bsr[ni]  = bs [ni * 16 + lr];
        bt1r[ni] = bt1[ni * 16 + lr];
        wt2r[ni] = Wt2[ni * 16 + lr];
    }

    #pragma unroll
    for (int mi = 0; mi < 2; ++mi)
        #pragma unroll
        for (int jj = 0; jj < 4; ++jj) {
            const int n = m0 + w * 32 + mi * 16 + lq * 4 + jj;
            // temperature: t1 cols are ni 4..7 (cols 64..127)
            float tsum = 0.f;
            #pragma unroll
            for (int ni = 0; ni < 4; ++ni)
                tsum += gelu_fast(acc[mi][ni + 4][jj] + bt1r[ni]) * wt2r[ni];
            tsum += __shfl_xor(tsum, 1);
            tsum += __shfl_xor(tsum, 2);
            tsum += __shfl_xor(tsum, 4);
            tsum += __shfl_xor(tsum, 8);
            float temp = gelu_fast(tsum + bt2v) + biasph;
            temp = fmaxf(temp, 0.01f);
            const float invt = __builtin_amdgcn_rcpf(temp);

            // gumbel softmax over 64 lg cols (ni 0..3, 16 lanes), shift by 25
            const float* up = &u[((size_t)h * NPTS + n) * 64 + lr];
            float s[4];
            float ps = 0.f;
            #pragma unroll
            for (int ni = 0; ni < 4; ++ni) {
                float uu = up[ni * 16];
                float gn = -__logf(-__logf(uu + 1e-8f) + 1e-8f);
                s[ni] = __expf(fmaf(acc[mi][ni][jj] + bsr[ni] + gn, invt, -25.0f));
                ps += s[ni];
            }
            ps += __shfl_xor(ps, 1);
            ps += __shfl_xor(ps, 2);
            ps += __shfl_xor(ps, 4);
            ps += __shfl_xor(ps, 8);
            const float inv = __builtin_amdgcn_rcpf(ps);
            ushort* sp = &swb[(size_t)n * 512 + h * 64 + lr];
            #pragma unroll
            for (int ni = 0; ni < 4; ++ni)
                sp[ni * 16] = f2bf(s[ni] * inv);
        }
}

// ---------------------------------------------------------------------------
// Stage 3: per (h, chunk of 1024 pts): partial slice_tokens[g][c], norm[g]
// ---------------------------------------------------------------------------
__global__ __launch_bounds__(256)
void gather_kernel(const ushort* __restrict__ xmb, const ushort* __restrict__ swb,
                   float* __restrict__ stp, float* __restrict__ normp) {
    __shared__ float xt [64][68];
    __shared__ float stl[64][68];
    __shared__ float nacc[4][64];
    const int h  = blockIdx.y;
    const int n0 = blockIdx.x * 1024;
    const int t  = threadIdx.x;
    const int q  = t >> 6, c = t & 63;
    float acc[16];
    #pragma unroll
    for (int i = 0; i < 16; ++i) acc[i] = 0.f;
    float nsum = 0.f;

    for (int tile = 0; tile < 16; ++tile) {
        const int pt = n0 + tile * 64;
        __syncthreads();
        #pragma unroll
        for (int i = 0; i < 2; ++i) {
            int idx = i * 256 + t;            // 0..511
            int p = idx >> 3, cc = (idx & 7) * 8;
            ushort8 xv = *(const ushort8*)&xmb[(size_t)(pt + p) * 512 + h * 64 + cc];
            ushort8 sv = *(const ushort8*)&swb[(size_t)(pt + p) * 512 + h * 64 + cc];
            #pragma unroll
            for (int j = 0; j < 8; ++j) {
                xt [p][cc + j] = bf2f(xv[j]);
                stl[p][cc + j] = bf2f(sv[j]);
            }
        }
        __syncthreads();
        for (int p = 0; p < 64; ++p) {
            float xvv = xt[p][c];
            #pragma unroll
            for (int i4 = 0; i4 < 4; ++i4) {
                float4 sv = *(const float4*)&stl[p][q*16 + i4*4];
                acc[i4*4+0] = fmaf(sv.x, xvv, acc[i4*4+0]);
                acc[i4*4+1] = fmaf(sv.y, xvv, acc[i4*4+1]);
                acc[i4*4+2] = fmaf(sv.z, xvv, acc[i4*4+2]);
                acc[i4*4+3] = fmaf(sv.w, xvv, acc[i4*4+3]);
            }
        }
        #pragma unroll
        for (int pp = 0; pp < 16; ++pp) nsum += stl[q*16 + pp][c];
    }
    const size_t pbase = ((size_t)h * 64 + blockIdx.x) * 4096;
    #pragma unroll
    for (int i = 0; i < 16; ++i)
        stp[pbase + (size_t)(q*16 + i)*64 + c] = acc[i];
    nacc[q][c] = nsum;
    __syncthreads();
    if (t < 64)
        normp[((size_t)h * 64 + blockIdx.x) * 64 + t] =
            nacc[0][t] + nacc[1][t] + nacc[2][t] + nacc[3][t];
}

// ---------------------------------------------------------------------------
// Stage 4a: parallel reduction of chunk partials -> st_red, nrm
// ---------------------------------------------------------------------------
__global__ __launch_bounds__(256)
void reduce_st_kernel(const float* __restrict__ stp, const float* __restrict__ normp,
                      float* __restrict__ st_red, float* __restrict__ nrm) {
    const int h = blockIdx.x;
    const int e = blockIdx.y * 256 + threadIdx.x;   // 0..4095
    float s = 0.f;
    #pragma unroll 8
    for (int ch = 0; ch < 64; ++ch)
        s += stp[((size_t)h * 64 + ch) * 4096 + e];
    st_red[(size_t)h * 4096 + e] = s;
    if (blockIdx.y == 0 && threadIdx.x < 64) {
        float ns = 0.f;
        #pragma unroll 8
        for (int ch = 0; ch < 64; ++ch)
            ns += normp[((size_t)h * 64 + ch) * 64 + threadIdx.x];
        nrm[h * 64 + threadIdx.x] = ns + 1e-5f;
    }
}

// ---------------------------------------------------------------------------
// Stage 4b: per head: normalize tokens, qkv, 64x64 attention -> osl
// ---------------------------------------------------------------------------
__global__ __launch_bounds__(256)
void attn_small_kernel(const float* __restrict__ st_red, const float* __restrict__ nrm,
                       const float* __restrict__ Wq, const float* __restrict__ Wk,
                       const float* __restrict__ Wv, float* __restrict__ osl) {
    __shared__ float st[64][68];
    __shared__ float ql[64][68];
    __shared__ float kl[64][68];
    __shared__ float vl[64][68];
    __shared__ float sc[64][68];
    __shared__ float nl[64];
    const int h = blockIdx.x;
    const int t = threadIdx.x;

    if (t < 64) nl[t] = nrm[h * 64 + t];
    __syncthreads();
    for (int e = t; e < 4096; e += 256)
        st[e>>6][e&63] = st_red[(size_t)h * 4096 + e] / nl[e>>6];
    __syncthreads();
    for (int e = t; e < 4096; e += 256) {
        int g = e >> 6, dd = e & 63;
        float aq = 0.f, ak = 0.f, av = 0.f;
        for (int cc = 0; cc < 64; ++cc) {
            float sv = st[g][cc];
            aq = fmaf(sv, Wq[dd*64 + cc], aq);
            ak = fmaf(sv, Wk[dd*64 + cc], ak);
            av = fmaf(sv, Wv[dd*64 + cc], av);
        }
        ql[g][dd] = aq; kl[g][dd] = ak; vl[g][dd] = av;
    }
    __syncthreads();
    for (int e = t; e < 4096; e += 256) {
        int g = e >> 6, gp = e & 63;
        float s = 0.f;
        for (int dd = 0; dd < 64; ++dd) s = fmaf(ql[g][dd], kl[gp][dd], s);
        sc[g][gp] = s * 0.125f;
    }
    __syncthreads();
    if (t < 64) {
        float m = -1e30f;
        for (int j = 0; j < 64; ++j) m = fmaxf(m, sc[t][j]);
        float ssum = 0.f;
        for (int j = 0; j < 64; ++j) { float p = expf(sc[t][j] - m); sc[t][j] = p; ssum += p; }
        float inv = 1.f / ssum;
        for (int j = 0; j < 64; ++j) sc[t][j] *= inv;
    }
    __syncthreads();
    for (int e = t; e < 4096; e += 256) {
        int g = e >> 6, dd = e & 63;
        float s = 0.f;
        for (int gp = 0; gp < 64; ++gp) s = fmaf(sc[g][gp], vl[gp][dd], s);
        osl[(size_t)h * 4096 + e] = s;
    }
}

// ---------------------------------------------------------------------------
// Stage 4c: fold out_slice into Wout: Mt[i][h*64+g]
// ---------------------------------------------------------------------------
__global__ __launch_bounds__(256)
void fold_kernel(const float* __restrict__ osl, const float* __restrict__ Wout,
                 float* __restrict__ Mt) {
    __shared__ float os[64][65];
    __shared__ float wl[128][65];
    const int h  = blockIdx.x;
    const int i0 = blockIdx.y * 128;
    const int t  = threadIdx.x;
    for (int e = t; e < 4096; e += 256) os[e>>6][e&63] = osl[(size_t)h * 4096 + e];
    for (int e = t; e < 8192; e += 256) {
        int i = e >> 6, d = e & 63;
        wl[i][d] = Wout[(size_t)(i0 + i) * HDIM + h * 64 + d];
    }
    __syncthreads();
    const int g = t & 63, iq = t >> 6;
    #pragma unroll 4
    for (int k = 0; k < 32; ++k) {
        int i = iq * 32 + k;
        float s = 0.f;
        #pragma unroll
        for (int d = 0; d < 64; ++d) s = fmaf(os[g][d], wl[i][d], s);
        Mt[(size_t)(i0 + i) * HDIM + h * 64 + g] = s;
    }
}

// ---------------------------------------------------------------------------
// Stage 5: out_f32[M][256] = swb_bf16[M][512] @ Mt^T + bout
// ---------------------------------------------------------------------------
__global__ __launch_bounds__(256)
void gemm_out_kernel(const ushort* __restrict__ A, const float* __restrict__ B,
                     const float* __restrict__ bias, float* __restrict__ C) {
    __shared__ __align__(16) ushort Al[128][64];
    __shared__ __align__(16) ushort Bl[128][64];
    const int m0 = blockIdx.x * 128, n0 = blockIdx.y * 128;
    const int t = threadIdx.x, l = t & 63, w = t >> 6;
    const int wr = w >> 1, wc = w & 1;
    const int lr = l & 15, lq = l >> 4;

    f32x4 acc[4][4];
    #pragma unroll
    for (int mi = 0; mi < 4; ++mi)
        #pragma unroll
        for (int ni = 0; ni < 4; ++ni) acc[mi][ni] = (f32x4){0.f, 0.f, 0.f, 0.f};

    for (int ks = 0; ks < 8; ++ks) {          // K-step of 64 (K=512)
        __syncthreads();
        #pragma unroll
        for (int i = 0; i < 4; ++i) {
            int idx = i * 256 + t;
            int row = idx >> 3, g = idx & 7;
            ushort8 av = *(const ushort8*)&A[(size_t)(m0 + row) * 512 + ks * 64 + g * 8];
            *(ushort8*)&Al[row][(g ^ (row & 7)) * 8] = av;
            const float* bp = &B[(size_t)(n0 + row) * 512 + ks * 64 + g * 8];
            float4 b0 = *(const float4*)bp;
            float4 b1 = *(const float4*)(bp + 4);
            ushort8 bv = { f2bf(b0.x), f2bf(b0.y), f2bf(b0.z), f2bf(b0.w),
                           f2bf(b1.x), f2bf(b1.y), f2bf(b1.z), f2bf(b1.w) };
            *(ushort8*)&Bl[row][(g ^ (row & 7)) * 8] = bv;
        }
        __syncthreads();
        #pragma unroll
        for (int kf = 0; kf < 2; ++kf) {
            short8 af[4], bfr[4];
            #pragma unroll
            for (int mi = 0; mi < 4; ++mi) {
                int row = wr * 64 + mi * 16 + lr, g = kf * 4 + lq;
                af[mi] = *(const short8*)&Al[row][(g ^ (row & 7)) * 8];
            }
            #pragma unroll
            for (int ni = 0; ni < 4; ++ni) {
                int row = wc * 64 + ni * 16 + lr, g = kf * 4 + lq;
                bfr[ni] = *(const short8*)&Bl[row][(g ^ (row & 7)) * 8];
            }
            #pragma unroll
            for (int mi = 0; mi < 4; ++mi)
                #pragma unroll
                for (int ni = 0; ni < 4; ++ni)
                    acc[mi][ni] = __builtin_amdgcn_mfma_f32_16x16x32_bf16(
                        af[mi], bfr[ni], acc[mi][ni], 0, 0, 0);
        }
    }
    #pragma unroll
    for (int ni = 0; ni < 4; ++ni) {
        int col = n0 + wc * 64 + ni * 16 + lr;
        float bb = bias[col];
        #pragma unroll
        for (int mi = 0; mi < 4; ++mi)
            #pragma unroll
            for (int j = 0; j < 4; ++j) {
                int row = m0 + wr * 64 + mi * 16 + lq * 4 + j;
                C[(size_t)row * 256 + col] = acc[mi][ni][j] + bb;
            }
    }
}

// ---------------------------------------------------------------------------
extern "C" void kernel_launch(void* const* d_in, const int* in_sizes, int n_in,
                              void* d_out, int out_size, void* d_ws, size_t ws_size,
                              hipStream_t stream) {
    const float* x    = (const float*)d_in[0];
    const float* Wx   = (const float*)d_in[1];
    const float* bx   = (const float*)d_in[2];
    const float* Wt1  = (const float*)d_in[3];
    const float* bt1  = (const float*)d_in[4];
    const float* Wt2  = (const float*)d_in[5];
    const float* bt2  = (const float*)d_in[6];
    const float* biasp= (const float*)d_in[7];
    const float* Ws   = (const float*)d_in[8];
    const float* bs   = (const float*)d_in[9];
    const float* Wq   = (const float*)d_in[10];
    const float* Wk   = (const float*)d_in[11];
    const float* Wv   = (const float*)d_in[12];
    const float* Wout = (const float*)d_in[13];
    const float* bout = (const float*)d_in[14];
    const float* u    = (const float*)d_in[15];
    float* out = (float*)d_out;

    float*  stp    = (float*)d_ws;                           // 8*64*4096 f32
    float*  normp  = stp    + (size_t)NH * 64 * 4096;        // 8*64*64
    float*  Mt     = normp  + (size_t)NH * 64 * 64;          // 256*512
    float*  st_red = Mt     + (size_t)DIMX * HDIM;           // 8*4096
    float*  nrm    = st_red + (size_t)NH * 4096;             // 8*64
    float*  osl    = nrm    + (size_t)NH * 64;               // 8*4096
    ushort* xmb    = (ushort*)(osl + (size_t)NH * 4096);     // 65536*512 bf16
    ushort* swb    = xmb + (size_t)NPTS * HDIM;              // 65536*512 bf16

    // 1) xmid (bf16) = x @ Wx^T + bx
    gemm_xmid_kernel<<<dim3(512, 4), 256, 0, stream>>>(x, Wx, bx, xmb);
    // 2) fused logits/temp MFMA GEMM + gumbel softmax -> sw (bf16)
    lgt1_mfma_kernel<<<dim3(512, 8), 256, 0, stream>>>(xmb, Ws, bs, Wt1, bt1,
                                                       Wt2, bt2, biasp, u, swb);
    // 3) slice token partials
    gather_kernel<<<dim3(64, 8), 256, 0, stream>>>(xmb, swb, stp, normp);
    // 4a) reduce partials (parallel)
    reduce_st_kernel<<<dim3(8, 16), 256, 0, stream>>>(stp, normp, st_red, nrm);
    // 4b) tiny attention
    attn_small_kernel<<<8, 256, 0, stream>>>(st_red, nrm, Wq, Wk, Wv, osl);
    // 4c) fold out_slice into Wout
    fold_kernel<<<dim3(8, 2), 256, 0, stream>>>(osl, Wout, Mt);
    // 5) out = sw @ Mt^T + bout
    gemm_out_kernel<<<dim3(512, 2), 256, 0, stream>>>(swb, Mt, bout, out);
}

// Round 7
// 291.114 us; speedup vs baseline: 4.6540x; 1.2046x over previous
//
#include <hip/hip_runtime.h>
#include <math.h>

// Physics_Attention: B=1, N=65536, DIM=256, H=8, D=64, G=64
#define NPTS  65536
#define DIMX  256
#define NH    8
#define HDIM  512   // H*D

typedef __attribute__((ext_vector_type(4))) float f32x4;
typedef __attribute__((ext_vector_type(8))) short short8;
typedef __attribute__((ext_vector_type(8))) unsigned short ushort8;
typedef __attribute__((ext_vector_type(4))) unsigned short us4;

__device__ __forceinline__ ushort f2bf(float f) {   // RNE f32->bf16
    unsigned x = __float_as_uint(f);
    return (ushort)((x + 0x7fffu + ((x >> 16) & 1u)) >> 16);
}
__device__ __forceinline__ float bf2f(ushort u) {
    return __uint_as_float((unsigned)u << 16);
}
// Fast erf (A&S 7.1.26, abs err 1.5e-7) — no branches, HW exp/rcp
__device__ __forceinline__ float erf_fast(float x) {
    float ax = fabsf(x);
    float t  = __builtin_amdgcn_rcpf(1.0f + 0.3275911f * ax);
    float p  = fmaf(fmaf(fmaf(fmaf(1.061405429f, t, -1.453152027f), t,
                   1.421413741f), t, -0.284496736f), t, 0.254829592f) * t;
    float y  = 1.0f - p * __expf(-ax * ax);
    return copysignf(y, x);
}
__device__ __forceinline__ float gelu_fast(float x) {
    return 0.5f * x * (1.0f + erf_fast(x * 0.7071067811865476f));
}

// ---------------------------------------------------------------------------
// Stage 1: xmb_bf16[M][512] = x_f32[M][256] @ Wx^T + bx   (M=65536)
// ---------------------------------------------------------------------------
__global__ __launch_bounds__(256)
void gemm_xmid_kernel(const float* __restrict__ A, const float* __restrict__ B,
                      const float* __restrict__ bias, ushort* __restrict__ C) {
    __shared__ __align__(16) ushort Al[128][64];
    __shared__ __align__(16) ushort Bl[128][64];
    const int m0 = blockIdx.x * 128, n0 = blockIdx.y * 128;
    const int t = threadIdx.x, l = t & 63, w = t >> 6;
    const int wr = w >> 1, wc = w & 1;
    const int lr = l & 15, lq = l >> 4;

    f32x4 acc[4][4];
    #pragma unroll
    for (int mi = 0; mi < 4; ++mi)
        #pragma unroll
        for (int ni = 0; ni < 4; ++ni) acc[mi][ni] = (f32x4){0.f, 0.f, 0.f, 0.f};

    for (int ks = 0; ks < 4; ++ks) {          // K-step of 64 (K=256)
        __syncthreads();
        #pragma unroll
        for (int i = 0; i < 4; ++i) {
            int idx = i * 256 + t;            // 0..1023
            int row = idx >> 3, g = idx & 7;
            const float* ap = &A[(size_t)(m0 + row) * 256 + ks * 64 + g * 8];
            float4 a0 = *(const float4*)ap;
            float4 a1 = *(const float4*)(ap + 4);
            ushort8 av = { f2bf(a0.x), f2bf(a0.y), f2bf(a0.z), f2bf(a0.w),
                           f2bf(a1.x), f2bf(a1.y), f2bf(a1.z), f2bf(a1.w) };
            *(ushort8*)&Al[row][(g ^ (row & 7)) * 8] = av;
            const float* bp = &B[(size_t)(n0 + row) * 256 + ks * 64 + g * 8];
            float4 b0 = *(const float4*)bp;
            float4 b1 = *(const float4*)(bp + 4);
            ushort8 bv = { f2bf(b0.x), f2bf(b0.y), f2bf(b0.z), f2bf(b0.w),
                           f2bf(b1.x), f2bf(b1.y), f2bf(b1.z), f2bf(b1.w) };
            *(ushort8*)&Bl[row][(g ^ (row & 7)) * 8] = bv;
        }
        __syncthreads();
        #pragma unroll
        for (int kf = 0; kf < 2; ++kf) {
            short8 af[4], bfr[4];
            #pragma unroll
            for (int mi = 0; mi < 4; ++mi) {
                int row = wr * 64 + mi * 16 + lr, g = kf * 4 + lq;
                af[mi] = *(const short8*)&Al[row][(g ^ (row & 7)) * 8];
            }
            #pragma unroll
            for (int ni = 0; ni < 4; ++ni) {
                int row = wc * 64 + ni * 16 + lr, g = kf * 4 + lq;
                bfr[ni] = *(const short8*)&Bl[row][(g ^ (row & 7)) * 8];
            }
            #pragma unroll
            for (int mi = 0; mi < 4; ++mi)
                #pragma unroll
                for (int ni = 0; ni < 4; ++ni)
                    acc[mi][ni] = __builtin_amdgcn_mfma_f32_16x16x32_bf16(
                        af[mi], bfr[ni], acc[mi][ni], 0, 0, 0);
        }
    }
    #pragma unroll
    for (int ni = 0; ni < 4; ++ni) {
        int col = n0 + wc * 64 + ni * 16 + lr;
        float bb = bias[col];
        #pragma unroll
        for (int mi = 0; mi < 4; ++mi)
            #pragma unroll
            for (int j = 0; j < 4; ++j) {
                int row = m0 + wr * 64 + mi * 16 + lq * 4 + j;
                C[(size_t)row * 512 + col] = f2bf(acc[mi][ni][j] + bb);
            }
    }
}

// ---------------------------------------------------------------------------
// Stage 2: per (128-pt tile, head): [lg | t1] = xmb_h @ [Ws;Wt1]^T via MFMA,
// then temp-MLP + gumbel softmax in-wave. Fast erf, constant-shift softmax.
// ---------------------------------------------------------------------------
__global__ __launch_bounds__(256)
void lgt1_mfma_kernel(const ushort* __restrict__ xmb,
                      const float* __restrict__ Ws,  const float* __restrict__ bs,
                      const float* __restrict__ Wt1, const float* __restrict__ bt1,
                      const float* __restrict__ Wt2, const float* __restrict__ bt2,
                      const float* __restrict__ biasp,
                      const float* __restrict__ u,
                      ushort* __restrict__ swb) {
    __shared__ __align__(16) ushort Al[128][64];
    __shared__ __align__(16) ushort Bl[128][64];
    const int h = blockIdx.y, m0 = blockIdx.x * 128;
    const int t = threadIdx.x, l = t & 63, w = t >> 6;
    const int lr = l & 15, lq = l >> 4;

    #pragma unroll
    for (int i = 0; i < 4; ++i) {
        int idx = i * 256 + t;
        int row = idx >> 3, g = idx & 7;
        ushort8 av = *(const ushort8*)&xmb[(size_t)(m0 + row) * 512 + h * 64 + g * 8];
        *(ushort8*)&Al[row][(g ^ (row & 7)) * 8] = av;
        const float* src = (row < 64 ? &Ws[(size_t)row * 64]
                                     : &Wt1[(size_t)(row - 64) * 64]) + g * 8;
        float4 b0 = *(const float4*)src;
        float4 b1 = *(const float4*)(src + 4);
        ushort8 bv = { f2bf(b0.x), f2bf(b0.y), f2bf(b0.z), f2bf(b0.w),
                       f2bf(b1.x), f2bf(b1.y), f2bf(b1.z), f2bf(b1.w) };
        *(ushort8*)&Bl[row][(g ^ (row & 7)) * 8] = bv;
    }
    __syncthreads();

    f32x4 acc[2][8];
    #pragma unroll
    for (int mi = 0; mi < 2; ++mi)
        #pragma unroll
        for (int ni = 0; ni < 8; ++ni) acc[mi][ni] = (f32x4){0.f, 0.f, 0.f, 0.f};

    #pragma unroll
    for (int kf = 0; kf < 2; ++kf) {
        short8 af[2], bfr[8];
        #pragma unroll
        for (int mi = 0; mi < 2; ++mi) {
            int row = w * 32 + mi * 16 + lr, g = kf * 4 + lq;
            af[mi] = *(const short8*)&Al[row][(g ^ (row & 7)) * 8];
        }
        #pragma unroll
        for (int ni = 0; ni < 8; ++ni) {
            int row = ni * 16 + lr, g = kf * 4 + lq;
            bfr[ni] = *(const short8*)&Bl[row][(g ^ (row & 7)) * 8];
        }
        #pragma unroll
        for (int mi = 0; mi < 2; ++mi)
            #pragma unroll
            for (int ni = 0; ni < 8; ++ni)
                acc[mi][ni] = __builtin_amdgcn_mfma_f32_16x16x32_bf16(
                    af[mi], bfr[ni], acc[mi][ni], 0, 0, 0);
    }

    const float bt2v = bt2[0], biasph = biasp[h];
    float bsr[4], bt1r[4], wt2r[4];
    #pragma unroll
    for (int ni = 0; ni < 4; ++ni) {
        bsr[ni]  = bs [ni * 16 + lr];
        bt1r[ni] = bt1[ni * 16 + lr];
        wt2r[ni] = Wt2[ni * 16 + lr];
    }

    #pragma unroll
    for (int mi = 0; mi < 2; ++mi)
        #pragma unroll
        for (int jj = 0; jj < 4; ++jj) {
            const int n = m0 + w * 32 + mi * 16 + lq * 4 + jj;
            float tsum = 0.f;
            #pragma unroll
            for (int ni = 0; ni < 4; ++ni)
                tsum += gelu_fast(acc[mi][ni + 4][jj] + bt1r[ni]) * wt2r[ni];
            tsum += __shfl_xor(tsum, 1);
            tsum += __shfl_xor(tsum, 2);
            tsum += __shfl_xor(tsum, 4);
            tsum += __shfl_xor(tsum, 8);
            float temp = gelu_fast(tsum + bt2v) + biasph;
            temp = fmaxf(temp, 0.01f);
            const float invt = __builtin_amdgcn_rcpf(temp);

            const float* up = &u[((size_t)h * NPTS + n) * 64 + lr];
            float s[4];
            float ps = 0.f;
            #pragma unroll
            for (int ni = 0; ni < 4; ++ni) {
                float uu = up[ni * 16];
                float gn = -__logf(-__logf(uu + 1e-8f) + 1e-8f);
                s[ni] = __expf(fmaf(acc[mi][ni][jj] + bsr[ni] + gn, invt, -25.0f));
                ps += s[ni];
            }
            ps += __shfl_xor(ps, 1);
            ps += __shfl_xor(ps, 2);
            ps += __shfl_xor(ps, 4);
            ps += __shfl_xor(ps, 8);
            const float inv = __builtin_amdgcn_rcpf(ps);
            ushort* sp = &swb[(size_t)n * 512 + h * 64 + lr];
            #pragma unroll
            for (int ni = 0; ni < 4; ++ni)
                sp[ni * 16] = f2bf(s[ni] * inv);
        }
}

// ---------------------------------------------------------------------------
// Stage 3 (MFMA): per (h, 1024-pt chunk): C[g][c] = sum_n sw[n][g]*x[n][c]
// via transposed bf16 LDS tiles (swizzled), 4 waves own k-slices; each wave
// writes its own chunk partial (chunks = 4 * 64 blocks = 256 per head).
// norm[g] accumulated in registers during staging.
// Swizzle: nb_phys = nb ^ (g&7) ^ ((g>>3)&7)  (<=2-way banks on both sides)
// ---------------------------------------------------------------------------
__global__ __launch_bounds__(256)
void gather_mfma_kernel(const ushort* __restrict__ xmb, const ushort* __restrict__ swb,
                        float* __restrict__ stp, float* __restrict__ normp) {
    __shared__ __align__(16) ushort swT[64][128];
    __shared__ __align__(16) ushort xT [64][128];
    const int h  = blockIdx.y;
    const int n0 = blockIdx.x * 1024;
    const int t  = threadIdx.x, l = t & 63, w = t >> 6;
    const int lr = l & 15, lq = l >> 4;
    const int gb = t & 7;          // 8-g block this thread stages
    const int ng = t >> 3;         // 0..31: 4-n group

    f32x4 acc[4][4];               // [gi][ci] -> full C[64][64] per wave
    #pragma unroll
    for (int gi = 0; gi < 4; ++gi)
        #pragma unroll
        for (int ci = 0; ci < 4; ++ci) acc[gi][ci] = (f32x4){0.f, 0.f, 0.f, 0.f};
    float nrm8[8];
    #pragma unroll
    for (int j = 0; j < 8; ++j) nrm8[j] = 0.f;

    for (int r = 0; r < 8; ++r) {
        const int nt = n0 + r * 128;
        // load 4 n-rows x 8 g/c values
        ushort8 sv[4], xv[4];
        #pragma unroll
        for (int i = 0; i < 4; ++i) {
            int n = nt + ng * 4 + i;
            sv[i] = *(const ushort8*)&swb[(size_t)n * 512 + h * 64 + gb * 8];
            xv[i] = *(const ushort8*)&xmb[(size_t)n * 512 + h * 64 + gb * 8];
        }
        __syncthreads();           // prev round's frag reads done
        #pragma unroll
        for (int j = 0; j < 8; ++j) {
            int g   = gb * 8 + j;
            int swz = (ng >> 1) ^ (g & 7) ^ ((g >> 3) & 7);   // nb = ng>>1
            int off = swz * 8 + (ng & 1) * 4;
            us4 s4 = { sv[0][j], sv[1][j], sv[2][j], sv[3][j] };
            us4 x4 = { xv[0][j], xv[1][j], xv[2][j], xv[3][j] };
            *(us4*)&swT[g][off] = s4;
            *(us4*)&xT [g][off] = x4;
            nrm8[j] += (bf2f(sv[0][j]) + bf2f(sv[1][j]))
                     + (bf2f(sv[2][j]) + bf2f(sv[3][j]));
        }
        __syncthreads();
        // wave w consumes k-slice [w*32, w*32+32): nb = w*4 + lq
        short8 af[4], bfr[4];
        #pragma unroll
        for (int gi = 0; gi < 4; ++gi) {
            int g   = gi * 16 + lr;
            int swz = (w * 4 + lq) ^ (g & 7) ^ ((g >> 3) & 7);
            af[gi]  = *(const short8*)&swT[g][swz * 8];
            bfr[gi] = *(const short8*)&xT [g][swz * 8];
        }
        #pragma unroll
        for (int gi = 0; gi < 4; ++gi)
            #pragma unroll
            for (int ci = 0; ci < 4; ++ci)
                acc[gi][ci] = __builtin_amdgcn_mfma_f32_16x16x32_bf16(
                    af[gi], bfr[ci], acc[gi][ci], 0, 0, 0);
    }

    // write wave's chunk partial: chunk = blockIdx.x*4 + w
    const size_t base = ((size_t)h * 256 + blockIdx.x * 4 + w) * 4096;
    #pragma unroll
    for (int gi = 0; gi < 4; ++gi)
        #pragma unroll
        for (int ci = 0; ci < 4; ++ci)
            #pragma unroll
            for (int j = 0; j < 4; ++j)
                stp[base + (size_t)(gi * 16 + lq * 4 + j) * 64 + ci * 16 + lr]
                    = acc[gi][ci][j];

    // norm partials -> LDS reduce -> normp[h][block][g]
    __syncthreads();
    float* narr = (float*)swT;     // 32*64 f32 = 8 KB
    #pragma unroll
    for (int j = 0; j < 8; ++j) narr[ng * 64 + gb * 8 + j] = nrm8[j];
    __syncthreads();
    if (t < 64) {
        float s = 0.f;
        #pragma unroll 8
        for (int k = 0; k < 32; ++k) s += narr[k * 64 + t];
        normp[((size_t)h * 64 + blockIdx.x) * 64 + t] = s;
    }
}

// ---------------------------------------------------------------------------
// Stage 4a: reduce chunk partials -> st_red (256 chunks), nrm (64 chunks)
// ---------------------------------------------------------------------------
__global__ __launch_bounds__(256)
void reduce_st_kernel(const float* __restrict__ stp, const float* __restrict__ normp,
                      float* __restrict__ st_red, float* __restrict__ nrm) {
    const int h = blockIdx.x;
    const int e = blockIdx.y * 256 + threadIdx.x;   // 0..4095
    float s = 0.f;
    #pragma unroll 8
    for (int ch = 0; ch < 256; ++ch)
        s += stp[((size_t)h * 256 + ch) * 4096 + e];
    st_red[(size_t)h * 4096 + e] = s;
    if (blockIdx.y == 0 && threadIdx.x < 64) {
        float ns = 0.f;
        #pragma unroll 8
        for (int ch = 0; ch < 64; ++ch)
            ns += normp[((size_t)h * 64 + ch) * 64 + threadIdx.x];
        nrm[h * 64 + threadIdx.x] = ns + 1e-5f;
    }
}

// ---------------------------------------------------------------------------
// Stage 4b: per head: normalize tokens, qkv, 64x64 attention -> osl
// ---------------------------------------------------------------------------
__global__ __launch_bounds__(256)
void attn_small_kernel(const float* __restrict__ st_red, const float* __restrict__ nrm,
                       const float* __restrict__ Wq, const float* __restrict__ Wk,
                       const float* __restrict__ Wv, float* __restrict__ osl) {
    __shared__ float st[64][68];
    __shared__ float ql[64][68];
    __shared__ float kl[64][68];
    __shared__ float vl[64][68];
    __shared__ float sc[64][68];
    __shared__ float nl[64];
    const int h = blockIdx.x;
    const int t = threadIdx.x;

    if (t < 64) nl[t] = nrm[h * 64 + t];
    __syncthreads();
    for (int e = t; e < 4096; e += 256)
        st[e>>6][e&63] = st_red[(size_t)h * 4096 + e] / nl[e>>6];
    __syncthreads();
    for (int e = t; e < 4096; e += 256) {
        int g = e >> 6, dd = e & 63;
        float aq = 0.f, ak = 0.f, av = 0.f;
        for (int cc = 0; cc < 64; ++cc) {
            float sv = st[g][cc];
            aq = fmaf(sv, Wq[dd*64 + cc], aq);
            ak = fmaf(sv, Wk[dd*64 + cc], ak);
            av = fmaf(sv, Wv[dd*64 + cc], av);
        }
        ql[g][dd] = aq; kl[g][dd] = ak; vl[g][dd] = av;
    }
    __syncthreads();
    for (int e = t; e < 4096; e += 256) {
        int g = e >> 6, gp = e & 63;
        float s = 0.f;
        for (int dd = 0; dd < 64; ++dd) s = fmaf(ql[g][dd], kl[gp][dd], s);
        sc[g][gp] = s * 0.125f;
    }
    __syncthreads();
    if (t < 64) {
        float m = -1e30f;
        for (int j = 0; j < 64; ++j) m = fmaxf(m, sc[t][j]);
        float ssum = 0.f;
        for (int j = 0; j < 64; ++j) { float p = expf(sc[t][j] - m); sc[t][j] = p; ssum += p; }
        float inv = 1.f / ssum;
        for (int j = 0; j < 64; ++j) sc[t][j] *= inv;
    }
    __syncthreads();
    for (int e = t; e < 4096; e += 256) {
        int g = e >> 6, dd = e & 63;
        float s = 0.f;
        for (int gp = 0; gp < 64; ++gp) s = fmaf(sc[g][gp], vl[gp][dd], s);
        osl[(size_t)h * 4096 + e] = s;
    }
}

// ---------------------------------------------------------------------------
// Stage 4c: fold out_slice into Wout: Mt[i][h*64+g]
// ---------------------------------------------------------------------------
__global__ __launch_bounds__(256)
void fold_kernel(const float* __restrict__ osl, const float* __restrict__ Wout,
                 float* __restrict__ Mt) {
    __shared__ float os[64][65];
    __shared__ float wl[128][65];
    const int h  = blockIdx.x;
    const int i0 = blockIdx.y * 128;
    const int t  = threadIdx.x;
    for (int e = t; e < 4096; e += 256) os[e>>6][e&63] = osl[(size_t)h * 4096 + e];
    for (int e = t; e < 8192; e += 256) {
        int i = e >> 6, d = e & 63;
        wl[i][d] = Wout[(size_t)(i0 + i) * HDIM + h * 64 + d];
    }
    __syncthreads();
    const int g = t & 63, iq = t >> 6;
    #pragma unroll 4
    for (int k = 0; k < 32; ++k) {
        int i = iq * 32 + k;
        float s = 0.f;
        #pragma unroll
        for (int d = 0; d < 64; ++d) s = fmaf(os[g][d], wl[i][d], s);
        Mt[(size_t)(i0 + i) * HDIM + h * 64 + g] = s;
    }
}

// ---------------------------------------------------------------------------
// Stage 5: out_f32[M][256] = swb_bf16[M][512] @ Mt^T + bout
// ---------------------------------------------------------------------------
__global__ __launch_bounds__(256)
void gemm_out_kernel(const ushort* __restrict__ A, const float* __restrict__ B,
                     const float* __restrict__ bias, float* __restrict__ C) {
    __shared__ __align__(16) ushort Al[128][64];
    __shared__ __align__(16) ushort Bl[128][64];
    const int m0 = blockIdx.x * 128, n0 = blockIdx.y * 128;
    const int t = threadIdx.x, l = t & 63, w = t >> 6;
    const int wr = w >> 1, wc = w & 1;
    const int lr = l & 15, lq = l >> 4;

    f32x4 acc[4][4];
    #pragma unroll
    for (int mi = 0; mi < 4; ++mi)
        #pragma unroll
        for (int ni = 0; ni < 4; ++ni) acc[mi][ni] = (f32x4){0.f, 0.f, 0.f, 0.f};

    for (int ks = 0; ks < 8; ++ks) {          // K-step of 64 (K=512)
        __syncthreads();
        #pragma unroll
        for (int i = 0; i < 4; ++i) {
            int idx = i * 256 + t;
            int row = idx >> 3, g = idx & 7;
            ushort8 av = *(const ushort8*)&A[(size_t)(m0 + row) * 512 + ks * 64 + g * 8];
            *(ushort8*)&Al[row][(g ^ (row & 7)) * 8] = av;
            const float* bp = &B[(size_t)(n0 + row) * 512 + ks * 64 + g * 8];
            float4 b0 = *(const float4*)bp;
            float4 b1 = *(const float4*)(bp + 4);
            ushort8 bv = { f2bf(b0.x), f2bf(b0.y), f2bf(b0.z), f2bf(b0.w),
                           f2bf(b1.x), f2bf(b1.y), f2bf(b1.z), f2bf(b1.w) };
            *(ushort8*)&Bl[row][(g ^ (row & 7)) * 8] = bv;
        }
        __syncthreads();
        #pragma unroll
        for (int kf = 0; kf < 2; ++kf) {
            short8 af[4], bfr[4];
            #pragma unroll
            for (int mi = 0; mi < 4; ++mi) {
                int row = wr * 64 + mi * 16 + lr, g = kf * 4 + lq;
                af[mi] = *(const short8*)&Al[row][(g ^ (row & 7)) * 8];
            }
            #pragma unroll
            for (int ni = 0; ni < 4; ++ni) {
                int row = wc * 64 + ni * 16 + lr, g = kf * 4 + lq;
                bfr[ni] = *(const short8*)&Bl[row][(g ^ (row & 7)) * 8];
            }
            #pragma unroll
            for (int mi = 0; mi < 4; ++mi)
                #pragma unroll
                for (int ni = 0; ni < 4; ++ni)
                    acc[mi][ni] = __builtin_amdgcn_mfma_f32_16x16x32_bf16(
                        af[mi], bfr[ni], acc[mi][ni], 0, 0, 0);
        }
    }
    #pragma unroll
    for (int ni = 0; ni < 4; ++ni) {
        int col = n0 + wc * 64 + ni * 16 + lr;
        float bb = bias[col];
        #pragma unroll
        for (int mi = 0; mi < 4; ++mi)
            #pragma unroll
            for (int j = 0; j < 4; ++j) {
                int row = m0 + wr * 64 + mi * 16 + lq * 4 + j;
                C[(size_t)row * 256 + col] = acc[mi][ni][j] + bb;
            }
    }
}

// ---------------------------------------------------------------------------
extern "C" void kernel_launch(void* const* d_in, const int* in_sizes, int n_in,
                              void* d_out, int out_size, void* d_ws, size_t ws_size,
                              hipStream_t stream) {
    const float* x    = (const float*)d_in[0];
    const float* Wx   = (const float*)d_in[1];
    const float* bx   = (const float*)d_in[2];
    const float* Wt1  = (const float*)d_in[3];
    const float* bt1  = (const float*)d_in[4];
    const float* Wt2  = (const float*)d_in[5];
    const float* bt2  = (const float*)d_in[6];
    const float* biasp= (const float*)d_in[7];
    const float* Ws   = (const float*)d_in[8];
    const float* bs   = (const float*)d_in[9];
    const float* Wq   = (const float*)d_in[10];
    const float* Wk   = (const float*)d_in[11];
    const float* Wv   = (const float*)d_in[12];
    const float* Wout = (const float*)d_in[13];
    const float* bout = (const float*)d_in[14];
    const float* u    = (const float*)d_in[15];
    float* out = (float*)d_out;

    float*  stp    = (float*)d_ws;                           // 8*256*4096 f32 = 33.5 MB
    float*  normp  = stp    + (size_t)NH * 256 * 4096;       // 8*64*64
    float*  Mt     = normp  + (size_t)NH * 64 * 64;          // 256*512
    float*  st_red = Mt     + (size_t)DIMX * HDIM;           // 8*4096
    float*  nrm    = st_red + (size_t)NH * 4096;             // 8*64
    float*  osl    = nrm    + (size_t)NH * 64;               // 8*4096
    ushort* xmb    = (ushort*)(osl + (size_t)NH * 4096);     // 65536*512 bf16
    ushort* swb    = xmb + (size_t)NPTS * HDIM;              // 65536*512 bf16

    // 1) xmid (bf16) = x @ Wx^T + bx
    gemm_xmid_kernel<<<dim3(512, 4), 256, 0, stream>>>(x, Wx, bx, xmb);
    // 2) fused logits/temp MFMA GEMM + gumbel softmax -> sw (bf16)
    lgt1_mfma_kernel<<<dim3(512, 8), 256, 0, stream>>>(xmb, Ws, bs, Wt1, bt1,
                                                       Wt2, bt2, biasp, u, swb);
    // 3) slice token partials via MFMA (transposed LDS tiles)
    gather_mfma_kernel<<<dim3(64, 8), 256, 0, stream>>>(xmb, swb, stp, normp);
    // 4a) reduce partials
    reduce_st_kernel<<<dim3(8, 16), 256, 0, stream>>>(stp, normp, st_red, nrm);
    // 4b) tiny attention
    attn_small_kernel<<<8, 256, 0, stream>>>(st_red, nrm, Wq, Wk, Wv, osl);
    // 4c) fold out_slice into Wout
    fold_kernel<<<dim3(8, 2), 256, 0, stream>>>(osl, Wout, Mt);
    // 5) out = sw @ Mt^T + bout
    gemm_out_kernel<<<dim3(512, 2), 256, 0, stream>>>(swb, Mt, bout, out);
}

// Round 9
// 290.413 us; speedup vs baseline: 4.6652x; 1.0024x over previous
//
#include <hip/hip_runtime.h>
#include <math.h>

// Physics_Attention: B=1, N=65536, DIM=256, H=8, D=64, G=64
#define NPTS  65536
#define DIMX  256
#define NH    8
#define HDIM  512   // H*D

typedef __attribute__((ext_vector_type(4))) float f32x4;
typedef __attribute__((ext_vector_type(8))) short short8;
typedef __attribute__((ext_vector_type(8))) unsigned short ushort8;
typedef __attribute__((ext_vector_type(4))) unsigned short us4;

__device__ __forceinline__ ushort f2bf(float f) {   // RNE f32->bf16
    unsigned x = __float_as_uint(f);
    return (ushort)((x + 0x7fffu + ((x >> 16) & 1u)) >> 16);
}
__device__ __forceinline__ float bf2f(ushort u) {
    return __uint_as_float((unsigned)u << 16);
}
// Fast erf (A&S 7.1.26, abs err 1.5e-7) — no branches, HW exp/rcp
__device__ __forceinline__ float erf_fast(float x) {
    float ax = fabsf(x);
    float t  = __builtin_amdgcn_rcpf(1.0f + 0.3275911f * ax);
    float p  = fmaf(fmaf(fmaf(fmaf(1.061405429f, t, -1.453152027f), t,
                   1.421413741f), t, -0.284496736f), t, 0.254829592f) * t;
    float y  = 1.0f - p * __expf(-ax * ax);
    return copysignf(y, x);
}
__device__ __forceinline__ float gelu_fast(float x) {
    return 0.5f * x * (1.0f + erf_fast(x * 0.7071067811865476f));
}

// ---------------------------------------------------------------------------
// Stage 0: convert [Ws;Wt1] (128x64 f32) -> wb bf16 (L2-resident weight tile)
// ---------------------------------------------------------------------------
__global__ __launch_bounds__(256)
void prep_wb_kernel(const float* __restrict__ Ws, const float* __restrict__ Wt1,
                    ushort* __restrict__ wb) {
    const int t = threadIdx.x;
    #pragma unroll
    for (int i = 0; i < 32; ++i) {
        int idx = i * 256 + t;             // 0..8191
        int row = idx >> 6, col = idx & 63;
        float v = (row < 64) ? Ws[row * 64 + col] : Wt1[(row - 64) * 64 + col];
        wb[idx] = f2bf(v);
    }
}

// ---------------------------------------------------------------------------
// Stage 1: xmb_bf16[M][512] = x_f32[M][256] @ Wx^T + bx   (M=65536)
// ---------------------------------------------------------------------------
__global__ __launch_bounds__(256)
void gemm_xmid_kernel(const float* __restrict__ A, const float* __restrict__ B,
                      const float* __restrict__ bias, ushort* __restrict__ C) {
    __shared__ __align__(16) ushort Al[128][64];
    __shared__ __align__(16) ushort Bl[128][64];
    const int m0 = blockIdx.x * 128, n0 = blockIdx.y * 128;
    const int t = threadIdx.x, l = t & 63, w = t >> 6;
    const int wr = w >> 1, wc = w & 1;
    const int lr = l & 15, lq = l >> 4;

    f32x4 acc[4][4];
    #pragma unroll
    for (int mi = 0; mi < 4; ++mi)
        #pragma unroll
        for (int ni = 0; ni < 4; ++ni) acc[mi][ni] = (f32x4){0.f, 0.f, 0.f, 0.f};

    for (int ks = 0; ks < 4; ++ks) {          // K-step of 64 (K=256)
        __syncthreads();
        #pragma unroll
        for (int i = 0; i < 4; ++i) {
            int idx = i * 256 + t;            // 0..1023
            int row = idx >> 3, g = idx & 7;
            const float* ap = &A[(size_t)(m0 + row) * 256 + ks * 64 + g * 8];
            float4 a0 = *(const float4*)ap;
            float4 a1 = *(const float4*)(ap + 4);
            ushort8 av = { f2bf(a0.x), f2bf(a0.y), f2bf(a0.z), f2bf(a0.w),
                           f2bf(a1.x), f2bf(a1.y), f2bf(a1.z), f2bf(a1.w) };
            *(ushort8*)&Al[row][(g ^ (row & 7)) * 8] = av;
            const float* bp = &B[(size_t)(n0 + row) * 256 + ks * 64 + g * 8];
            float4 b0 = *(const float4*)bp;
            float4 b1 = *(const float4*)(bp + 4);
            ushort8 bv = { f2bf(b0.x), f2bf(b0.y), f2bf(b0.z), f2bf(b0.w),
                           f2bf(b1.x), f2bf(b1.y), f2bf(b1.z), f2bf(b1.w) };
            *(ushort8*)&Bl[row][(g ^ (row & 7)) * 8] = bv;
        }
        __syncthreads();
        #pragma unroll
        for (int kf = 0; kf < 2; ++kf) {
            short8 af[4], bfr[4];
            #pragma unroll
            for (int mi = 0; mi < 4; ++mi) {
                int row = wr * 64 + mi * 16 + lr, g = kf * 4 + lq;
                af[mi] = *(const short8*)&Al[row][(g ^ (row & 7)) * 8];
            }
            #pragma unroll
            for (int ni = 0; ni < 4; ++ni) {
                int row = wc * 64 + ni * 16 + lr, g = kf * 4 + lq;
                bfr[ni] = *(const short8*)&Bl[row][(g ^ (row & 7)) * 8];
            }
            #pragma unroll
            for (int mi = 0; mi < 4; ++mi)
                #pragma unroll
                for (int ni = 0; ni < 4; ++ni)
                    acc[mi][ni] = __builtin_amdgcn_mfma_f32_16x16x32_bf16(
                        af[mi], bfr[ni], acc[mi][ni], 0, 0, 0);
        }
    }
    #pragma unroll
    for (int ni = 0; ni < 4; ++ni) {
        int col = n0 + wc * 64 + ni * 16 + lr;
        float bb = bias[col];
        #pragma unroll
        for (int mi = 0; mi < 4; ++mi)
            #pragma unroll
            for (int j = 0; j < 4; ++j) {
                int row = m0 + wr * 64 + mi * 16 + lq * 4 + j;
                C[(size_t)row * 512 + col] = f2bf(acc[mi][ni][j] + bb);
            }
    }
}

// ---------------------------------------------------------------------------
// Stage 2 v2: [lg | t1] = xmb_h @ wb^T (K=64) via MFMA; B-frags direct from
// global bf16 wb (L2-hot), A tile in 16KB LDS (one barrier). Epilogue batched
// across the 4 jj-rows per mi; log2/exp2 with folded constants.
//   s = exp2( (lg+bs)*invt*log2e - invt*log2(inner) - 25*log2e )
//   inner = 1e-8 - ln2*log2(u+1e-8)          (gn*invt folds: ln2*log2e = 1)
// ---------------------------------------------------------------------------
__global__ __launch_bounds__(256)
void lgt1_mfma_kernel(const ushort* __restrict__ xmb,
                      const ushort* __restrict__ wb,
                      const float* __restrict__ bs,  const float* __restrict__ bt1,
                      const float* __restrict__ Wt2, const float* __restrict__ bt2,
                      const float* __restrict__ biasp,
                      const float* __restrict__ u,
                      ushort* __restrict__ swb) {
    __shared__ __align__(16) ushort Al[128][64];
    const int h = blockIdx.y, m0 = blockIdx.x * 128;
    const int t = threadIdx.x, l = t & 63, w = t >> 6;
    const int lr = l & 15, lq = l >> 4;
    const float LOG2E = 1.4426950408889634f;
    const float LN2   = 0.6931471805599453f;
    const float SH2   = 36.0673760222f;      // 25*log2e

    #pragma unroll
    for (int i = 0; i < 4; ++i) {
        int idx = i * 256 + t;               // 0..1023
        int row = idx >> 3, g = idx & 7;
        ushort8 av = *(const ushort8*)&xmb[(size_t)(m0 + row) * 512 + h * 64 + g * 8];
        *(ushort8*)&Al[row][(g ^ (row & 7)) * 8] = av;
    }

    // prefetch u for mi=0 rows (hidden under staging + MFMA)
    float uu0[4][4];
    #pragma unroll
    for (int jj = 0; jj < 4; ++jj) {
        const int n = m0 + w * 32 + lq * 4 + jj;
        const float* up = &u[((size_t)h * NPTS + n) * 64 + lr];
        #pragma unroll
        for (int ni = 0; ni < 4; ++ni) uu0[jj][ni] = up[ni * 16];
    }
    __syncthreads();

    f32x4 acc[2][8];
    #pragma unroll
    for (int mi = 0; mi < 2; ++mi)
        #pragma unroll
        for (int ni = 0; ni < 8; ++ni) acc[mi][ni] = (f32x4){0.f, 0.f, 0.f, 0.f};

    #pragma unroll
    for (int kf = 0; kf < 2; ++kf) {
        const int g = kf * 4 + lq;
        short8 af[2], bfr[8];
        #pragma unroll
        for (int mi = 0; mi < 2; ++mi) {
            int row = w * 32 + mi * 16 + lr;
            af[mi] = *(const short8*)&Al[row][(g ^ (row & 7)) * 8];
        }
        #pragma unroll
        for (int ni = 0; ni < 8; ++ni)       // direct from global wb (L2-hot)
            bfr[ni] = *(const short8*)&wb[(size_t)(ni * 16 + lr) * 64 + g * 8];
        #pragma unroll
        for (int mi = 0; mi < 2; ++mi)
            #pragma unroll
            for (int ni = 0; ni < 8; ++ni)
                acc[mi][ni] = __builtin_amdgcn_mfma_f32_16x16x32_bf16(
                    af[mi], bfr[ni], acc[mi][ni], 0, 0, 0);
    }

    // prefetch u for mi=1 rows (hidden under mi=0 epilogue)
    float uu1[4][4];
    #pragma unroll
    for (int jj = 0; jj < 4; ++jj) {
        const int n = m0 + w * 32 + 16 + lq * 4 + jj;
        const float* up = &u[((size_t)h * NPTS + n) * 64 + lr];
        #pragma unroll
        for (int ni = 0; ni < 4; ++ni) uu1[jj][ni] = up[ni * 16];
    }

    const float bt2v = bt2[0], biasph = biasp[h];
    float bsr[4], bt1r[4], wt2r[4];
    #pragma unroll
    for (int ni = 0; ni < 4; ++ni) {
        bsr[ni]  = bs [ni * 16 + lr];
        bt1r[ni] = bt1[ni * 16 + lr];
        wt2r[ni] = Wt2[ni * 16 + lr];
    }

    #pragma unroll
    for (int mi = 0; mi < 2; ++mi) {
        // phase 1: 16 independent gelu partials
        float ts[4];
        #pragma unroll
        for (int jj = 0; jj < 4; ++jj) {
            float s = 0.f;
            #pragma unroll
            for (int ni = 0; ni < 4; ++ni)
                s += gelu_fast(acc[mi][ni + 4][jj] + bt1r[ni]) * wt2r[ni];
            ts[jj] = s;
        }
        // phase 2: 4 interleaved shuffle-reduce chains
        #pragma unroll
        for (int off = 1; off <= 8; off <<= 1) {
            #pragma unroll
            for (int jj = 0; jj < 4; ++jj) ts[jj] += __shfl_xor(ts[jj], off);
        }
        // phase 3: temps
        float invt[4], invt2[4];
        #pragma unroll
        for (int jj = 0; jj < 4; ++jj) {
            float tmp = gelu_fast(ts[jj] + bt2v) + biasph;
            tmp = fmaxf(tmp, 0.01f);
            invt[jj]  = __builtin_amdgcn_rcpf(tmp);
            invt2[jj] = invt[jj] * LOG2E;
        }
        // phase 4: 16 independent gumbel chains
        float sv[4][4], ps[4] = {0.f, 0.f, 0.f, 0.f};
        #pragma unroll
        for (int jj = 0; jj < 4; ++jj) {
            #pragma unroll
            for (int ni = 0; ni < 4; ++ni) {
                float uuv = (mi == 0 ? uu0[jj][ni] : uu1[jj][ni]);
                float L1 = __log2f(uuv + 1e-8f);
                float inner = fmaf(-LN2, L1, 1e-8f);
                float L2v = __log2f(inner);
                float base = fmaf(acc[mi][ni][jj] + bsr[ni], invt2[jj], -SH2);
                sv[jj][ni] = __builtin_amdgcn_exp2f(fmaf(-invt[jj], L2v, base));
                ps[jj] += sv[jj][ni];
            }
        }
        // phase 5: 4 interleaved ps reduces
        #pragma unroll
        for (int off = 1; off <= 8; off <<= 1) {
            #pragma unroll
            for (int jj = 0; jj < 4; ++jj) ps[jj] += __shfl_xor(ps[jj], off);
        }
        // phase 6: stores
        #pragma unroll
        for (int jj = 0; jj < 4; ++jj) {
            const int n = m0 + w * 32 + mi * 16 + lq * 4 + jj;
            const float inv = __builtin_amdgcn_rcpf(ps[jj]);
            ushort* sp = &swb[(size_t)n * 512 + h * 64 + lr];
            #pragma unroll
            for (int ni = 0; ni < 4; ++ni)
                sp[ni * 16] = f2bf(sv[jj][ni] * inv);
        }
    }
}

// ---------------------------------------------------------------------------
// Stage 3 (MFMA): per (h, 1024-pt chunk): C[g][c] = sum_n sw[n][g]*x[n][c]
// ---------------------------------------------------------------------------
__global__ __launch_bounds__(256)
void gather_mfma_kernel(const ushort* __restrict__ xmb, const ushort* __restrict__ swb,
                        float* __restrict__ stp, float* __restrict__ normp) {
    __shared__ __align__(16) ushort swT[64][128];
    __shared__ __align__(16) ushort xT [64][128];
    const int h  = blockIdx.y;
    const int n0 = blockIdx.x * 1024;
    const int t  = threadIdx.x, l = t & 63, w = t >> 6;
    const int lr = l & 15, lq = l >> 4;
    const int gb = t & 7;
    const int ng = t >> 3;

    f32x4 acc[4][4];
    #pragma unroll
    for (int gi = 0; gi < 4; ++gi)
        #pragma unroll
        for (int ci = 0; ci < 4; ++ci) acc[gi][ci] = (f32x4){0.f, 0.f, 0.f, 0.f};
    float nrm8[8];
    #pragma unroll
    for (int j = 0; j < 8; ++j) nrm8[j] = 0.f;

    for (int r = 0; r < 8; ++r) {
        const int nt = n0 + r * 128;
        ushort8 sv[4], xv[4];
        #pragma unroll
        for (int i = 0; i < 4; ++i) {
            int n = nt + ng * 4 + i;
            sv[i] = *(const ushort8*)&swb[(size_t)n * 512 + h * 64 + gb * 8];
            xv[i] = *(const ushort8*)&xmb[(size_t)n * 512 + h * 64 + gb * 8];
        }
        __syncthreads();
        #pragma unroll
        for (int j = 0; j < 8; ++j) {
            int g   = gb * 8 + j;
            int swz = (ng >> 1) ^ (g & 7) ^ ((g >> 3) & 7);
            int off = swz * 8 + (ng & 1) * 4;
            us4 s4 = { sv[0][j], sv[1][j], sv[2][j], sv[3][j] };
            us4 x4 = { xv[0][j], xv[1][j], xv[2][j], xv[3][j] };
            *(us4*)&swT[g][off] = s4;
            *(us4*)&xT [g][off] = x4;
            nrm8[j] += (bf2f(sv[0][j]) + bf2f(sv[1][j]))
                     + (bf2f(sv[2][j]) + bf2f(sv[3][j]));
        }
        __syncthreads();
        short8 af[4], bfr[4];
        #pragma unroll
        for (int gi = 0; gi < 4; ++gi) {
            int g   = gi * 16 + lr;
            int swz = (w * 4 + lq) ^ (g & 7) ^ ((g >> 3) & 7);
            af[gi]  = *(const short8*)&swT[g][swz * 8];
            bfr[gi] = *(const short8*)&xT [g][swz * 8];
        }
        #pragma unroll
        for (int gi = 0; gi < 4; ++gi)
            #pragma unroll
            for (int ci = 0; ci < 4; ++ci)
                acc[gi][ci] = __builtin_amdgcn_mfma_f32_16x16x32_bf16(
                    af[gi], bfr[ci], acc[gi][ci], 0, 0, 0);
    }

    const size_t base = ((size_t)h * 256 + blockIdx.x * 4 + w) * 4096;
    #pragma unroll
    for (int gi = 0; gi < 4; ++gi)
        #pragma unroll
        for (int ci = 0; ci < 4; ++ci)
            #pragma unroll
            for (int j = 0; j < 4; ++j)
                stp[base + (size_t)(gi * 16 + lq * 4 + j) * 64 + ci * 16 + lr]
                    = acc[gi][ci][j];

    __syncthreads();
    float* narr = (float*)swT;
    #pragma unroll
    for (int j = 0; j < 8; ++j) narr[ng * 64 + gb * 8 + j] = nrm8[j];
    __syncthreads();
    if (t < 64) {
        float s = 0.f;
        #pragma unroll 8
        for (int k = 0; k < 32; ++k) s += narr[k * 64 + t];
        normp[((size_t)h * 64 + blockIdx.x) * 64 + t] = s;
    }
}

// ---------------------------------------------------------------------------
// Stage 4a: reduce chunk partials -> st_red (256 chunks), nrm (64 chunks)
// ---------------------------------------------------------------------------
__global__ __launch_bounds__(256)
void reduce_st_kernel(const float* __restrict__ stp, const float* __restrict__ normp,
                      float* __restrict__ st_red, float* __restrict__ nrm) {
    const int h = blockIdx.x;
    const int e = blockIdx.y * 256 + threadIdx.x;
    float s = 0.f;
    #pragma unroll 8
    for (int ch = 0; ch < 256; ++ch)
        s += stp[((size_t)h * 256 + ch) * 4096 + e];
    st_red[(size_t)h * 4096 + e] = s;
    if (blockIdx.y == 0 && threadIdx.x < 64) {
        float ns = 0.f;
        #pragma unroll 8
        for (int ch = 0; ch < 64; ++ch)
            ns += normp[((size_t)h * 64 + ch) * 64 + threadIdx.x];
        nrm[h * 64 + threadIdx.x] = ns + 1e-5f;
    }
}

// ---------------------------------------------------------------------------
// Stage 4b: per head: normalize tokens, qkv, 64x64 attention -> osl
// ---------------------------------------------------------------------------
__global__ __launch_bounds__(256)
void attn_small_kernel(const float* __restrict__ st_red, const float* __restrict__ nrm,
                       const float* __restrict__ Wq, const float* __restrict__ Wk,
                       const float* __restrict__ Wv, float* __restrict__ osl) {
    __shared__ float st[64][68];
    __shared__ float ql[64][68];
    __shared__ float kl[64][68];
    __shared__ float vl[64][68];
    __shared__ float sc[64][68];
    __shared__ float nl[64];
    const int h = blockIdx.x;
    const int t = threadIdx.x;

    if (t < 64) nl[t] = nrm[h * 64 + t];
    __syncthreads();
    for (int e = t; e < 4096; e += 256)
        st[e>>6][e&63] = st_red[(size_t)h * 4096 + e] / nl[e>>6];
    __syncthreads();
    for (int e = t; e < 4096; e += 256) {
        int g = e >> 6, dd = e & 63;
        float aq = 0.f, ak = 0.f, av = 0.f;
        for (int cc = 0; cc < 64; ++cc) {
            float sv = st[g][cc];
            aq = fmaf(sv, Wq[dd*64 + cc], aq);
            ak = fmaf(sv, Wk[dd*64 + cc], ak);
            av = fmaf(sv, Wv[dd*64 + cc], av);
        }
        ql[g][dd] = aq; kl[g][dd] = ak; vl[g][dd] = av;
    }
    __syncthreads();
    for (int e = t; e < 4096; e += 256) {
        int g = e >> 6, gp = e & 63;
        float s = 0.f;
        for (int dd = 0; dd < 64; ++dd) s = fmaf(ql[g][dd], kl[gp][dd], s);
        sc[g][gp] = s * 0.125f;
    }
    __syncthreads();
    if (t < 64) {
        float m = -1e30f;
        for (int j = 0; j < 64; ++j) m = fmaxf(m, sc[t][j]);
        float ssum = 0.f;
        for (int j = 0; j < 64; ++j) { float p = expf(sc[t][j] - m); sc[t][j] = p; ssum += p; }
        float inv = 1.f / ssum;
        for (int j = 0; j < 64; ++j) sc[t][j] *= inv;
    }
    __syncthreads();
    for (int e = t; e < 4096; e += 256) {
        int g = e >> 6, dd = e & 63;
        float s = 0.f;
        for (int gp = 0; gp < 64; ++gp) s = fmaf(sc[g][gp], vl[gp][dd], s);
        osl[(size_t)h * 4096 + e] = s;
    }
}

// ---------------------------------------------------------------------------
// Stage 4c: fold out_slice into Wout: Mt[i][h*64+g]
// ---------------------------------------------------------------------------
__global__ __launch_bounds__(256)
void fold_kernel(const float* __restrict__ osl, const float* __restrict__ Wout,
                 float* __restrict__ Mt) {
    __shared__ float os[64][65];
    __shared__ float wl[128][65];
    const int h  = blockIdx.x;
    const int i0 = blockIdx.y * 128;
    const int t  = threadIdx.x;
    for (int e = t; e < 4096; e += 256) os[e>>6][e&63] = osl[(size_t)h * 4096 + e];
    for (int e = t; e < 8192; e += 256) {
        int i = e >> 6, d = e & 63;
        wl[i][d] = Wout[(size_t)(i0 + i) * HDIM + h * 64 + d];
    }
    __syncthreads();
    const int g = t & 63, iq = t >> 6;
    #pragma unroll 4
    for (int k = 0; k < 32; ++k) {
        int i = iq * 32 + k;
        float s = 0.f;
        #pragma unroll
        for (int d = 0; d < 64; ++d) s = fmaf(os[g][d], wl[i][d], s);
        Mt[(size_t)(i0 + i) * HDIM + h * 64 + g] = s;
    }
}

// ---------------------------------------------------------------------------
// Stage 5: out_f32[M][256] = swb_bf16[M][512] @ Mt^T + bout
// ---------------------------------------------------------------------------
__global__ __launch_bounds__(256)
void gemm_out_kernel(const ushort* __restrict__ A, const float* __restrict__ B,
                     const float* __restrict__ bias, float* __restrict__ C) {
    __shared__ __align__(16) ushort Al[128][64];
    __shared__ __align__(16) ushort Bl[128][64];
    const int m0 = blockIdx.x * 128, n0 = blockIdx.y * 128;
    const int t = threadIdx.x, l = t & 63, w = t >> 6;
    const int wr = w >> 1, wc = w & 1;
    const int lr = l & 15, lq = l >> 4;

    f32x4 acc[4][4];
    #pragma unroll
    for (int mi = 0; mi < 4; ++mi)
        #pragma unroll
        for (int ni = 0; ni < 4; ++ni) acc[mi][ni] = (f32x4){0.f, 0.f, 0.f, 0.f};

    for (int ks = 0; ks < 8; ++ks) {          // K-step of 64 (K=512)
        __syncthreads();
        #pragma unroll
        for (int i = 0; i < 4; ++i) {
            int idx = i * 256 + t;
            int row = idx >> 3, g = idx & 7;
            ushort8 av = *(const ushort8*)&A[(size_t)(m0 + row) * 512 + ks * 64 + g * 8];
            *(ushort8*)&Al[row][(g ^ (row & 7)) * 8] = av;
            const float* bp = &B[(size_t)(n0 + row) * 512 + ks * 64 + g * 8];
            float4 b0 = *(const float4*)bp;
            float4 b1 = *(const float4*)(bp + 4);
            ushort8 bv = { f2bf(b0.x), f2bf(b0.y), f2bf(b0.z), f2bf(b0.w),
                           f2bf(b1.x), f2bf(b1.y), f2bf(b1.z), f2bf(b1.w) };
            *(ushort8*)&Bl[row][(g ^ (row & 7)) * 8] = bv;
        }
        __syncthreads();
        #pragma unroll
        for (int kf = 0; kf < 2; ++kf) {
            short8 af[4], bfr[4];
            #pragma unroll
            for (int mi = 0; mi < 4; ++mi) {
                int row = wr * 64 + mi * 16 + lr, g = kf * 4 + lq;
                af[mi] = *(const short8*)&Al[row][(g ^ (row & 7)) * 8];
            }
            #pragma unroll
            for (int ni = 0; ni < 4; ++ni) {
                int row = wc * 64 + ni * 16 + lr, g = kf * 4 + lq;
                bfr[ni] = *(const short8*)&Bl[row][(g ^ (row & 7)) * 8];
            }
            #pragma unroll
            for (int mi = 0; mi < 4; ++mi)
                #pragma unroll
                for (int ni = 0; ni < 4; ++ni)
                    acc[mi][ni] = __builtin_amdgcn_mfma_f32_16x16x32_bf16(
                        af[mi], bfr[ni], acc[mi][ni], 0, 0, 0);
        }
    }
    #pragma unroll
    for (int ni = 0; ni < 4; ++ni) {
        int col = n0 + wc * 64 + ni * 16 + lr;
        float bb = bias[col];
        #pragma unroll
        for (int mi = 0; mi < 4; ++mi)
            #pragma unroll
            for (int j = 0; j < 4; ++j) {
                int row = m0 + wr * 64 + mi * 16 + lq * 4 + j;
                C[(size_t)row * 256 + col] = acc[mi][ni][j] + bb;
            }
    }
}

// ---------------------------------------------------------------------------
extern "C" void kernel_launch(void* const* d_in, const int* in_sizes, int n_in,
                              void* d_out, int out_size, void* d_ws, size_t ws_size,
                              hipStream_t stream) {
    const float* x    = (const float*)d_in[0];
    const float* Wx   = (const float*)d_in[1];
    const float* bx   = (const float*)d_in[2];
    const float* Wt1  = (const float*)d_in[3];
    const float* bt1  = (const float*)d_in[4];
    const float* Wt2  = (const float*)d_in[5];
    const float* bt2  = (const float*)d_in[6];
    const float* biasp= (const float*)d_in[7];
    const float* Ws   = (const float*)d_in[8];
    const float* bs   = (const float*)d_in[9];
    const float* Wq   = (const float*)d_in[10];
    const float* Wk   = (const float*)d_in[11];
    const float* Wv   = (const float*)d_in[12];
    const float* Wout = (const float*)d_in[13];
    const float* bout = (const float*)d_in[14];
    const float* u    = (const float*)d_in[15];
    float* out = (float*)d_out;

    float*  stp    = (float*)d_ws;                           // 8*256*4096 f32
    float*  normp  = stp    + (size_t)NH * 256 * 4096;       // 8*64*64
    float*  Mt     = normp  + (size_t)NH * 64 * 64;          // 256*512
    float*  st_red = Mt     + (size_t)DIMX * HDIM;           // 8*4096
    float*  nrm    = st_red + (size_t)NH * 4096;             // 8*64
    float*  osl    = nrm    + (size_t)NH * 64;               // 8*4096
    ushort* wb     = (ushort*)(osl + (size_t)NH * 4096);     // 128*64 bf16
    ushort* xmb    = wb  + (size_t)128 * 64;                 // 65536*512 bf16
    ushort* swb    = xmb + (size_t)NPTS * HDIM;              // 65536*512 bf16

    // 0) convert [Ws;Wt1] to bf16 (L2-resident weight tile)
    prep_wb_kernel<<<1, 256, 0, stream>>>(Ws, Wt1, wb);
    // 1) xmid (bf16) = x @ Wx^T + bx
    gemm_xmid_kernel<<<dim3(512, 4), 256, 0, stream>>>(x, Wx, bx, xmb);
    // 2) fused logits/temp MFMA GEMM + gumbel softmax -> sw (bf16)
    lgt1_mfma_kernel<<<dim3(512, 8), 256, 0, stream>>>(xmb, wb, bs, bt1,
                                                       Wt2, bt2, biasp, u, swb);
    // 3) slice token partials via MFMA (transposed LDS tiles)
    gather_mfma_kernel<<<dim3(64, 8), 256, 0, stream>>>(xmb, swb, stp, normp);
    // 4a) reduce partials
    reduce_st_kernel<<<dim3(8, 16), 256, 0, stream>>>(stp, normp, st_red, nrm);
    // 4b) tiny attention
    attn_small_kernel<<<8, 256, 0, stream>>>(st_red, nrm, Wq, Wk, Wv, osl);
    // 4c) fold out_slice into Wout
    fold_kernel<<<dim3(8, 2), 256, 0, stream>>>(osl, Wout, Mt);
    // 5) out = sw @ Mt^T + bout
    gemm_out_kernel<<<dim3(512, 2), 256, 0, stream>>>(swb, Mt, bout, out);
}

// Round 11
// 266.049 us; speedup vs baseline: 5.0924x; 1.0916x over previous
//
#include <hip/hip_runtime.h>
#include <math.h>

// Physics_Attention: B=1, N=65536, DIM=256, H=8, D=64, G=64
#define NPTS  65536
#define DIMX  256
#define NH    8
#define HDIM  512   // H*D

typedef __attribute__((ext_vector_type(4))) float f32x4;
typedef __attribute__((ext_vector_type(8))) short short8;
typedef __attribute__((ext_vector_type(8))) unsigned short ushort8;
typedef __attribute__((ext_vector_type(4))) unsigned short us4;

__device__ __forceinline__ ushort f2bf(float f) {   // RNE f32->bf16
    unsigned x = __float_as_uint(f);
    return (ushort)((x + 0x7fffu + ((x >> 16) & 1u)) >> 16);
}
__device__ __forceinline__ float bf2f(ushort u) {
    return __uint_as_float((unsigned)u << 16);
}
// Fast erf (A&S 7.1.26, abs err 1.5e-7) — no branches, HW exp/rcp
__device__ __forceinline__ float erf_fast(float x) {
    float ax = fabsf(x);
    float t  = __builtin_amdgcn_rcpf(1.0f + 0.3275911f * ax);
    float p  = fmaf(fmaf(fmaf(fmaf(1.061405429f, t, -1.453152027f), t,
                   1.421413741f), t, -0.284496736f), t, 0.254829592f) * t;
    float y  = 1.0f - p * __expf(-ax * ax);
    return copysignf(y, x);
}
__device__ __forceinline__ float gelu_fast(float x) {
    return 0.5f * x * (1.0f + erf_fast(x * 0.7071067811865476f));
}

// ---------------------------------------------------------------------------
// Stage 0: pre-convert Wx (512x256) and [Ws;Wt1] (128x64) to bf16.
// ---------------------------------------------------------------------------
__global__ __launch_bounds__(256)
void prep_kernel(const float* __restrict__ Wx, const float* __restrict__ Ws,
                 const float* __restrict__ Wt1,
                 ushort* __restrict__ Wxb, ushort* __restrict__ wb) {
    const int t = threadIdx.x;
    if (blockIdx.x < 64) {
        int idx = blockIdx.x * 2048 + t * 8;
        float4 a0 = *(const float4*)&Wx[idx];
        float4 a1 = *(const float4*)&Wx[idx + 4];
        ushort8 v = { f2bf(a0.x), f2bf(a0.y), f2bf(a0.z), f2bf(a0.w),
                      f2bf(a1.x), f2bf(a1.y), f2bf(a1.z), f2bf(a1.w) };
        *(ushort8*)&Wxb[idx] = v;
    } else {
        int idx = (blockIdx.x - 64) * 2048 + t * 8;   // 0..8191
        int row = idx >> 6, col = idx & 63;
        const float* src = (row < 64) ? &Ws[row * 64 + col]
                                      : &Wt1[(row - 64) * 64 + col];
        float4 a0 = *(const float4*)src;
        float4 a1 = *(const float4*)(src + 4);
        ushort8 v = { f2bf(a0.x), f2bf(a0.y), f2bf(a0.z), f2bf(a0.w),
                      f2bf(a1.x), f2bf(a1.y), f2bf(a1.z), f2bf(a1.w) };
        *(ushort8*)&wb[idx] = v;
    }
}

// ---------------------------------------------------------------------------
// Stage 1: xmb_bf16[M][512] = x_f32[M][256] @ Wxb^T + bx   (M=65536)
// ---------------------------------------------------------------------------
__global__ __launch_bounds__(256)
void gemm_xmid_kernel(const float* __restrict__ A, const ushort* __restrict__ B,
                      const float* __restrict__ bias, ushort* __restrict__ C) {
    __shared__ __align__(16) ushort Al[128][64];
    __shared__ __align__(16) ushort Bl[128][64];
    const int m0 = blockIdx.x * 128, n0 = blockIdx.y * 128;
    const int t = threadIdx.x, l = t & 63, w = t >> 6;
    const int wr = w >> 1, wc = w & 1;
    const int lr = l & 15, lq = l >> 4;

    f32x4 acc[4][4];
    #pragma unroll
    for (int mi = 0; mi < 4; ++mi)
        #pragma unroll
        for (int ni = 0; ni < 4; ++ni) acc[mi][ni] = (f32x4){0.f, 0.f, 0.f, 0.f};

    for (int ks = 0; ks < 4; ++ks) {          // K-step of 64 (K=256)
        __syncthreads();
        #pragma unroll
        for (int i = 0; i < 4; ++i) {
            int idx = i * 256 + t;            // 0..1023
            int row = idx >> 3, g = idx & 7;
            const float* ap = &A[(size_t)(m0 + row) * 256 + ks * 64 + g * 8];
            float4 a0 = *(const float4*)ap;
            float4 a1 = *(const float4*)(ap + 4);
            ushort8 av = { f2bf(a0.x), f2bf(a0.y), f2bf(a0.z), f2bf(a0.w),
                           f2bf(a1.x), f2bf(a1.y), f2bf(a1.z), f2bf(a1.w) };
            *(ushort8*)&Al[row][(g ^ (row & 7)) * 8] = av;
            ushort8 bv = *(const ushort8*)&B[(size_t)(n0 + row) * 256 + ks * 64 + g * 8];
            *(ushort8*)&Bl[row][(g ^ (row & 7)) * 8] = bv;
        }
        __syncthreads();
        #pragma unroll
        for (int kf = 0; kf < 2; ++kf) {
            short8 af[4], bfr[4];
            #pragma unroll
            for (int mi = 0; mi < 4; ++mi) {
                int row = wr * 64 + mi * 16 + lr, g = kf * 4 + lq;
                af[mi] = *(const short8*)&Al[row][(g ^ (row & 7)) * 8];
            }
            #pragma unroll
            for (int ni = 0; ni < 4; ++ni) {
                int row = wc * 64 + ni * 16 + lr, g = kf * 4 + lq;
                bfr[ni] = *(const short8*)&Bl[row][(g ^ (row & 7)) * 8];
            }
            #pragma unroll
            for (int mi = 0; mi < 4; ++mi)
                #pragma unroll
                for (int ni = 0; ni < 4; ++ni)
                    acc[mi][ni] = __builtin_amdgcn_mfma_f32_16x16x32_bf16(
                        af[mi], bfr[ni], acc[mi][ni], 0, 0, 0);
        }
    }
    #pragma unroll
    for (int ni = 0; ni < 4; ++ni) {
        int col = n0 + wc * 64 + ni * 16 + lr;
        float bb = bias[col];
        #pragma unroll
        for (int mi = 0; mi < 4; ++mi)
            #pragma unroll
            for (int j = 0; j < 4; ++j) {
                int row = m0 + wr * 64 + mi * 16 + lq * 4 + j;
                C[(size_t)row * 512 + col] = f2bf(acc[mi][ni][j] + bb);
            }
    }
}

// ---------------------------------------------------------------------------
// Stage 2: [lg | t1] = xmb_h @ wb^T (K=64) via MFMA; B-frags direct from
// global bf16 wb (L2-hot), A tile in 16KB LDS. Batched epilogue, log2/exp2.
// ---------------------------------------------------------------------------
__global__ __launch_bounds__(256)
void lgt1_mfma_kernel(const ushort* __restrict__ xmb,
                      const ushort* __restrict__ wb,
                      const float* __restrict__ bs,  const float* __restrict__ bt1,
                      const float* __restrict__ Wt2, const float* __restrict__ bt2,
                      const float* __restrict__ biasp,
                      const float* __restrict__ u,
                      ushort* __restrict__ swb) {
    __shared__ __align__(16) ushort Al[128][64];
    const int h = blockIdx.y, m0 = blockIdx.x * 128;
    const int t = threadIdx.x, l = t & 63, w = t >> 6;
    const int lr = l & 15, lq = l >> 4;
    const float LOG2E = 1.4426950408889634f;
    const float LN2   = 0.6931471805599453f;
    const float SH2   = 36.0673760222f;      // 25*log2e

    #pragma unroll
    for (int i = 0; i < 4; ++i) {
        int idx = i * 256 + t;               // 0..1023
        int row = idx >> 3, g = idx & 7;
        ushort8 av = *(const ushort8*)&xmb[(size_t)(m0 + row) * 512 + h * 64 + g * 8];
        *(ushort8*)&Al[row][(g ^ (row & 7)) * 8] = av;
    }

    float uu0[4][4];
    #pragma unroll
    for (int jj = 0; jj < 4; ++jj) {
        const int n = m0 + w * 32 + lq * 4 + jj;
        const float* up = &u[((size_t)h * NPTS + n) * 64 + lr];
        #pragma unroll
        for (int ni = 0; ni < 4; ++ni) uu0[jj][ni] = up[ni * 16];
    }
    __syncthreads();

    f32x4 acc[2][8];
    #pragma unroll
    for (int mi = 0; mi < 2; ++mi)
        #pragma unroll
        for (int ni = 0; ni < 8; ++ni) acc[mi][ni] = (f32x4){0.f, 0.f, 0.f, 0.f};

    #pragma unroll
    for (int kf = 0; kf < 2; ++kf) {
        const int g = kf * 4 + lq;
        short8 af[2], bfr[8];
        #pragma unroll
        for (int mi = 0; mi < 2; ++mi) {
            int row = w * 32 + mi * 16 + lr;
            af[mi] = *(const short8*)&Al[row][(g ^ (row & 7)) * 8];
        }
        #pragma unroll
        for (int ni = 0; ni < 8; ++ni)
            bfr[ni] = *(const short8*)&wb[(size_t)(ni * 16 + lr) * 64 + g * 8];
        #pragma unroll
        for (int mi = 0; mi < 2; ++mi)
            #pragma unroll
            for (int ni = 0; ni < 8; ++ni)
                acc[mi][ni] = __builtin_amdgcn_mfma_f32_16x16x32_bf16(
                    af[mi], bfr[ni], acc[mi][ni], 0, 0, 0);
    }

    float uu1[4][4];
    #pragma unroll
    for (int jj = 0; jj < 4; ++jj) {
        const int n = m0 + w * 32 + 16 + lq * 4 + jj;
        const float* up = &u[((size_t)h * NPTS + n) * 64 + lr];
        #pragma unroll
        for (int ni = 0; ni < 4; ++ni) uu1[jj][ni] = up[ni * 16];
    }

    const float bt2v = bt2[0], biasph = biasp[h];
    float bsr[4], bt1r[4], wt2r[4];
    #pragma unroll
    for (int ni = 0; ni < 4; ++ni) {
        bsr[ni]  = bs [ni * 16 + lr];
        bt1r[ni] = bt1[ni * 16 + lr];
        wt2r[ni] = Wt2[ni * 16 + lr];
    }

    #pragma unroll
    for (int mi = 0; mi < 2; ++mi) {
        float ts[4];
        #pragma unroll
        for (int jj = 0; jj < 4; ++jj) {
            float s = 0.f;
            #pragma unroll
            for (int ni = 0; ni < 4; ++ni)
                s += gelu_fast(acc[mi][ni + 4][jj] + bt1r[ni]) * wt2r[ni];
            ts[jj] = s;
        }
        #pragma unroll
        for (int off = 1; off <= 8; off <<= 1) {
            #pragma unroll
            for (int jj = 0; jj < 4; ++jj) ts[jj] += __shfl_xor(ts[jj], off);
        }
        float invt[4], invt2[4];
        #pragma unroll
        for (int jj = 0; jj < 4; ++jj) {
            float tmp = gelu_fast(ts[jj] + bt2v) + biasph;
            tmp = fmaxf(tmp, 0.01f);
            invt[jj]  = __builtin_amdgcn_rcpf(tmp);
            invt2[jj] = invt[jj] * LOG2E;
        }
        float sv[4][4], ps[4] = {0.f, 0.f, 0.f, 0.f};
        #pragma unroll
        for (int jj = 0; jj < 4; ++jj) {
            #pragma unroll
            for (int ni = 0; ni < 4; ++ni) {
                float uuv = (mi == 0 ? uu0[jj][ni] : uu1[jj][ni]);
                float L1 = __log2f(uuv + 1e-8f);
                float inner = fmaf(-LN2, L1, 1e-8f);
                float L2v = __log2f(inner);
                float base = fmaf(acc[mi][ni][jj] + bsr[ni], invt2[jj], -SH2);
                sv[jj][ni] = __builtin_amdgcn_exp2f(fmaf(-invt[jj], L2v, base));
                ps[jj] += sv[jj][ni];
            }
        }
        #pragma unroll
        for (int off = 1; off <= 8; off <<= 1) {
            #pragma unroll
            for (int jj = 0; jj < 4; ++jj) ps[jj] += __shfl_xor(ps[jj], off);
        }
        #pragma unroll
        for (int jj = 0; jj < 4; ++jj) {
            const int n = m0 + w * 32 + mi * 16 + lq * 4 + jj;
            const float inv = __builtin_amdgcn_rcpf(ps[jj]);
            ushort* sp = &swb[(size_t)n * 512 + h * 64 + lr];
            #pragma unroll
            for (int ni = 0; ni < 4; ++ni)
                sp[ni * 16] = f2bf(sv[jj][ni] * inv);
        }
    }
}

// ---------------------------------------------------------------------------
// Stage 3 (MFMA): per (h, 1024-pt chunk): C[g][c] = sum_n sw[n][g]*x[n][c]
// Cross-wave reduce via LDS. NOTE: single `tile` array — sred MUST span a
// guaranteed-contiguous 32KB (round-10 lesson: two separate __shared__
// arrays have no adjacency guarantee; aliasing past the first is UB).
// ---------------------------------------------------------------------------
__global__ __launch_bounds__(256)
void gather_mfma_kernel(const ushort* __restrict__ xmb, const ushort* __restrict__ swb,
                        float* __restrict__ stp, float* __restrict__ normp) {
    __shared__ __align__(16) ushort tile[2][64][128];   // [0]=swT, [1]=xT
    ushort (* __restrict__ swT)[128] = tile[0];
    ushort (* __restrict__ xT )[128] = tile[1];
    const int h  = blockIdx.y;
    const int n0 = blockIdx.x * 1024;
    const int t  = threadIdx.x, l = t & 63, w = t >> 6;
    const int lr = l & 15, lq = l >> 4;
    const int gb = t & 7;
    const int ng = t >> 3;

    f32x4 acc[4][4];
    #pragma unroll
    for (int gi = 0; gi < 4; ++gi)
        #pragma unroll
        for (int ci = 0; ci < 4; ++ci) acc[gi][ci] = (f32x4){0.f, 0.f, 0.f, 0.f};
    float nrm8[8];
    #pragma unroll
    for (int j = 0; j < 8; ++j) nrm8[j] = 0.f;

    for (int r = 0; r < 8; ++r) {
        const int nt = n0 + r * 128;
        ushort8 sv[4], xv[4];
        #pragma unroll
        for (int i = 0; i < 4; ++i) {
            int n = nt + ng * 4 + i;
            sv[i] = *(const ushort8*)&swb[(size_t)n * 512 + h * 64 + gb * 8];
            xv[i] = *(const ushort8*)&xmb[(size_t)n * 512 + h * 64 + gb * 8];
        }
        __syncthreads();
        #pragma unroll
        for (int j = 0; j < 8; ++j) {
            int g   = gb * 8 + j;
            int swz = (ng >> 1) ^ (g & 7) ^ ((g >> 3) & 7);
            int off = swz * 8 + (ng & 1) * 4;
            us4 s4 = { sv[0][j], sv[1][j], sv[2][j], sv[3][j] };
            us4 x4 = { xv[0][j], xv[1][j], xv[2][j], xv[3][j] };
            *(us4*)&swT[g][off] = s4;
            *(us4*)&xT [g][off] = x4;
            nrm8[j] += (bf2f(sv[0][j]) + bf2f(sv[1][j]))
                     + (bf2f(sv[2][j]) + bf2f(sv[3][j]));
        }
        __syncthreads();
        short8 af[4], bfr[4];
        #pragma unroll
        for (int gi = 0; gi < 4; ++gi) {
            int g   = gi * 16 + lr;
            int swz = (w * 4 + lq) ^ (g & 7) ^ ((g >> 3) & 7);
            af[gi]  = *(const short8*)&swT[g][swz * 8];
            bfr[gi] = *(const short8*)&xT [g][swz * 8];
        }
        #pragma unroll
        for (int gi = 0; gi < 4; ++gi)
            #pragma unroll
            for (int ci = 0; ci < 4; ++ci)
                acc[gi][ci] = __builtin_amdgcn_mfma_f32_16x16x32_bf16(
                    af[gi], bfr[ci], acc[gi][ci], 0, 0, 0);
    }

    // cross-wave reduce via LDS: sred[4 waves][32 rows][64 cols] f32 = 32KB,
    // guaranteed contiguous because it aliases the single `tile` array.
    float* sred = (float*)tile;
    const size_t stbase = ((size_t)h * 64 + blockIdx.x) * 4096;
    #pragma unroll
    for (int half = 0; half < 2; ++half) {
        __syncthreads();
        #pragma unroll
        for (int gg = 0; gg < 2; ++gg) {
            int gi = half * 2 + gg;
            #pragma unroll
            for (int ci = 0; ci < 4; ++ci)
                #pragma unroll
                for (int j = 0; j < 4; ++j)
                    sred[(w * 32 + gg * 16 + lq * 4 + j) * 64 + ci * 16 + lr]
                        = acc[gi][ci][j];
        }
        __syncthreads();
        #pragma unroll
        for (int i = 0; i < 8; ++i) {
            int e = i * 256 + t;            // 0..2047
            float s = (sred[e] + sred[2048 + e]) + (sred[4096 + e] + sred[6144 + e]);
            stp[stbase + half * 2048 + e] = s;
        }
    }

    // norm partials -> LDS reduce -> normp[h][block][g]
    __syncthreads();
    float* narr = (float*)tile;     // 32*64 f32 = 8 KB
    #pragma unroll
    for (int j = 0; j < 8; ++j) narr[ng * 64 + gb * 8 + j] = nrm8[j];
    __syncthreads();
    if (t < 64) {
        float s = 0.f;
        #pragma unroll 8
        for (int k = 0; k < 32; ++k) s += narr[k * 64 + t];
        normp[((size_t)h * 64 + blockIdx.x) * 64 + t] = s;
    }
}

// ---------------------------------------------------------------------------
// Stage 4a: reduce chunk partials -> st_red, nrm
// ---------------------------------------------------------------------------
__global__ __launch_bounds__(256)
void reduce_st_kernel(const float* __restrict__ stp, const float* __restrict__ normp,
                      float* __restrict__ st_red, float* __restrict__ nrm) {
    const int h = blockIdx.x;
    const int e = blockIdx.y * 256 + threadIdx.x;
    float s = 0.f;
    #pragma unroll 8
    for (int ch = 0; ch < 64; ++ch)
        s += stp[((size_t)h * 64 + ch) * 4096 + e];
    st_red[(size_t)h * 4096 + e] = s;
    if (blockIdx.y == 0 && threadIdx.x < 64) {
        float ns = 0.f;
        #pragma unroll 8
        for (int ch = 0; ch < 64; ++ch)
            ns += normp[((size_t)h * 64 + ch) * 64 + threadIdx.x];
        nrm[h * 64 + threadIdx.x] = ns + 1e-5f;
    }
}

// ---------------------------------------------------------------------------
// Stage 4b: per head: normalize tokens, qkv, 64x64 attention -> osl
// ---------------------------------------------------------------------------
__global__ __launch_bounds__(256)
void attn_small_kernel(const float* __restrict__ st_red, const float* __restrict__ nrm,
                       const float* __restrict__ Wq, const float* __restrict__ Wk,
                       const float* __restrict__ Wv, float* __restrict__ osl) {
    __shared__ float st[64][68];
    __shared__ float ql[64][68];
    __shared__ float kl[64][68];
    __shared__ float vl[64][68];
    __shared__ float sc[64][68];
    __shared__ float nl[64];
    const int h = blockIdx.x;
    const int t = threadIdx.x;

    if (t < 64) nl[t] = nrm[h * 64 + t];
    __syncthreads();
    for (int e = t; e < 4096; e += 256)
        st[e>>6][e&63] = st_red[(size_t)h * 4096 + e] / nl[e>>6];
    __syncthreads();
    for (int e = t; e < 4096; e += 256) {
        int g = e >> 6, dd = e & 63;
        float aq = 0.f, ak = 0.f, av = 0.f;
        for (int cc = 0; cc < 64; ++cc) {
            float sv = st[g][cc];
            aq = fmaf(sv, Wq[dd*64 + cc], aq);
            ak = fmaf(sv, Wk[dd*64 + cc], ak);
            av = fmaf(sv, Wv[dd*64 + cc], av);
        }
        ql[g][dd] = aq; kl[g][dd] = ak; vl[g][dd] = av;
    }
    __syncthreads();
    for (int e = t; e < 4096; e += 256) {
        int g = e >> 6, gp = e & 63;
        float s = 0.f;
        for (int dd = 0; dd < 64; ++dd) s = fmaf(ql[g][dd], kl[gp][dd], s);
        sc[g][gp] = s * 0.125f;
    }
    __syncthreads();
    if (t < 64) {
        float m = -1e30f;
        for (int j = 0; j < 64; ++j) m = fmaxf(m, sc[t][j]);
        float ssum = 0.f;
        for (int j = 0; j < 64; ++j) { float p = expf(sc[t][j] - m); sc[t][j] = p; ssum += p; }
        float inv = 1.f / ssum;
        for (int j = 0; j < 64; ++j) sc[t][j] *= inv;
    }
    __syncthreads();
    for (int e = t; e < 4096; e += 256) {
        int g = e >> 6, dd = e & 63;
        float s = 0.f;
        for (int gp = 0; gp < 64; ++gp) s = fmaf(sc[g][gp], vl[gp][dd], s);
        osl[(size_t)h * 4096 + e] = s;
    }
}

// ---------------------------------------------------------------------------
// Stage 4c: fold out_slice into Wout: Mtb[i][h*64+g] (bf16 output)
// ---------------------------------------------------------------------------
__global__ __launch_bounds__(256)
void fold_kernel(const float* __restrict__ osl, const float* __restrict__ Wout,
                 ushort* __restrict__ Mtb) {
    __shared__ float os[64][65];
    __shared__ float wl[128][65];
    const int h  = blockIdx.x;
    const int i0 = blockIdx.y * 128;
    const int t  = threadIdx.x;
    for (int e = t; e < 4096; e += 256) os[e>>6][e&63] = osl[(size_t)h * 4096 + e];
    for (int e = t; e < 8192; e += 256) {
        int i = e >> 6, d = e & 63;
        wl[i][d] = Wout[(size_t)(i0 + i) * HDIM + h * 64 + d];
    }
    __syncthreads();
    const int g = t & 63, iq = t >> 6;
    #pragma unroll 4
    for (int k = 0; k < 32; ++k) {
        int i = iq * 32 + k;
        float s = 0.f;
        #pragma unroll
        for (int d = 0; d < 64; ++d) s = fmaf(os[g][d], wl[i][d], s);
        Mtb[(size_t)(i0 + i) * HDIM + h * 64 + g] = f2bf(s);
    }
}

// ---------------------------------------------------------------------------
// Stage 5: out_f32[M][256] = swb_bf16[M][512] @ Mtb^T + bout
// ---------------------------------------------------------------------------
__global__ __launch_bounds__(256)
void gemm_out_kernel(const ushort* __restrict__ A, const ushort* __restrict__ B,
                     const float* __restrict__ bias, float* __restrict__ C) {
    __shared__ __align__(16) ushort Al[128][64];
    __shared__ __align__(16) ushort Bl[128][64];
    const int m0 = blockIdx.x * 128, n0 = blockIdx.y * 128;
    const int t = threadIdx.x, l = t & 63, w = t >> 6;
    const int wr = w >> 1, wc = w & 1;
    const int lr = l & 15, lq = l >> 4;

    f32x4 acc[4][4];
    #pragma unroll
    for (int mi = 0; mi < 4; ++mi)
        #pragma unroll
        for (int ni = 0; ni < 4; ++ni) acc[mi][ni] = (f32x4){0.f, 0.f, 0.f, 0.f};

    for (int ks = 0; ks < 8; ++ks) {          // K-step of 64 (K=512)
        __syncthreads();
        #pragma unroll
        for (int i = 0; i < 4; ++i) {
            int idx = i * 256 + t;
            int row = idx >> 3, g = idx & 7;
            ushort8 av = *(const ushort8*)&A[(size_t)(m0 + row) * 512 + ks * 64 + g * 8];
            *(ushort8*)&Al[row][(g ^ (row & 7)) * 8] = av;
            ushort8 bv = *(const ushort8*)&B[(size_t)(n0 + row) * 512 + ks * 64 + g * 8];
            *(ushort8*)&Bl[row][(g ^ (row & 7)) * 8] = bv;
        }
        __syncthreads();
        #pragma unroll
        for (int kf = 0; kf < 2; ++kf) {
            short8 af[4], bfr[4];
            #pragma unroll
            for (int mi = 0; mi < 4; ++mi) {
                int row = wr * 64 + mi * 16 + lr, g = kf * 4 + lq;
                af[mi] = *(const short8*)&Al[row][(g ^ (row & 7)) * 8];
            }
            #pragma unroll
            for (int ni = 0; ni < 4; ++ni) {
                int row = wc * 64 + ni * 16 + lr, g = kf * 4 + lq;
                bfr[ni] = *(const short8*)&Bl[row][(g ^ (row & 7)) * 8];
            }
            #pragma unroll
            for (int mi = 0; mi < 4; ++mi)
                #pragma unroll
                for (int ni = 0; ni < 4; ++ni)
                    acc[mi][ni] = __builtin_amdgcn_mfma_f32_16x16x32_bf16(
                        af[mi], bfr[ni], acc[mi][ni], 0, 0, 0);
        }
    }
    #pragma unroll
    for (int ni = 0; ni < 4; ++ni) {
        int col = n0 + wc * 64 + ni * 16 + lr;
        float bb = bias[col];
        #pragma unroll
        for (int mi = 0; mi < 4; ++mi)
            #pragma unroll
            for (int j = 0; j < 4; ++j) {
                int row = m0 + wr * 64 + mi * 16 + lq * 4 + j;
                C[(size_t)row * 256 + col] = acc[mi][ni][j] + bb;
            }
    }
}

// ---------------------------------------------------------------------------
extern "C" void kernel_launch(void* const* d_in, const int* in_sizes, int n_in,
                              void* d_out, int out_size, void* d_ws, size_t ws_size,
                              hipStream_t stream) {
    const float* x    = (const float*)d_in[0];
    const float* Wx   = (const float*)d_in[1];
    const float* bx   = (const float*)d_in[2];
    const float* Wt1  = (const float*)d_in[3];
    const float* bt1  = (const float*)d_in[4];
    const float* Wt2  = (const float*)d_in[5];
    const float* bt2  = (const float*)d_in[6];
    const float* biasp= (const float*)d_in[7];
    const float* Ws   = (const float*)d_in[8];
    const float* bs   = (const float*)d_in[9];
    const float* Wq   = (const float*)d_in[10];
    const float* Wk   = (const float*)d_in[11];
    const float* Wv   = (const float*)d_in[12];
    const float* Wout = (const float*)d_in[13];
    const float* bout = (const float*)d_in[14];
    const float* u    = (const float*)d_in[15];
    float* out = (float*)d_out;

    float*  stp    = (float*)d_ws;                           // 8*64*4096 f32 = 8.4 MB
    float*  normp  = stp    + (size_t)NH * 64 * 4096;        // 8*64*64
    float*  st_red = normp  + (size_t)NH * 64 * 64;          // 8*4096
    float*  nrm    = st_red + (size_t)NH * 4096;             // 8*64
    float*  osl    = nrm    + (size_t)NH * 64;               // 8*4096
    ushort* wb     = (ushort*)(osl + (size_t)NH * 4096);     // 128*64 bf16
    ushort* Wxb    = wb  + (size_t)128 * 64;                 // 512*256 bf16
    ushort* Mtb    = Wxb + (size_t)HDIM * DIMX;              // 256*512 bf16
    ushort* xmb    = Mtb + (size_t)DIMX * HDIM;              // 65536*512 bf16
    ushort* swb    = xmb + (size_t)NPTS * HDIM;              // 65536*512 bf16

    // 0) pre-convert Wx and [Ws;Wt1] to bf16
    prep_kernel<<<68, 256, 0, stream>>>(Wx, Ws, Wt1, Wxb, wb);
    // 1) xmid (bf16) = x @ Wx^T + bx
    gemm_xmid_kernel<<<dim3(512, 4), 256, 0, stream>>>(x, Wxb, bx, xmb);
    // 2) fused logits/temp MFMA GEMM + gumbel softmax -> sw (bf16)
    lgt1_mfma_kernel<<<dim3(512, 8), 256, 0, stream>>>(xmb, wb, bs, bt1,
                                                       Wt2, bt2, biasp, u, swb);
    // 3) slice token partials via MFMA (in-block cross-wave reduce)
    gather_mfma_kernel<<<dim3(64, 8), 256, 0, stream>>>(xmb, swb, stp, normp);
    // 4a) reduce partials
    reduce_st_kernel<<<dim3(8, 16), 256, 0, stream>>>(stp, normp, st_red, nrm);
    // 4b) tiny attention
    attn_small_kernel<<<8, 256, 0, stream>>>(st_red, nrm, Wq, Wk, Wv, osl);
    // 4c) fold out_slice into Wout (bf16 output)
    fold_kernel<<<dim3(8, 2), 256, 0, stream>>>(osl, Wout, Mtb);
    // 5) out = sw @ Mtb^T + bout
    gemm_out_kernel<<<dim3(512, 2), 256, 0, stream>>>(swb, Mtb, bout, out);
}

// Round 12
// 263.074 us; speedup vs baseline: 5.1500x; 1.0113x over previous
//
#include <hip/hip_runtime.h>
#include <math.h>

// Physics_Attention: B=1, N=65536, DIM=256, H=8, D=64, G=64
#define NPTS  65536
#define DIMX  256
#define NH    8
#define HDIM  512   // H*D

typedef __attribute__((ext_vector_type(4))) float f32x4;
typedef __attribute__((ext_vector_type(8))) short short8;
typedef __attribute__((ext_vector_type(8))) unsigned short ushort8;
typedef __attribute__((ext_vector_type(4))) unsigned short us4;

__device__ __forceinline__ ushort f2bf(float f) {   // RNE f32->bf16
    unsigned x = __float_as_uint(f);
    return (ushort)((x + 0x7fffu + ((x >> 16) & 1u)) >> 16);
}
__device__ __forceinline__ float bf2f(ushort u) {
    return __uint_as_float((unsigned)u << 16);
}
// Fast erf (A&S 7.1.26, abs err 1.5e-7) — no branches, HW exp/rcp
__device__ __forceinline__ float erf_fast(float x) {
    float ax = fabsf(x);
    float t  = __builtin_amdgcn_rcpf(1.0f + 0.3275911f * ax);
    float p  = fmaf(fmaf(fmaf(fmaf(1.061405429f, t, -1.453152027f), t,
                   1.421413741f), t, -0.284496736f), t, 0.254829592f) * t;
    float y  = 1.0f - p * __expf(-ax * ax);
    return copysignf(y, x);
}
__device__ __forceinline__ float gelu_fast(float x) {
    return 0.5f * x * (1.0f + erf_fast(x * 0.7071067811865476f));
}

// ---------------------------------------------------------------------------
// Stage 0: pre-convert Wx (512x256) and [Ws;Wt1] (128x64) to bf16.
// ---------------------------------------------------------------------------
__global__ __launch_bounds__(256)
void prep_kernel(const float* __restrict__ Wx, const float* __restrict__ Ws,
                 const float* __restrict__ Wt1,
                 ushort* __restrict__ Wxb, ushort* __restrict__ wb) {
    const int t = threadIdx.x;
    if (blockIdx.x < 64) {
        int idx = blockIdx.x * 2048 + t * 8;
        float4 a0 = *(const float4*)&Wx[idx];
        float4 a1 = *(const float4*)&Wx[idx + 4];
        ushort8 v = { f2bf(a0.x), f2bf(a0.y), f2bf(a0.z), f2bf(a0.w),
                      f2bf(a1.x), f2bf(a1.y), f2bf(a1.z), f2bf(a1.w) };
        *(ushort8*)&Wxb[idx] = v;
    } else {
        int idx = (blockIdx.x - 64) * 2048 + t * 8;   // 0..8191
        int row = idx >> 6, col = idx & 63;
        const float* src = (row < 64) ? &Ws[row * 64 + col]
                                      : &Wt1[(row - 64) * 64 + col];
        float4 a0 = *(const float4*)src;
        float4 a1 = *(const float4*)(src + 4);
        ushort8 v = { f2bf(a0.x), f2bf(a0.y), f2bf(a0.z), f2bf(a0.w),
                      f2bf(a1.x), f2bf(a1.y), f2bf(a1.z), f2bf(a1.w) };
        *(ushort8*)&wb[idx] = v;
    }
}

// ---------------------------------------------------------------------------
// Stage 1+2 FUSED: per (128-pt tile, head-pair hp):
//   xmid tile [128 rows][128 cols = heads 2hp..2hp+1] via MFMA (K=256),
//   -> bf16 into LDS pool (reused Al/Bl space, single array = contiguous)
//   -> vectorized copy-out to xmb
//   -> per head: [lg|t1] = xmid_h @ wb^T (A-frags from LDS, B from L2 wb),
//      temp-MLP + gumbel softmax epilogue, write swb.
// ---------------------------------------------------------------------------
__global__ __launch_bounds__(256)
void xmid_lgt1_kernel(const float* __restrict__ A, const ushort* __restrict__ B,
                      const float* __restrict__ bias,
                      const ushort* __restrict__ wb,
                      const float* __restrict__ bs,  const float* __restrict__ bt1,
                      const float* __restrict__ Wt2, const float* __restrict__ bt2,
                      const float* __restrict__ biasp,
                      const float* __restrict__ u,
                      ushort* __restrict__ xmb, ushort* __restrict__ swb) {
    __shared__ __align__(16) ushort pool[2][128][64];   // Al/Bl, then Xl[128][128]
    const int hp = blockIdx.y;                 // head pair 0..3
    const int m0 = blockIdx.x * 128, n0 = hp * 128;
    const int t = threadIdx.x, l = t & 63, w = t >> 6;
    const int wr = w >> 1, wc = w & 1;
    const int lr = l & 15, lq = l >> 4;
    const float LOG2E = 1.4426950408889634f;
    const float LN2   = 0.6931471805599453f;
    const float SH2   = 36.0673760222f;        // 25*log2e

    // ---------------- phase 1: xmid GEMM (K=256) ----------------
    f32x4 acc[4][4];
    #pragma unroll
    for (int mi = 0; mi < 4; ++mi)
        #pragma unroll
        for (int ni = 0; ni < 4; ++ni) acc[mi][ni] = (f32x4){0.f, 0.f, 0.f, 0.f};

    for (int ks = 0; ks < 4; ++ks) {
        __syncthreads();
        #pragma unroll
        for (int i = 0; i < 4; ++i) {
            int idx = i * 256 + t;             // 0..1023
            int row = idx >> 3, g = idx & 7;
            const float* ap = &A[(size_t)(m0 + row) * 256 + ks * 64 + g * 8];
            float4 a0 = *(const float4*)ap;
            float4 a1 = *(const float4*)(ap + 4);
            ushort8 av = { f2bf(a0.x), f2bf(a0.y), f2bf(a0.z), f2bf(a0.w),
                           f2bf(a1.x), f2bf(a1.y), f2bf(a1.z), f2bf(a1.w) };
            *(ushort8*)&pool[0][row][(g ^ (row & 7)) * 8] = av;
            ushort8 bv = *(const ushort8*)&B[(size_t)(n0 + row) * 256 + ks * 64 + g * 8];
            *(ushort8*)&pool[1][row][(g ^ (row & 7)) * 8] = bv;
        }
        __syncthreads();
        #pragma unroll
        for (int kf = 0; kf < 2; ++kf) {
            short8 af[4], bfr[4];
            #pragma unroll
            for (int mi = 0; mi < 4; ++mi) {
                int row = wr * 64 + mi * 16 + lr, g = kf * 4 + lq;
                af[mi] = *(const short8*)&pool[0][row][(g ^ (row & 7)) * 8];
            }
            #pragma unroll
            for (int ni = 0; ni < 4; ++ni) {
                int row = wc * 64 + ni * 16 + lr, g = kf * 4 + lq;
                bfr[ni] = *(const short8*)&pool[1][row][(g ^ (row & 7)) * 8];
            }
            #pragma unroll
            for (int mi = 0; mi < 4; ++mi)
                #pragma unroll
                for (int ni = 0; ni < 4; ++ni)
                    acc[mi][ni] = __builtin_amdgcn_mfma_f32_16x16x32_bf16(
                        af[mi], bfr[ni], acc[mi][ni], 0, 0, 0);
        }
    }

    // ---------------- xmid tile -> LDS (Xl) + global xmb ----------------
    __syncthreads();                            // all frag reads of pool done
    ushort (* __restrict__ Xl)[128] = (ushort (*)[128])(&pool[0][0][0]);
    #pragma unroll
    for (int ni = 0; ni < 4; ++ni) {
        int colL = wc * 64 + ni * 16 + lr;      // local col 0..127
        float bb = bias[n0 + colL];
        int gg = colL >> 3, c7 = colL & 7;
        #pragma unroll
        for (int mi = 0; mi < 4; ++mi)
            #pragma unroll
            for (int j = 0; j < 4; ++j) {
                int row = wr * 64 + mi * 16 + lq * 4 + j;
                Xl[row][(gg ^ (row & 7)) * 8 + c7] = f2bf(acc[mi][ni][j] + bb);
            }
    }
    __syncthreads();
    // vectorized copy-out to xmb (coalesced 16B stores)
    #pragma unroll
    for (int i = 0; i < 8; ++i) {
        int e = i * 256 + t;                    // 0..2047
        int row = e >> 4, gg = e & 15;
        ushort8 v = *(const ushort8*)&Xl[row][(gg ^ (row & 7)) * 8];
        *(ushort8*)&xmb[(size_t)(m0 + row) * 512 + n0 + gg * 8] = v;
    }

    // ---------------- phase 2: lgt1 per head ----------------
    const float bt2v = bt2[0];
    float bsr[4], bt1r[4], wt2r[4];
    #pragma unroll
    for (int ni = 0; ni < 4; ++ni) {
        bsr[ni]  = bs [ni * 16 + lr];
        bt1r[ni] = bt1[ni * 16 + lr];
        wt2r[ni] = Wt2[ni * 16 + lr];
    }

    #pragma unroll
    for (int hh = 0; hh < 2; ++hh) {
        const int h = hp * 2 + hh;
        const float biasph = biasp[h];

        f32x4 acc2[2][8];
        #pragma unroll
        for (int mi = 0; mi < 2; ++mi)
            #pragma unroll
            for (int ni = 0; ni < 8; ++ni) acc2[mi][ni] = (f32x4){0.f, 0.f, 0.f, 0.f};

        #pragma unroll
        for (int kf = 0; kf < 2; ++kf) {
            const int g = kf * 4 + lq;
            short8 af[2], bfr[8];
            #pragma unroll
            for (int mi = 0; mi < 2; ++mi) {
                int row = w * 32 + mi * 16 + lr;
                int gg = hh * 8 + g;
                af[mi] = *(const short8*)&Xl[row][(gg ^ (row & 7)) * 8];
            }
            #pragma unroll
            for (int ni = 0; ni < 8; ++ni)      // direct from global wb (L2-hot)
                bfr[ni] = *(const short8*)&wb[(size_t)(ni * 16 + lr) * 64 + g * 8];
            #pragma unroll
            for (int mi = 0; mi < 2; ++mi)
                #pragma unroll
                for (int ni = 0; ni < 8; ++ni)
                    acc2[mi][ni] = __builtin_amdgcn_mfma_f32_16x16x32_bf16(
                        af[mi], bfr[ni], acc2[mi][ni], 0, 0, 0);
        }

        #pragma unroll
        for (int mi = 0; mi < 2; ++mi) {
            // just-in-time u loads (hidden under the gelu chains below)
            float uu[4][4];
            #pragma unroll
            for (int jj = 0; jj < 4; ++jj) {
                const int n = m0 + w * 32 + mi * 16 + lq * 4 + jj;
                const float* up = &u[((size_t)h * NPTS + n) * 64 + lr];
                #pragma unroll
                for (int ni = 0; ni < 4; ++ni) uu[jj][ni] = up[ni * 16];
            }
            // phase A: 16 independent gelu partials (t1 cols = ni 4..7)
            float ts[4];
            #pragma unroll
            for (int jj = 0; jj < 4; ++jj) {
                float s = 0.f;
                #pragma unroll
                for (int ni = 0; ni < 4; ++ni)
                    s += gelu_fast(acc2[mi][ni + 4][jj] + bt1r[ni]) * wt2r[ni];
                ts[jj] = s;
            }
            #pragma unroll
            for (int off = 1; off <= 8; off <<= 1) {
                #pragma unroll
                for (int jj = 0; jj < 4; ++jj) ts[jj] += __shfl_xor(ts[jj], off);
            }
            float invt[4], invt2[4];
            #pragma unroll
            for (int jj = 0; jj < 4; ++jj) {
                float tmp = gelu_fast(ts[jj] + bt2v) + biasph;
                tmp = fmaxf(tmp, 0.01f);
                invt[jj]  = __builtin_amdgcn_rcpf(tmp);
                invt2[jj] = invt[jj] * LOG2E;
            }
            float sv[4][4], ps[4] = {0.f, 0.f, 0.f, 0.f};
            #pragma unroll
            for (int jj = 0; jj < 4; ++jj) {
                #pragma unroll
                for (int ni = 0; ni < 4; ++ni) {
                    float L1 = __log2f(uu[jj][ni] + 1e-8f);
                    float inner = fmaf(-LN2, L1, 1e-8f);
                    float L2v = __log2f(inner);
                    float base = fmaf(acc2[mi][ni][jj] + bsr[ni], invt2[jj], -SH2);
                    sv[jj][ni] = __builtin_amdgcn_exp2f(fmaf(-invt[jj], L2v, base));
                    ps[jj] += sv[jj][ni];
                }
            }
            #pragma unroll
            for (int off = 1; off <= 8; off <<= 1) {
                #pragma unroll
                for (int jj = 0; jj < 4; ++jj) ps[jj] += __shfl_xor(ps[jj], off);
            }
            #pragma unroll
            for (int jj = 0; jj < 4; ++jj) {
                const int n = m0 + w * 32 + mi * 16 + lq * 4 + jj;
                const float inv = __builtin_amdgcn_rcpf(ps[jj]);
                ushort* sp = &swb[(size_t)n * 512 + h * 64 + lr];
                #pragma unroll
                for (int ni = 0; ni < 4; ++ni)
                    sp[ni * 16] = f2bf(sv[jj][ni] * inv);
            }
        }
    }
}

// ---------------------------------------------------------------------------
// Stage 3 (MFMA): per (h, 1024-pt chunk): C[g][c] = sum_n sw[n][g]*x[n][c]
// Cross-wave reduce via LDS (single contiguous `tile` array).
// ---------------------------------------------------------------------------
__global__ __launch_bounds__(256)
void gather_mfma_kernel(const ushort* __restrict__ xmb, const ushort* __restrict__ swb,
                        float* __restrict__ stp, float* __restrict__ normp) {
    __shared__ __align__(16) ushort tile[2][64][128];   // [0]=swT, [1]=xT
    ushort (* __restrict__ swT)[128] = tile[0];
    ushort (* __restrict__ xT )[128] = tile[1];
    const int h  = blockIdx.y;
    const int n0 = blockIdx.x * 1024;
    const int t  = threadIdx.x, l = t & 63, w = t >> 6;
    const int lr = l & 15, lq = l >> 4;
    const int gb = t & 7;
    const int ng = t >> 3;

    f32x4 acc[4][4];
    #pragma unroll
    for (int gi = 0; gi < 4; ++gi)
        #pragma unroll
        for (int ci = 0; ci < 4; ++ci) acc[gi][ci] = (f32x4){0.f, 0.f, 0.f, 0.f};
    float nrm8[8];
    #pragma unroll
    for (int j = 0; j < 8; ++j) nrm8[j] = 0.f;

    for (int r = 0; r < 8; ++r) {
        const int nt = n0 + r * 128;
        ushort8 sv[4], xv[4];
        #pragma unroll
        for (int i = 0; i < 4; ++i) {
            int n = nt + ng * 4 + i;
            sv[i] = *(const ushort8*)&swb[(size_t)n * 512 + h * 64 + gb * 8];
            xv[i] = *(const ushort8*)&xmb[(size_t)n * 512 + h * 64 + gb * 8];
        }
        __syncthreads();
        #pragma unroll
        for (int j = 0; j < 8; ++j) {
            int g   = gb * 8 + j;
            int swz = (ng >> 1) ^ (g & 7) ^ ((g >> 3) & 7);
            int off = swz * 8 + (ng & 1) * 4;
            us4 s4 = { sv[0][j], sv[1][j], sv[2][j], sv[3][j] };
            us4 x4 = { xv[0][j], xv[1][j], xv[2][j], xv[3][j] };
            *(us4*)&swT[g][off] = s4;
            *(us4*)&xT [g][off] = x4;
            nrm8[j] += (bf2f(sv[0][j]) + bf2f(sv[1][j]))
                     + (bf2f(sv[2][j]) + bf2f(sv[3][j]));
        }
        __syncthreads();
        short8 af[4], bfr[4];
        #pragma unroll
        for (int gi = 0; gi < 4; ++gi) {
            int g   = gi * 16 + lr;
            int swz = (w * 4 + lq) ^ (g & 7) ^ ((g >> 3) & 7);
            af[gi]  = *(const short8*)&swT[g][swz * 8];
            bfr[gi] = *(const short8*)&xT [g][swz * 8];
        }
        #pragma unroll
        for (int gi = 0; gi < 4; ++gi)
            #pragma unroll
            for (int ci = 0; ci < 4; ++ci)
                acc[gi][ci] = __builtin_amdgcn_mfma_f32_16x16x32_bf16(
                    af[gi], bfr[ci], acc[gi][ci], 0, 0, 0);
    }

    // cross-wave reduce via LDS: sred[4][32][64] f32 = 32KB (contiguous)
    float* sred = (float*)tile;
    const size_t stbase = ((size_t)h * 64 + blockIdx.x) * 4096;
    #pragma unroll
    for (int half = 0; half < 2; ++half) {
        __syncthreads();
        #pragma unroll
        for (int gg = 0; gg < 2; ++gg) {
            int gi = half * 2 + gg;
            #pragma unroll
            for (int ci = 0; ci < 4; ++ci)
                #pragma unroll
                for (int j = 0; j < 4; ++j)
                    sred[(w * 32 + gg * 16 + lq * 4 + j) * 64 + ci * 16 + lr]
                        = acc[gi][ci][j];
        }
        __syncthreads();
        #pragma unroll
        for (int i = 0; i < 8; ++i) {
            int e = i * 256 + t;            // 0..2047
            float s = (sred[e] + sred[2048 + e]) + (sred[4096 + e] + sred[6144 + e]);
            stp[stbase + half * 2048 + e] = s;
        }
    }

    __syncthreads();
    float* narr = (float*)tile;
    #pragma unroll
    for (int j = 0; j < 8; ++j) narr[ng * 64 + gb * 8 + j] = nrm8[j];
    __syncthreads();
    if (t < 64) {
        float s = 0.f;
        #pragma unroll 8
        for (int k = 0; k < 32; ++k) s += narr[k * 64 + t];
        normp[((size_t)h * 64 + blockIdx.x) * 64 + t] = s;
    }
}

// ---------------------------------------------------------------------------
// Stage 4a: reduce chunk partials -> st_red, nrm
// ---------------------------------------------------------------------------
__global__ __launch_bounds__(256)
void reduce_st_kernel(const float* __restrict__ stp, const float* __restrict__ normp,
                      float* __restrict__ st_red, float* __restrict__ nrm) {
    const int h = blockIdx.x;
    const int e = blockIdx.y * 256 + threadIdx.x;
    float s = 0.f;
    #pragma unroll 8
    for (int ch = 0; ch < 64; ++ch)
        s += stp[((size_t)h * 64 + ch) * 4096 + e];
    st_red[(size_t)h * 4096 + e] = s;
    if (blockIdx.y == 0 && threadIdx.x < 64) {
        float ns = 0.f;
        #pragma unroll 8
        for (int ch = 0; ch < 64; ++ch)
            ns += normp[((size_t)h * 64 + ch) * 64 + threadIdx.x];
        nrm[h * 64 + threadIdx.x] = ns + 1e-5f;
    }
}

// ---------------------------------------------------------------------------
// Stage 4b: per head: normalize tokens, qkv, 64x64 attention -> osl
// ---------------------------------------------------------------------------
__global__ __launch_bounds__(256)
void attn_small_kernel(const float* __restrict__ st_red, const float* __restrict__ nrm,
                       const float* __restrict__ Wq, const float* __restrict__ Wk,
                       const float* __restrict__ Wv, float* __restrict__ osl) {
    __shared__ float st[64][68];
    __shared__ float ql[64][68];
    __shared__ float kl[64][68];
    __shared__ float vl[64][68];
    __shared__ float sc[64][68];
    __shared__ float nl[64];
    const int h = blockIdx.x;
    const int t = threadIdx.x;

    if (t < 64) nl[t] = nrm[h * 64 + t];
    __syncthreads();
    for (int e = t; e < 4096; e += 256)
        st[e>>6][e&63] = st_red[(size_t)h * 4096 + e] / nl[e>>6];
    __syncthreads();
    for (int e = t; e < 4096; e += 256) {
        int g = e >> 6, dd = e & 63;
        float aq = 0.f, ak = 0.f, av = 0.f;
        for (int cc = 0; cc < 64; ++cc) {
            float sv = st[g][cc];
            aq = fmaf(sv, Wq[dd*64 + cc], aq);
            ak = fmaf(sv, Wk[dd*64 + cc], ak);
            av = fmaf(sv, Wv[dd*64 + cc], av);
        }
        ql[g][dd] = aq; kl[g][dd] = ak; vl[g][dd] = av;
    }
    __syncthreads();
    for (int e = t; e < 4096; e += 256) {
        int g = e >> 6, gp = e & 63;
        float s = 0.f;
        for (int dd = 0; dd < 64; ++dd) s = fmaf(ql[g][dd], kl[gp][dd], s);
        sc[g][gp] = s * 0.125f;
    }
    __syncthreads();
    if (t < 64) {
        float m = -1e30f;
        for (int j = 0; j < 64; ++j) m = fmaxf(m, sc[t][j]);
        float ssum = 0.f;
        for (int j = 0; j < 64; ++j) { float p = expf(sc[t][j] - m); sc[t][j] = p; ssum += p; }
        float inv = 1.f / ssum;
        for (int j = 0; j < 64; ++j) sc[t][j] *= inv;
    }
    __syncthreads();
    for (int e = t; e < 4096; e += 256) {
        int g = e >> 6, dd = e & 63;
        float s = 0.f;
        for (int gp = 0; gp < 64; ++gp) s = fmaf(sc[g][gp], vl[gp][dd], s);
        osl[(size_t)h * 4096 + e] = s;
    }
}

// ---------------------------------------------------------------------------
// Stage 4c: fold out_slice into Wout: Mtb[i][h*64+g] (bf16 output)
// ---------------------------------------------------------------------------
__global__ __launch_bounds__(256)
void fold_kernel(const float* __restrict__ osl, const float* __restrict__ Wout,
                 ushort* __restrict__ Mtb) {
    __shared__ float os[64][65];
    __shared__ float wl[128][65];
    const int h  = blockIdx.x;
    const int i0 = blockIdx.y * 128;
    const int t  = threadIdx.x;
    for (int e = t; e < 4096; e += 256) os[e>>6][e&63] = osl[(size_t)h * 4096 + e];
    for (int e = t; e < 8192; e += 256) {
        int i = e >> 6, d = e & 63;
        wl[i][d] = Wout[(size_t)(i0 + i) * HDIM + h * 64 + d];
    }
    __syncthreads();
    const int g = t & 63, iq = t >> 6;
    #pragma unroll 4
    for (int k = 0; k < 32; ++k) {
        int i = iq * 32 + k;
        float s = 0.f;
        #pragma unroll
        for (int d = 0; d < 64; ++d) s = fmaf(os[g][d], wl[i][d], s);
        Mtb[(size_t)(i0 + i) * HDIM + h * 64 + g] = f2bf(s);
    }
}

// ---------------------------------------------------------------------------
// Stage 5: out_f32[M][256] = swb_bf16[M][512] @ Mtb^T + bout
// ---------------------------------------------------------------------------
__global__ __launch_bounds__(256)
void gemm_out_kernel(const ushort* __restrict__ A, const ushort* __restrict__ B,
                     const float* __restrict__ bias, float* __restrict__ C) {
    __shared__ __align__(16) ushort Al[128][64];
    __shared__ __align__(16) ushort Bl[128][64];
    const int m0 = blockIdx.x * 128, n0 = blockIdx.y * 128;
    const int t = threadIdx.x, l = t & 63, w = t >> 6;
    const int wr = w >> 1, wc = w & 1;
    const int lr = l & 15, lq = l >> 4;

    f32x4 acc[4][4];
    #pragma unroll
    for (int mi = 0; mi < 4; ++mi)
        #pragma unroll
        for (int ni = 0; ni < 4; ++ni) acc[mi][ni] = (f32x4){0.f, 0.f, 0.f, 0.f};

    for (int ks = 0; ks < 8; ++ks) {          // K-step of 64 (K=512)
        __syncthreads();
        #pragma unroll
        for (int i = 0; i < 4; ++i) {
            int idx = i * 256 + t;
            int row = idx >> 3, g = idx & 7;
            ushort8 av = *(const ushort8*)&A[(size_t)(m0 + row) * 512 + ks * 64 + g * 8];
            *(ushort8*)&Al[row][(g ^ (row & 7)) * 8] = av;
            ushort8 bv = *(const ushort8*)&B[(size_t)(n0 + row) * 512 + ks * 64 + g * 8];
            *(ushort8*)&Bl[row][(g ^ (row & 7)) * 8] = bv;
        }
        __syncthreads();
        #pragma unroll
        for (int kf = 0; kf < 2; ++kf) {
            short8 af[4], bfr[4];
            #pragma unroll
            for (int mi = 0; mi < 4; ++mi) {
                int row = wr * 64 + mi * 16 + lr, g = kf * 4 + lq;
                af[mi] = *(const short8*)&Al[row][(g ^ (row & 7)) * 8];
            }
            #pragma unroll
            for (int ni = 0; ni < 4; ++ni) {
                int row = wc * 64 + ni * 16 + lr, g = kf * 4 + lq;
                bfr[ni] = *(const short8*)&Bl[row][(g ^ (row & 7)) * 8];
            }
            #pragma unroll
            for (int mi = 0; mi < 4; ++mi)
                #pragma unroll
                for (int ni = 0; ni < 4; ++ni)
                    acc[mi][ni] = __builtin_amdgcn_mfma_f32_16x16x32_bf16(
                        af[mi], bfr[ni], acc[mi][ni], 0, 0, 0);
        }
    }
    #pragma unroll
    for (int ni = 0; ni < 4; ++ni) {
        int col = n0 + wc * 64 + ni * 16 + lr;
        float bb = bias[col];
        #pragma unroll
        for (int mi = 0; mi < 4; ++mi)
            #pragma unroll
            for (int j = 0; j < 4; ++j) {
                int row = m0 + wr * 64 + mi * 16 + lq * 4 + j;
                C[(size_t)row * 256 + col] = acc[mi][ni][j] + bb;
            }
    }
}

// ---------------------------------------------------------------------------
extern "C" void kernel_launch(void* const* d_in, const int* in_sizes, int n_in,
                              void* d_out, int out_size, void* d_ws, size_t ws_size,
                              hipStream_t stream) {
    const float* x    = (const float*)d_in[0];
    const float* Wx   = (const float*)d_in[1];
    const float* bx   = (const float*)d_in[2];
    const float* Wt1  = (const float*)d_in[3];
    const float* bt1  = (const float*)d_in[4];
    const float* Wt2  = (const float*)d_in[5];
    const float* bt2  = (const float*)d_in[6];
    const float* biasp= (const float*)d_in[7];
    const float* Ws   = (const float*)d_in[8];
    const float* bs   = (const float*)d_in[9];
    const float* Wq   = (const float*)d_in[10];
    const float* Wk   = (const float*)d_in[11];
    const float* Wv   = (const float*)d_in[12];
    const float* Wout = (const float*)d_in[13];
    const float* bout = (const float*)d_in[14];
    const float* u    = (const float*)d_in[15];
    float* out = (float*)d_out;

    float*  stp    = (float*)d_ws;                           // 8*64*4096 f32 = 8.4 MB
    float*  normp  = stp    + (size_t)NH * 64 * 4096;        // 8*64*64
    float*  st_red = normp  + (size_t)NH * 64 * 64;          // 8*4096
    float*  nrm    = st_red + (size_t)NH * 4096;             // 8*64
    float*  osl    = nrm    + (size_t)NH * 64;               // 8*4096
    ushort* wb     = (ushort*)(osl + (size_t)NH * 4096);     // 128*64 bf16
    ushort* Wxb    = wb  + (size_t)128 * 64;                 // 512*256 bf16
    ushort* Mtb    = Wxb + (size_t)HDIM * DIMX;              // 256*512 bf16
    ushort* xmb    = Mtb + (size_t)DIMX * HDIM;              // 65536*512 bf16
    ushort* swb    = xmb + (size_t)NPTS * HDIM;              // 65536*512 bf16

    // 0) pre-convert Wx and [Ws;Wt1] to bf16
    prep_kernel<<<68, 256, 0, stream>>>(Wx, Ws, Wt1, Wxb, wb);
    // 1+2) fused: xmid GEMM + logits/temp GEMM + gumbel softmax
    xmid_lgt1_kernel<<<dim3(512, 4), 256, 0, stream>>>(x, Wxb, bx, wb, bs, bt1,
                                                       Wt2, bt2, biasp, u,
                                                       xmb, swb);
    // 3) slice token partials via MFMA (in-block cross-wave reduce)
    gather_mfma_kernel<<<dim3(64, 8), 256, 0, stream>>>(xmb, swb, stp, normp);
    // 4a) reduce partials
    reduce_st_kernel<<<dim3(8, 16), 256, 0, stream>>>(stp, normp, st_red, nrm);
    // 4b) tiny attention
    attn_small_kernel<<<8, 256, 0, stream>>>(st_red, nrm, Wq, Wk, Wv, osl);
    // 4c) fold out_slice into Wout (bf16 output)
    fold_kernel<<<dim3(8, 2), 256, 0, stream>>>(osl, Wout, Mtb);
    // 5) out = sw @ Mtb^T + bout
    gemm_out_kernel<<<dim3(512, 2), 256, 0, stream>>>(swb, Mtb, bout, out);
}